// Round 16
// baseline (881.886 us; speedup 1.0000x reference)
//
#include <hip/hip_runtime.h>
#include <hip/hip_bf16.h>
#include <cfloat>

#define Nn 100000
#define Ee 800000
#define Gg 256
// H=96, NI=32, EI=10, OUT=256, L=3

typedef __attribute__((ext_vector_type(8))) short short8;
typedef __attribute__((ext_vector_type(4))) float f32x4;
typedef unsigned short u16;

static __device__ __forceinline__ float blo(unsigned u) { return __builtin_bit_cast(float, u << 16); }
static __device__ __forceinline__ float bhi(unsigned u) { return __builtin_bit_cast(float, u & 0xffff0000u); }
static __device__ __forceinline__ float bus(u16 u) { return __builtin_bit_cast(float, ((unsigned)u) << 16); }
static __device__ __forceinline__ u16 f2bu(float f) {
  __hip_bfloat16 b = __float2bfloat16(f);
  return __builtin_bit_cast(u16, b);
}
static __device__ __forceinline__ unsigned pack2(float lo, float hi) {
  return (unsigned)f2bu(lo) | ((unsigned)f2bu(hi) << 16);
}

// ---------------- CSR build ----------------

__global__ __launch_bounds__(512) void k_gptr(const int* __restrict__ batch, int* __restrict__ gptr) {
  int g = threadIdx.x;
  if (g > Gg) return;
  if (g == Gg) { gptr[Gg] = Nn; return; }
  int lo = 0, hi = Nn;
  while (lo < hi) { int mid = (lo + hi) >> 1; if (batch[mid] < g) lo = mid + 1; else hi = mid; }
  gptr[g] = lo;
}

__global__ __launch_bounds__(256) void k_deg(const int* __restrict__ dst, int* __restrict__ deg) {
  int e = blockIdx.x * 256 + threadIdx.x;
  if (e < Ee) atomicAdd(&deg[dst[e]], 1);
}

__global__ __launch_bounds__(256) void k_scanA(const int* __restrict__ deg, int* __restrict__ localA,
                                               int* __restrict__ bsum) {
  __shared__ int ts[256];
  int t = threadIdx.x, b = blockIdx.x;
  int base = b * 1024 + t * 4;
  int v[4]; int s = 0;
#pragma unroll
  for (int k = 0; k < 4; k++) { int idx = base + k; v[k] = (idx < Nn) ? deg[idx] : 0; s += v[k]; }
  ts[t] = s; __syncthreads();
  for (int off = 1; off < 256; off <<= 1) {
    int y = (t >= off) ? ts[t - off] : 0;
    __syncthreads();
    ts[t] += y;
    __syncthreads();
  }
  int ex = ts[t] - s;
#pragma unroll
  for (int k = 0; k < 4; k++) { int idx = base + k; if (idx < Nn) localA[idx] = ex; ex += v[k]; }
  if (t == 255) bsum[b] = ts[255];
}

__global__ __launch_bounds__(128) void k_scanB(int* __restrict__ bsum) {
  __shared__ int s[128];
  const int NB = (Nn + 1023) / 1024;
  int t = threadIdx.x;
  int v = (t < NB) ? bsum[t] : 0;
  s[t] = v; __syncthreads();
  for (int off = 1; off < 128; off <<= 1) {
    int y = (t >= off) ? s[t - off] : 0;
    __syncthreads();
    s[t] += y;
    __syncthreads();
  }
  if (t < NB) bsum[t] = s[t] - v;   // exclusive
}

__global__ __launch_bounds__(256) void k_scanC(const int* __restrict__ localA, const int* __restrict__ bsum,
                                               int* __restrict__ rowptr, int* __restrict__ cursor) {
  int i = blockIdx.x * 256 + threadIdx.x;
  if (i < Nn) { int v = localA[i] + bsum[i >> 10]; rowptr[i] = v; cursor[i] = v; }
  if (i == 0) rowptr[Nn] = Ee;
}

__global__ __launch_bounds__(256) void k_fill(const int* __restrict__ dst, int* __restrict__ cursor,
                                              int* __restrict__ elist) {
  int e = blockIdx.x * 256 + threadIdx.x;
  if (e < Ee) { int p = atomicAdd(&cursor[dst[e]], 1); elist[p] = e; }
}

// ---------------- eSum precompute v2 (MFMA): eSum[nd] = sum_{e->nd} relu(ea_e@eW+eb) ----------------
// Edge MLP is matmul-shaped (M=E, K=10 pad 32, N=96) -> MFMA. Per 64-edge chunk: bf16 A-tile,
// bf16 Wt (staged once/block), 6 MFMA/wave, epilogue relu+bias and LDS atomicAdd into per-node
// f32 accumulators (handles intra-wave same-dst collisions and cross-wave races).
// Also fills srcPerm[q] = srcArr[elist[q]].

#define ES_NODES 16

__global__ __launch_bounds__(256) void k_esum(const float* __restrict__ eattr,
                                              const int* __restrict__ elist,
                                              const int* __restrict__ srcArr,
                                              const int* __restrict__ rowptr,
                                              const float* __restrict__ eW,
                                              const float* __restrict__ eb,
                                              int* __restrict__ srcPerm,
                                              float* __restrict__ eSum) {
  __shared__ __align__(16) __hip_bfloat16 At[64][40];   // 64 edges x K=32 (cols 10..31 zero), pad 40
  __shared__ __align__(16) __hip_bfloat16 Wt[96][40];   // Wt[col][k]
  __shared__ float eT[ES_NODES][104];                    // per-node accumulators (pad 104)
  __shared__ int dstl[64];
  __shared__ int rp16[ES_NODES + 1];
  __shared__ float ebias[96];
  int t = threadIdx.x;
  int n0 = blockIdx.x * ES_NODES;
  if (t <= ES_NODES) rp16[t] = rowptr[min(n0 + t, Nn)];
  for (int i = t; i < 64 * 40; i += 256) ((u16*)At)[i] = 0;
  for (int i = t; i < 96 * 40; i += 256) ((u16*)Wt)[i] = 0;
  for (int i = t; i < ES_NODES * 104; i += 256) ((float*)eT)[i] = 0.f;
  if (t < 96) ebias[t] = eb[t];
  __syncthreads();   // zeros visible before Wt fill (disjoint ranges though; keep simple)
  for (int i = t; i < 960; i += 256) {
    int k = i / 96, c = i - k * 96;
    Wt[c][k] = __float2bfloat16(eW[i]);
  }
  __syncthreads();
  int beg = rp16[0], end = rp16[ES_NODES];
  int w = t >> 6, l = t & 63;
  int lr = l & 15, lg = l >> 4;
  int row0 = w * 16;
  for (int cs = beg; cs < end; cs += 64) {
    int m = min(64, end - cs);
    for (int i = t; i < m; i += 256) {
      int q = cs + i;
      int e = elist[q];
      srcPerm[q] = srcArr[e];
      int lo = 0, hi = ES_NODES - 1;
      while (lo < hi) { int mid = (lo + hi + 1) >> 1; if (rp16[mid] <= q) lo = mid; else hi = mid - 1; }
      dstl[i] = lo;
    }
    for (int i = t; i < 5 * m; i += 256) {
      int ii = i / 5, k2 = (i - ii * 5) * 2;
      int e = elist[cs + ii];            // redundant load, L1-hit
      float2 v = *reinterpret_cast<const float2*>(&eattr[(size_t)e * 10 + k2]);
      *reinterpret_cast<unsigned*>(&At[ii][k2]) = pack2(v.x, v.y);
    }
    __syncthreads();
    short8 a = *reinterpret_cast<const short8*>(&At[row0 + lr][lg * 8]);
    f32x4 acc[6];
#pragma unroll
    for (int nt = 0; nt < 6; nt++) {
      short8 b = *reinterpret_cast<const short8*>(&Wt[nt * 16 + lr][lg * 8]);
      acc[nt] = __builtin_amdgcn_mfma_f32_16x16x32_bf16(a, b, (f32x4){0.f, 0.f, 0.f, 0.f}, 0, 0, 0);
    }
#pragma unroll
    for (int nt = 0; nt < 6; nt++) {
      int col = nt * 16 + lr;
      float bias = ebias[col];
#pragma unroll
      for (int j = 0; j < 4; j++) {
        int row = row0 + lg * 4 + j;
        if (row < m) {
          float ev = fmaxf(acc[nt][j] + bias, 0.f);
          atomicAdd(&eT[dstl[row]][col], ev);
        }
      }
    }
    __syncthreads();   // epilogue reads of dstl/At done before next chunk restages
  }
  for (int i = t; i < ES_NODES * 96; i += 256) {
    int nl = i / 96, jj = i - nl * 96;
    int n = n0 + nl;
    if (n < Nn) eSum[(size_t)n * 96 + jj] = eT[nl][jj];
  }
}

// ---------------- node MLP: h16 = relu(x @ W + b), x[N,32] ----------------

__global__ __launch_bounds__(256) void k_node_mlp(const float* __restrict__ x, const float* __restrict__ W,
                                                  const float* __restrict__ b, u16* __restrict__ h16) {
  __shared__ float xs[16][33];
  __shared__ float Ws[32 * 96];
  __shared__ float bs[96];
  int t = threadIdx.x;
  int n0 = blockIdx.x * 16;
  for (int i = t; i < 32 * 96; i += 256) Ws[i] = W[i];
  if (t < 96) bs[t] = b[t];
  for (int i = t; i < 512; i += 256) {
    int nl = i >> 5, k = i & 31; int n = n0 + nl;
    xs[nl][k] = (n < Nn) ? x[n * 32 + k] : 0.f;
  }
  __syncthreads();
#pragma unroll
  for (int p = 0; p < 6; p++) {
    int oi = t + p * 256; int nl = oi / 96, j = oi % 96; int n = n0 + nl;
    if (n < Nn) {
      float acc = bs[j];
#pragma unroll
      for (int k = 0; k < 32; k++) acc += xs[nl][k] * Ws[k * 96 + j];
      h16[(size_t)n * 96 + j] = f2bu(fmaxf(acc, 0.f));
    }
  }
}

// ---------------- FUSED layer kernel: h-gather sum + eSum + MFMA MLP ----------------
// v6: relu-identity removes the e stream entirely. Per edge: 3 uint4 h-loads only.
// 4-edge chunks (12 independent loads in flight). k-fast Wt staging; mid aliases A-tile.

#define MPAD 104

#define ACC8H(hv, B) \
  acc[B+0] += blo(hv.x); acc[B+1] += bhi(hv.x); acc[B+2] += blo(hv.y); acc[B+3] += bhi(hv.y); \
  acc[B+4] += blo(hv.z); acc[B+5] += bhi(hv.z); acc[B+6] += blo(hv.w); acc[B+7] += bhi(hv.w);

#define LOADH(hp, H0, H1, H2) \
  uint4 H0 = *reinterpret_cast<const uint4*>(hp); \
  uint4 H1 = *reinterpret_cast<const uint4*>(hp + 8); \
  uint4 H2 = *reinterpret_cast<const uint4*>(hp + 16);

__global__ __launch_bounds__(256) void k_layer(const u16* __restrict__ h16,
                                               const int* __restrict__ srcPerm,
                                               const int* __restrict__ rowptr,
                                               const float* __restrict__ eSum,
                                               const float* __restrict__ W1, const float* __restrict__ b1,
                                               const float* __restrict__ W2, const float* __restrict__ b2,
                                               const float* __restrict__ epsA, int layer,
                                               float* __restrict__ z) {
  __shared__ __align__(16) __hip_bfloat16 At[64][MPAD];   // A-tile, then mid (wave-private rows)
  __shared__ __align__(16) __hip_bfloat16 Wt[96][MPAD];   // Wt[col][k]
  __shared__ int rp[65];
  int t = threadIdx.x;
  int n0 = blockIdx.x * 64;
  if (t < 65) rp[t] = rowptr[min(n0 + t, Nn)];
  __syncthreads();
  float epsv = 1.0f + epsA[layer];
  int nl = t >> 2, q = t & 3;            // node-local, feature-quarter
  int beg = rp[nl], end = rp[nl + 1];
  const size_t fo = (size_t)q * 24;      // feature offset (elements)
  float acc[24];
#pragma unroll
  for (int j = 0; j < 24; j++) acc[j] = 0.f;
  int e = beg;
  for (; e + 4 <= end; e += 4) {
    int s0 = srcPerm[e], s1 = srcPerm[e + 1], s2 = srcPerm[e + 2], s3 = srcPerm[e + 3];
    const u16* hp0 = h16 + (size_t)s0 * 96 + fo;
    const u16* hp1 = h16 + (size_t)s1 * 96 + fo;
    const u16* hp2 = h16 + (size_t)s2 * 96 + fo;
    const u16* hp3 = h16 + (size_t)s3 * 96 + fo;
    LOADH(hp0, ha0, ha1, ha2)
    LOADH(hp1, hb0, hb1, hb2)
    LOADH(hp2, hc0, hc1, hc2)
    LOADH(hp3, hd0, hd1, hd2)
    ACC8H(ha0, 0)
    ACC8H(ha1, 8)
    ACC8H(ha2, 16)
    ACC8H(hb0, 0)
    ACC8H(hb1, 8)
    ACC8H(hb2, 16)
    ACC8H(hc0, 0)
    ACC8H(hc1, 8)
    ACC8H(hc2, 16)
    ACC8H(hd0, 0)
    ACC8H(hd1, 8)
    ACC8H(hd2, 16)
  }
  for (; e < end; e++) {
    int s0 = srcPerm[e];
    const u16* hp0 = h16 + (size_t)s0 * 96 + fo;
    LOADH(hp0, ha0, ha1, ha2)
    ACC8H(ha0, 0)
    ACC8H(ha1, 8)
    ACC8H(ha2, 16)
  }
  {
    int n = n0 + nl;
    uint4 hh0 = make_uint4(0, 0, 0, 0), hh1 = hh0, hh2 = hh0;
    float4 es0 = make_float4(0.f, 0.f, 0.f, 0.f), es1 = es0, es2 = es0, es3 = es0, es4 = es0, es5 = es0;
    if (n < Nn) {
      const u16* hp = h16 + (size_t)n * 96 + fo;
      hh0 = *reinterpret_cast<const uint4*>(hp);
      hh1 = *reinterpret_cast<const uint4*>(hp + 8);
      hh2 = *reinterpret_cast<const uint4*>(hp + 16);
      const float* ep = eSum + (size_t)n * 96 + fo;
      es0 = *reinterpret_cast<const float4*>(ep);
      es1 = *reinterpret_cast<const float4*>(ep + 4);
      es2 = *reinterpret_cast<const float4*>(ep + 8);
      es3 = *reinterpret_cast<const float4*>(ep + 12);
      es4 = *reinterpret_cast<const float4*>(ep + 16);
      es5 = *reinterpret_cast<const float4*>(ep + 20);
    }
    uint4 w0, w1, w2;
    w0.x = pack2(fmaf(epsv, blo(hh0.x), acc[0] + es0.x),  fmaf(epsv, bhi(hh0.x), acc[1] + es0.y));
    w0.y = pack2(fmaf(epsv, blo(hh0.y), acc[2] + es0.z),  fmaf(epsv, bhi(hh0.y), acc[3] + es0.w));
    w0.z = pack2(fmaf(epsv, blo(hh0.z), acc[4] + es1.x),  fmaf(epsv, bhi(hh0.z), acc[5] + es1.y));
    w0.w = pack2(fmaf(epsv, blo(hh0.w), acc[6] + es1.z),  fmaf(epsv, bhi(hh0.w), acc[7] + es1.w));
    w1.x = pack2(fmaf(epsv, blo(hh1.x), acc[8] + es2.x),  fmaf(epsv, bhi(hh1.x), acc[9] + es2.y));
    w1.y = pack2(fmaf(epsv, blo(hh1.y), acc[10] + es2.z), fmaf(epsv, bhi(hh1.y), acc[11] + es2.w));
    w1.z = pack2(fmaf(epsv, blo(hh1.z), acc[12] + es3.x), fmaf(epsv, bhi(hh1.z), acc[13] + es3.y));
    w1.w = pack2(fmaf(epsv, blo(hh1.w), acc[14] + es3.z), fmaf(epsv, bhi(hh1.w), acc[15] + es3.w));
    w2.x = pack2(fmaf(epsv, blo(hh2.x), acc[16] + es4.x), fmaf(epsv, bhi(hh2.x), acc[17] + es4.y));
    w2.y = pack2(fmaf(epsv, blo(hh2.y), acc[18] + es4.z), fmaf(epsv, bhi(hh2.y), acc[19] + es4.w));
    w2.z = pack2(fmaf(epsv, blo(hh2.z), acc[20] + es5.x), fmaf(epsv, bhi(hh2.z), acc[21] + es5.y));
    w2.w = pack2(fmaf(epsv, blo(hh2.w), acc[22] + es5.z), fmaf(epsv, bhi(hh2.w), acc[23] + es5.w));
    *reinterpret_cast<uint4*>(&At[nl][fo]) = w0;
    *reinterpret_cast<uint4*>(&At[nl][fo + 8]) = w1;
    *reinterpret_cast<uint4*>(&At[nl][fo + 16]) = w2;
  }
  // stage W1: k-fast packed writes (c across lanes -> coalesced global reads, uint2 LDS writes)
  for (int i = t; i < 24 * 96; i += 256) {
    int kg = i / 96, c = i - kg * 96;
    int k0 = kg * 4;
    float w0 = W1[(k0 + 0) * 96 + c];
    float w1 = W1[(k0 + 1) * 96 + c];
    float w2 = W1[(k0 + 2) * 96 + c];
    float w3 = W1[(k0 + 3) * 96 + c];
    *reinterpret_cast<uint2*>(&Wt[c][k0]) = make_uint2(pack2(w0, w1), pack2(w2, w3));
  }
  __syncthreads();
  int w = t >> 6, l = t & 63;
  int lr = l & 15, lg = l >> 4;
  int rowBase = w * 16;
  short8 a0 = *reinterpret_cast<const short8*>(&At[rowBase + lr][lg * 8]);
  short8 a1 = *reinterpret_cast<const short8*>(&At[rowBase + lr][32 + lg * 8]);
  short8 a2 = *reinterpret_cast<const short8*>(&At[rowBase + lr][64 + lg * 8]);
  f32x4 gacc[6];
#pragma unroll
  for (int nt = 0; nt < 6; nt++) gacc[nt] = (f32x4){0.f, 0.f, 0.f, 0.f};
#pragma unroll
  for (int nt = 0; nt < 6; nt++) {
    short8 b0 = *reinterpret_cast<const short8*>(&Wt[nt * 16 + lr][lg * 8]);
    short8 bv1 = *reinterpret_cast<const short8*>(&Wt[nt * 16 + lr][32 + lg * 8]);
    short8 bv2 = *reinterpret_cast<const short8*>(&Wt[nt * 16 + lr][64 + lg * 8]);
    gacc[nt] = __builtin_amdgcn_mfma_f32_16x16x32_bf16(a0, b0, gacc[nt], 0, 0, 0);
    gacc[nt] = __builtin_amdgcn_mfma_f32_16x16x32_bf16(a1, bv1, gacc[nt], 0, 0, 0);
    gacc[nt] = __builtin_amdgcn_mfma_f32_16x16x32_bf16(a2, bv2, gacc[nt], 0, 0, 0);
  }
  // mid overwrites A-tile: wave-private rows, a-frags already in registers
#pragma unroll
  for (int nt = 0; nt < 6; nt++) {
    int col = nt * 16 + lr;
    float bias = b1[col];
#pragma unroll
    for (int j = 0; j < 4; j++) {
      int row = rowBase + lg * 4 + j;
      At[row][col] = __float2bfloat16(fmaxf(gacc[nt][j] + bias, 0.f));
    }
  }
  __syncthreads();   // all waves done reading Wt(W1)
  for (int i = t; i < 24 * 96; i += 256) {
    int kg = i / 96, c = i - kg * 96;
    int k0 = kg * 4;
    float w0 = W2[(k0 + 0) * 96 + c];
    float w1 = W2[(k0 + 1) * 96 + c];
    float w2 = W2[(k0 + 2) * 96 + c];
    float w3 = W2[(k0 + 3) * 96 + c];
    *reinterpret_cast<uint2*>(&Wt[c][k0]) = make_uint2(pack2(w0, w1), pack2(w2, w3));
  }
  __syncthreads();
  short8 m0 = *reinterpret_cast<const short8*>(&At[rowBase + lr][lg * 8]);
  short8 m1 = *reinterpret_cast<const short8*>(&At[rowBase + lr][32 + lg * 8]);
  short8 m2 = *reinterpret_cast<const short8*>(&At[rowBase + lr][64 + lg * 8]);
#pragma unroll
  for (int nt = 0; nt < 6; nt++) gacc[nt] = (f32x4){0.f, 0.f, 0.f, 0.f};
#pragma unroll
  for (int nt = 0; nt < 6; nt++) {
    short8 b0 = *reinterpret_cast<const short8*>(&Wt[nt * 16 + lr][lg * 8]);
    short8 bv1 = *reinterpret_cast<const short8*>(&Wt[nt * 16 + lr][32 + lg * 8]);
    short8 bv2 = *reinterpret_cast<const short8*>(&Wt[nt * 16 + lr][64 + lg * 8]);
    gacc[nt] = __builtin_amdgcn_mfma_f32_16x16x32_bf16(m0, b0, gacc[nt], 0, 0, 0);
    gacc[nt] = __builtin_amdgcn_mfma_f32_16x16x32_bf16(m1, bv1, gacc[nt], 0, 0, 0);
    gacc[nt] = __builtin_amdgcn_mfma_f32_16x16x32_bf16(m2, bv2, gacc[nt], 0, 0, 0);
  }
#pragma unroll
  for (int nt = 0; nt < 6; nt++) {
    int col = nt * 16 + lr;
    float bias = b2[col];
#pragma unroll
    for (int j = 0; j < 4; j++) {
      int row = rowBase + lg * 4 + j;
      int n = n0 + row;
      if (n < Nn) z[(size_t)n * 96 + col] = gacc[nt][j] + bias;
    }
  }
}

// ---------------- FUSED GraphNorm: stats + normalize + residual, one block per graph ----------------

__global__ __launch_bounds__(384) void k_gnorm(const float* __restrict__ z, u16* __restrict__ h16,
                                               const int* __restrict__ gptr, const float* __restrict__ ms,
                                               const float* __restrict__ gw, const float* __restrict__ gb) {
  __shared__ float r1[16][100];
  __shared__ float r2[16][100];
  __shared__ float smm[96], sinv[96], sgb[96];
  int g = blockIdx.x, t = threadIdx.x;
  int beg = gptr[g], end = gptr[g + 1];
  int sub = t / 24, slot = t - (t / 24) * 24;
  int sl = slot * 4;
  float4 s1 = make_float4(0.f, 0.f, 0.f, 0.f), s2 = s1;
  for (int n = beg + sub; n < end; n += 16) {
    float4 zv = *reinterpret_cast<const float4*>(z + (size_t)n * 96 + sl);
    s1.x += zv.x; s1.y += zv.y; s1.z += zv.z; s1.w += zv.w;
    s2.x += zv.x * zv.x; s2.y += zv.y * zv.y; s2.z += zv.z * zv.z; s2.w += zv.w * zv.w;
  }
  *reinterpret_cast<float4*>(&r1[sub][sl]) = s1;
  *reinterpret_cast<float4*>(&r2[sub][sl]) = s2;
  __syncthreads();
  if (t < 96) {
    float S1 = 0.f, S2 = 0.f;
#pragma unroll
    for (int u = 0; u < 16; u++) { S1 += r1[u][t]; S2 += r2[u][t]; }
    float c = (float)max(end - beg, 1);
    float m = S1 / c;
    float mm = m * ms[t];
    float var = S2 / c - 2.f * mm * m + mm * mm;
    var = fmaxf(var, 0.f);
    smm[t] = mm;
    sinv[t] = rsqrtf(var + 1e-5f) * gw[t];
    sgb[t] = gb[t];
  }
  __syncthreads();
  float4 mm4 = *reinterpret_cast<const float4*>(&smm[sl]);
  float4 iv4 = *reinterpret_cast<const float4*>(&sinv[sl]);
  float4 gb4 = *reinterpret_cast<const float4*>(&sgb[sl]);
  for (int n = beg + sub; n < end; n += 16) {
    float4 zv = *reinterpret_cast<const float4*>(z + (size_t)n * 96 + sl);
    uint2 hv = *reinterpret_cast<const uint2*>(h16 + (size_t)n * 96 + sl);
    float o0 = fmaxf((zv.x - mm4.x) * iv4.x + gb4.x, 0.f) + blo(hv.x);
    float o1 = fmaxf((zv.y - mm4.y) * iv4.y + gb4.y, 0.f) + bhi(hv.x);
    float o2 = fmaxf((zv.z - mm4.z) * iv4.z + gb4.z, 0.f) + blo(hv.y);
    float o3 = fmaxf((zv.w - mm4.w) * iv4.w + gb4.w, 0.f) + bhi(hv.y);
    *reinterpret_cast<uint2*>(h16 + (size_t)n * 96 + sl) = make_uint2(pack2(o0, o1), pack2(o2, o3));
  }
}

// ---------------- pooling + LayerNorm + output MLP ----------------

__global__ __launch_bounds__(256) void k_pool_out(const u16* __restrict__ h16, const int* __restrict__ gptr,
                                                  const float* __restrict__ lng, const float* __restrict__ lnb,
                                                  const float* __restrict__ W1, const float* __restrict__ b1,
                                                  const float* __restrict__ W2, const float* __restrict__ b2,
                                                  float* __restrict__ out) {
  __shared__ float sh1[2][96], sh2[2][96];
  __shared__ float gbuf[192];
  __shared__ float rs[4], rq[4];
  __shared__ float s_mu, s_rstd;
  __shared__ float inter[96];
  int g = blockIdx.x, t = threadIdx.x;
  int beg = gptr[g], end = gptr[g + 1];
  if (t < 192) {
    int j = t % 96, half = t / 96;
    float s = 0.f, m = -INFINITY;
    for (int n = beg + half; n < end; n += 2) {
      float v = bus(h16[(size_t)n * 96 + j]);
      s += v; m = fmaxf(m, v);
    }
    sh1[half][j] = s; sh2[half][j] = m;
  }
  __syncthreads();
  if (t < 96) {
    float c = (float)max(end - beg, 1);
    gbuf[t] = (sh1[0][t] + sh1[1][t]) / c;
    gbuf[96 + t] = fmaxf(sh2[0][t], sh2[1][t]);
  }
  __syncthreads();
  float sv = (t < 192) ? gbuf[t] : 0.f;
  float qv = sv * sv;
#pragma unroll
  for (int off = 32; off; off >>= 1) { sv += __shfl_down(sv, off); qv += __shfl_down(qv, off); }
  if ((t & 63) == 0) { rs[t >> 6] = sv; rq[t >> 6] = qv; }
  __syncthreads();
  if (t == 0) {
    float S = rs[0] + rs[1] + rs[2] + rs[3];
    float Q = rq[0] + rq[1] + rq[2] + rq[3];
    float mu = S / 192.f;
    float va = Q / 192.f - mu * mu;
    s_mu = mu; s_rstd = rsqrtf(fmaxf(va, 0.f) + 1e-5f);
  }
  __syncthreads();
  if (t < 192) gbuf[t] = (gbuf[t] - s_mu) * s_rstd * lng[t] + lnb[t];
  __syncthreads();
  if (t < 96) {
    float a = b1[t];
    for (int k = 0; k < 192; k++) a += gbuf[k] * W1[k * 96 + t];
    inter[t] = fmaxf(a, 0.f);
  }
  __syncthreads();
  {
    float a = b2[t];
    for (int j = 0; j < 96; j++) a += inter[j] * W2[j * 256 + t];
    out[g * 256 + t] = a;
  }
}

// ---------------- host ----------------

extern "C" void kernel_launch(void* const* d_in, const int* in_sizes, int n_in,
                              void* d_out, int out_size, void* d_ws, size_t ws_size,
                              hipStream_t stream) {
  (void)in_sizes; (void)n_in; (void)out_size; (void)ws_size;
  const float* x     = (const float*)d_in[0];
  const float* eattr = (const float*)d_in[1];
  const int*   eidx2 = (const int*)  d_in[2];
  const int*   batch = (const int*)  d_in[3];
  const float* nodeW = (const float*)d_in[4];
  const float* nodeb = (const float*)d_in[5];
  const float* edgeW = (const float*)d_in[6];
  const float* edgeb = (const float*)d_in[7];
  const float* mlpW1 = (const float*)d_in[8];
  const float* mlpb1 = (const float*)d_in[9];
  const float* mlpW2 = (const float*)d_in[10];
  const float* mlpb2 = (const float*)d_in[11];
  const float* epsA  = (const float*)d_in[12];
  const float* gnw   = (const float*)d_in[13];
  const float* gnb   = (const float*)d_in[14];
  const float* gnms  = (const float*)d_in[15];
  const float* lng   = (const float*)d_in[16];
  const float* lnb   = (const float*)d_in[17];
  const float* oW1   = (const float*)d_in[18];
  const float* ob1   = (const float*)d_in[19];
  const float* oW2   = (const float*)d_in[20];
  const float* ob2   = (const float*)d_in[21];
  float* out = (float*)d_out;

  const int* srcArr = eidx2;        // edge_index[0]
  const int* dstArr = eidx2 + Ee;   // edge_index[1]

  char* p = (char*)d_ws;
  auto carve = [&](size_t bytes) -> void* {
    void* r = (void*)p;
    p += ((bytes + 255) & ~(size_t)255);
    return r;
  };
  // Total ~105 MB.
  u16* h16     = (u16*)carve((size_t)Nn * 96 * 2);     // h state, bf16
  float* aggz  = (float*)carve((size_t)Nn * 96 * 4);   // z (f32)
  float* eSum  = (float*)carve((size_t)Nn * 96 * 4);   // layer-invariant edge-message sums (f32)
  int* rowptr  = (int*)carve((size_t)(Nn + 1) * 4);
  int* elist   = (int*)carve((size_t)Ee * 4);
  int* gptr    = (int*)carve((size_t)(Gg + 1) * 4);
  // srcPerm (Ee ints) doubles as CSR temp space (deg/localA/cursor/bsum, 3*Nn+NB ints < Ee).
  int* srcPerm = (int*)carve((size_t)Ee * 4);
  int* deg     = srcPerm;
  int* localA  = srcPerm + Nn;
  int* cursor  = srcPerm + 2 * Nn;
  int* bsum    = srcPerm + 3 * Nn;

  hipMemsetAsync(deg, 0, (size_t)Nn * 4, stream);
  k_gptr<<<1, 512, 0, stream>>>(batch, gptr);
  k_deg<<<(Ee + 255) / 256, 256, 0, stream>>>(dstArr, deg);
  k_scanA<<<(Nn + 1023) / 1024, 256, 0, stream>>>(deg, localA, bsum);
  k_scanB<<<1, 128, 0, stream>>>(bsum);
  k_scanC<<<(Nn + 255) / 256, 256, 0, stream>>>(localA, bsum, rowptr, cursor);
  k_fill<<<(Ee + 255) / 256, 256, 0, stream>>>(dstArr, cursor, elist);

  // eSum precompute (MFMA; also writes srcPerm, overwriting the dead CSR temps)
  k_esum<<<(Nn + ES_NODES - 1) / ES_NODES, 256, 0, stream>>>(eattr, elist, srcArr, rowptr,
                                                             edgeW, edgeb, srcPerm, eSum);

  k_node_mlp<<<(Nn + 15) / 16, 256, 0, stream>>>(x, nodeW, nodeb, h16);

  for (int i = 0; i < 3; i++) {
    k_layer<<<(Nn + 63) / 64, 256, 0, stream>>>(h16, srcPerm, rowptr, eSum,
                                                mlpW1 + i * 9216, mlpb1 + i * 96,
                                                mlpW2 + i * 9216, mlpb2 + i * 96, epsA, i, aggz);
    k_gnorm<<<Gg, 384, 0, stream>>>(aggz, h16, gptr, gnms + i * 96, gnw + i * 96, gnb + i * 96);
  }

  k_pool_out<<<Gg, 256, 0, stream>>>(h16, gptr, lng, lnb, oW1, ob1, oW2, ob2, out);
}

// Round 17
// 542.783 us; speedup vs baseline: 1.6247x; 1.6247x over previous
//
#include <hip/hip_runtime.h>
#include <hip/hip_bf16.h>
#include <cfloat>

#define Nn 100000
#define Ee 800000
#define Gg 256
// H=96, NI=32, EI=10, OUT=256, L=3

typedef __attribute__((ext_vector_type(8))) short short8;
typedef __attribute__((ext_vector_type(4))) float f32x4;
typedef unsigned short u16;

static __device__ __forceinline__ float blo(unsigned u) { return __builtin_bit_cast(float, u << 16); }
static __device__ __forceinline__ float bhi(unsigned u) { return __builtin_bit_cast(float, u & 0xffff0000u); }
static __device__ __forceinline__ float bus(u16 u) { return __builtin_bit_cast(float, ((unsigned)u) << 16); }
static __device__ __forceinline__ u16 f2bu(float f) {
  __hip_bfloat16 b = __float2bfloat16(f);
  return __builtin_bit_cast(u16, b);
}
static __device__ __forceinline__ unsigned pack2(float lo, float hi) {
  return (unsigned)f2bu(lo) | ((unsigned)f2bu(hi) << 16);
}

// ---------------- CSR build ----------------

__global__ __launch_bounds__(512) void k_gptr(const int* __restrict__ batch, int* __restrict__ gptr) {
  int g = threadIdx.x;
  if (g > Gg) return;
  if (g == Gg) { gptr[Gg] = Nn; return; }
  int lo = 0, hi = Nn;
  while (lo < hi) { int mid = (lo + hi) >> 1; if (batch[mid] < g) lo = mid + 1; else hi = mid; }
  gptr[g] = lo;
}

__global__ __launch_bounds__(256) void k_deg(const int* __restrict__ dst, int* __restrict__ deg) {
  int e = blockIdx.x * 256 + threadIdx.x;
  if (e < Ee) atomicAdd(&deg[dst[e]], 1);
}

__global__ __launch_bounds__(256) void k_scanA(const int* __restrict__ deg, int* __restrict__ localA,
                                               int* __restrict__ bsum) {
  __shared__ int ts[256];
  int t = threadIdx.x, b = blockIdx.x;
  int base = b * 1024 + t * 4;
  int v[4]; int s = 0;
#pragma unroll
  for (int k = 0; k < 4; k++) { int idx = base + k; v[k] = (idx < Nn) ? deg[idx] : 0; s += v[k]; }
  ts[t] = s; __syncthreads();
  for (int off = 1; off < 256; off <<= 1) {
    int y = (t >= off) ? ts[t - off] : 0;
    __syncthreads();
    ts[t] += y;
    __syncthreads();
  }
  int ex = ts[t] - s;
#pragma unroll
  for (int k = 0; k < 4; k++) { int idx = base + k; if (idx < Nn) localA[idx] = ex; ex += v[k]; }
  if (t == 255) bsum[b] = ts[255];
}

__global__ __launch_bounds__(128) void k_scanB(int* __restrict__ bsum) {
  __shared__ int s[128];
  const int NB = (Nn + 1023) / 1024;
  int t = threadIdx.x;
  int v = (t < NB) ? bsum[t] : 0;
  s[t] = v; __syncthreads();
  for (int off = 1; off < 128; off <<= 1) {
    int y = (t >= off) ? s[t - off] : 0;
    __syncthreads();
    s[t] += y;
    __syncthreads();
  }
  if (t < NB) bsum[t] = s[t] - v;   // exclusive
}

__global__ __launch_bounds__(256) void k_scanC(const int* __restrict__ localA, const int* __restrict__ bsum,
                                               int* __restrict__ rowptr, int* __restrict__ cursor) {
  int i = blockIdx.x * 256 + threadIdx.x;
  if (i < Nn) { int v = localA[i] + bsum[i >> 10]; rowptr[i] = v; cursor[i] = v; }
  if (i == 0) rowptr[Nn] = Ee;
}

__global__ __launch_bounds__(256) void k_fill(const int* __restrict__ dst, int* __restrict__ cursor,
                                              int* __restrict__ elist) {
  int e = blockIdx.x * 256 + threadIdx.x;
  if (e < Ee) { int p = atomicAdd(&cursor[dst[e]], 1); elist[p] = e; }
}

// ---------------- eSum precompute v3 (MFMA + contention-free segmented sum) ----------------
// eSum[nd] = sum_{e->nd} relu(ea_e@eW+eb). MFMA computes 64 edge-messages/chunk into LDS P
// (bf16, plain stores). Then an ownership-partitioned reduce: thread owning (node,col) sums
// that node's CONTIGUOUS row range of P (dst-sorted CSR) into its exclusive eT slot.
// ZERO atomics (r16's LDS atomicAdd serialized same-address -> 444us; this removes it).
// Also fills srcPerm[q] = srcArr[elist[q]].

#define ES_NODES 16

__global__ __launch_bounds__(256) void k_esum(const float* __restrict__ eattr,
                                              const int* __restrict__ elist,
                                              const int* __restrict__ srcArr,
                                              const int* __restrict__ rowptr,
                                              const float* __restrict__ eW,
                                              const float* __restrict__ eb,
                                              int* __restrict__ srcPerm,
                                              float* __restrict__ eSum) {
  __shared__ __align__(16) __hip_bfloat16 At[64][40];   // 64 edges x K=32 (cols 10..31 zero), pad 40
  __shared__ __align__(16) __hip_bfloat16 Wt[96][40];   // Wt[col][k]
  __shared__ u16 P[64][104];                             // edge messages (bf16), pad 104
  __shared__ float eT[ES_NODES][96];                     // exclusive per-(node,col) accumulators
  __shared__ int rp16[ES_NODES + 1];
  __shared__ float ebias[96];
  int t = threadIdx.x;
  int n0 = blockIdx.x * ES_NODES;
  if (t <= ES_NODES) rp16[t] = rowptr[min(n0 + t, Nn)];
  for (int i = t; i < 64 * 40; i += 256) ((u16*)At)[i] = 0;
  for (int i = t; i < ES_NODES * 96; i += 256) ((float*)eT)[i] = 0.f;
  if (t < 96) ebias[t] = eb[t];
  for (int i = t; i < 960; i += 256) {
    int k = i / 96, c = i - k * 96;
    Wt[c][k] = __float2bfloat16(eW[i]);
  }
  for (int i = t + 960; i < 96 * 40; i += 256) {        // zero K=10..39 region of Wt (i>=960 ~ k>=10)
    int k = i / 96, c = i - k * 96;
    Wt[c][k] = __float2bfloat16(0.f);
  }
  __syncthreads();
  int beg = rp16[0], end = rp16[ES_NODES];
  int w = t >> 6, l = t & 63;
  int lr = l & 15, lg = l >> 4;
  int row0 = w * 16;
  for (int cs = beg; cs < end; cs += 64) {
    int m = min(64, end - cs);
    for (int i = t; i < m; i += 256) {
      int q = cs + i;
      srcPerm[q] = srcArr[elist[q]];
    }
    for (int i = t; i < 5 * m; i += 256) {
      int ii = i / 5, k2 = (i - ii * 5) * 2;
      int e = elist[cs + ii];            // redundant load, L1-hit
      float2 v = *reinterpret_cast<const float2*>(&eattr[(size_t)e * 10 + k2]);
      *reinterpret_cast<unsigned*>(&At[ii][k2]) = pack2(v.x, v.y);
    }
    __syncthreads();
    short8 a = *reinterpret_cast<const short8*>(&At[row0 + lr][lg * 8]);
    f32x4 acc[6];
#pragma unroll
    for (int nt = 0; nt < 6; nt++) {
      short8 b = *reinterpret_cast<const short8*>(&Wt[nt * 16 + lr][lg * 8]);
      acc[nt] = __builtin_amdgcn_mfma_f32_16x16x32_bf16(a, b, (f32x4){0.f, 0.f, 0.f, 0.f}, 0, 0, 0);
    }
#pragma unroll
    for (int nt = 0; nt < 6; nt++) {
      int col = nt * 16 + lr;
      float bias = ebias[col];
#pragma unroll
      for (int j = 0; j < 4; j++) {
        int row = row0 + lg * 4 + j;
        P[row][col] = f2bu(fmaxf(acc[nt][j] + bias, 0.f));
      }
    }
    __syncthreads();   // P complete
    // ownership-partitioned segmented sum: i -> (node nl, col c), rows contiguous in chunk
    for (int i = t; i < ES_NODES * 96; i += 256) {
      int nl = i / 96, c = i - nl * 96;
      int lo = max(rp16[nl] - cs, 0);
      int hi = min(rp16[nl + 1] - cs, m);
      if (lo < hi) {
        float s = 0.f;
        for (int r = lo; r < hi; r++) s += bus(P[r][c]);
        eT[nl][c] += s;                  // exclusive slot, no atomic
      }
    }
    __syncthreads();   // eT updates done before next chunk overwrites At/P
  }
  for (int i = t; i < ES_NODES * 96; i += 256) {
    int nl = i / 96, jj = i - nl * 96;
    int n = n0 + nl;
    if (n < Nn) eSum[(size_t)n * 96 + jj] = eT[nl][jj];
  }
}

// ---------------- node MLP: h16 = relu(x @ W + b), x[N,32] ----------------

__global__ __launch_bounds__(256) void k_node_mlp(const float* __restrict__ x, const float* __restrict__ W,
                                                  const float* __restrict__ b, u16* __restrict__ h16) {
  __shared__ float xs[16][33];
  __shared__ float Ws[32 * 96];
  __shared__ float bs[96];
  int t = threadIdx.x;
  int n0 = blockIdx.x * 16;
  for (int i = t; i < 32 * 96; i += 256) Ws[i] = W[i];
  if (t < 96) bs[t] = b[t];
  for (int i = t; i < 512; i += 256) {
    int nl = i >> 5, k = i & 31; int n = n0 + nl;
    xs[nl][k] = (n < Nn) ? x[n * 32 + k] : 0.f;
  }
  __syncthreads();
#pragma unroll
  for (int p = 0; p < 6; p++) {
    int oi = t + p * 256; int nl = oi / 96, j = oi % 96; int n = n0 + nl;
    if (n < Nn) {
      float acc = bs[j];
#pragma unroll
      for (int k = 0; k < 32; k++) acc += xs[nl][k] * Ws[k * 96 + j];
      h16[(size_t)n * 96 + j] = f2bu(fmaxf(acc, 0.f));
    }
  }
}

// ---------------- FUSED layer kernel: h-gather sum + eSum + MFMA MLP ----------------

#define MPAD 104

#define ACC8H(hv, B) \
  acc[B+0] += blo(hv.x); acc[B+1] += bhi(hv.x); acc[B+2] += blo(hv.y); acc[B+3] += bhi(hv.y); \
  acc[B+4] += blo(hv.z); acc[B+5] += bhi(hv.z); acc[B+6] += blo(hv.w); acc[B+7] += bhi(hv.w);

#define LOADH(hp, H0, H1, H2) \
  uint4 H0 = *reinterpret_cast<const uint4*>(hp); \
  uint4 H1 = *reinterpret_cast<const uint4*>(hp + 8); \
  uint4 H2 = *reinterpret_cast<const uint4*>(hp + 16);

__global__ __launch_bounds__(256) void k_layer(const u16* __restrict__ h16,
                                               const int* __restrict__ srcPerm,
                                               const int* __restrict__ rowptr,
                                               const float* __restrict__ eSum,
                                               const float* __restrict__ W1, const float* __restrict__ b1,
                                               const float* __restrict__ W2, const float* __restrict__ b2,
                                               const float* __restrict__ epsA, int layer,
                                               float* __restrict__ z) {
  __shared__ __align__(16) __hip_bfloat16 At[64][MPAD];   // A-tile, then mid (wave-private rows)
  __shared__ __align__(16) __hip_bfloat16 Wt[96][MPAD];   // Wt[col][k]
  __shared__ int rp[65];
  int t = threadIdx.x;
  int n0 = blockIdx.x * 64;
  if (t < 65) rp[t] = rowptr[min(n0 + t, Nn)];
  __syncthreads();
  float epsv = 1.0f + epsA[layer];
  int nl = t >> 2, q = t & 3;            // node-local, feature-quarter
  int beg = rp[nl], end = rp[nl + 1];
  const size_t fo = (size_t)q * 24;      // feature offset (elements)
  float acc[24];
#pragma unroll
  for (int j = 0; j < 24; j++) acc[j] = 0.f;
  int e = beg;
  for (; e + 4 <= end; e += 4) {
    int s0 = srcPerm[e], s1 = srcPerm[e + 1], s2 = srcPerm[e + 2], s3 = srcPerm[e + 3];
    const u16* hp0 = h16 + (size_t)s0 * 96 + fo;
    const u16* hp1 = h16 + (size_t)s1 * 96 + fo;
    const u16* hp2 = h16 + (size_t)s2 * 96 + fo;
    const u16* hp3 = h16 + (size_t)s3 * 96 + fo;
    LOADH(hp0, ha0, ha1, ha2)
    LOADH(hp1, hb0, hb1, hb2)
    LOADH(hp2, hc0, hc1, hc2)
    LOADH(hp3, hd0, hd1, hd2)
    ACC8H(ha0, 0)
    ACC8H(ha1, 8)
    ACC8H(ha2, 16)
    ACC8H(hb0, 0)
    ACC8H(hb1, 8)
    ACC8H(hb2, 16)
    ACC8H(hc0, 0)
    ACC8H(hc1, 8)
    ACC8H(hc2, 16)
    ACC8H(hd0, 0)
    ACC8H(hd1, 8)
    ACC8H(hd2, 16)
  }
  for (; e < end; e++) {
    int s0 = srcPerm[e];
    const u16* hp0 = h16 + (size_t)s0 * 96 + fo;
    LOADH(hp0, ha0, ha1, ha2)
    ACC8H(ha0, 0)
    ACC8H(ha1, 8)
    ACC8H(ha2, 16)
  }
  {
    int n = n0 + nl;
    uint4 hh0 = make_uint4(0, 0, 0, 0), hh1 = hh0, hh2 = hh0;
    float4 es0 = make_float4(0.f, 0.f, 0.f, 0.f), es1 = es0, es2 = es0, es3 = es0, es4 = es0, es5 = es0;
    if (n < Nn) {
      const u16* hp = h16 + (size_t)n * 96 + fo;
      hh0 = *reinterpret_cast<const uint4*>(hp);
      hh1 = *reinterpret_cast<const uint4*>(hp + 8);
      hh2 = *reinterpret_cast<const uint4*>(hp + 16);
      const float* ep = eSum + (size_t)n * 96 + fo;
      es0 = *reinterpret_cast<const float4*>(ep);
      es1 = *reinterpret_cast<const float4*>(ep + 4);
      es2 = *reinterpret_cast<const float4*>(ep + 8);
      es3 = *reinterpret_cast<const float4*>(ep + 12);
      es4 = *reinterpret_cast<const float4*>(ep + 16);
      es5 = *reinterpret_cast<const float4*>(ep + 20);
    }
    uint4 w0, w1, w2;
    w0.x = pack2(fmaf(epsv, blo(hh0.x), acc[0] + es0.x),  fmaf(epsv, bhi(hh0.x), acc[1] + es0.y));
    w0.y = pack2(fmaf(epsv, blo(hh0.y), acc[2] + es0.z),  fmaf(epsv, bhi(hh0.y), acc[3] + es0.w));
    w0.z = pack2(fmaf(epsv, blo(hh0.z), acc[4] + es1.x),  fmaf(epsv, bhi(hh0.z), acc[5] + es1.y));
    w0.w = pack2(fmaf(epsv, blo(hh0.w), acc[6] + es1.z),  fmaf(epsv, bhi(hh0.w), acc[7] + es1.w));
    w1.x = pack2(fmaf(epsv, blo(hh1.x), acc[8] + es2.x),  fmaf(epsv, bhi(hh1.x), acc[9] + es2.y));
    w1.y = pack2(fmaf(epsv, blo(hh1.y), acc[10] + es2.z), fmaf(epsv, bhi(hh1.y), acc[11] + es2.w));
    w1.z = pack2(fmaf(epsv, blo(hh1.z), acc[12] + es3.x), fmaf(epsv, bhi(hh1.z), acc[13] + es3.y));
    w1.w = pack2(fmaf(epsv, blo(hh1.w), acc[14] + es3.z), fmaf(epsv, bhi(hh1.w), acc[15] + es3.w));
    w2.x = pack2(fmaf(epsv, blo(hh2.x), acc[16] + es4.x), fmaf(epsv, bhi(hh2.x), acc[17] + es4.y));
    w2.y = pack2(fmaf(epsv, blo(hh2.y), acc[18] + es4.z), fmaf(epsv, bhi(hh2.y), acc[19] + es4.w));
    w2.z = pack2(fmaf(epsv, blo(hh2.z), acc[20] + es5.x), fmaf(epsv, bhi(hh2.z), acc[21] + es5.y));
    w2.w = pack2(fmaf(epsv, blo(hh2.w), acc[22] + es5.z), fmaf(epsv, bhi(hh2.w), acc[23] + es5.w));
    *reinterpret_cast<uint4*>(&At[nl][fo]) = w0;
    *reinterpret_cast<uint4*>(&At[nl][fo + 8]) = w1;
    *reinterpret_cast<uint4*>(&At[nl][fo + 16]) = w2;
  }
  // stage W1: k-fast packed writes (c across lanes -> coalesced global reads, uint2 LDS writes)
  for (int i = t; i < 24 * 96; i += 256) {
    int kg = i / 96, c = i - kg * 96;
    int k0 = kg * 4;
    float w0 = W1[(k0 + 0) * 96 + c];
    float w1 = W1[(k0 + 1) * 96 + c];
    float w2 = W1[(k0 + 2) * 96 + c];
    float w3 = W1[(k0 + 3) * 96 + c];
    *reinterpret_cast<uint2*>(&Wt[c][k0]) = make_uint2(pack2(w0, w1), pack2(w2, w3));
  }
  __syncthreads();
  int w = t >> 6, l = t & 63;
  int lr = l & 15, lg = l >> 4;
  int rowBase = w * 16;
  short8 a0 = *reinterpret_cast<const short8*>(&At[rowBase + lr][lg * 8]);
  short8 a1 = *reinterpret_cast<const short8*>(&At[rowBase + lr][32 + lg * 8]);
  short8 a2 = *reinterpret_cast<const short8*>(&At[rowBase + lr][64 + lg * 8]);
  f32x4 gacc[6];
#pragma unroll
  for (int nt = 0; nt < 6; nt++) gacc[nt] = (f32x4){0.f, 0.f, 0.f, 0.f};
#pragma unroll
  for (int nt = 0; nt < 6; nt++) {
    short8 b0 = *reinterpret_cast<const short8*>(&Wt[nt * 16 + lr][lg * 8]);
    short8 bv1 = *reinterpret_cast<const short8*>(&Wt[nt * 16 + lr][32 + lg * 8]);
    short8 bv2 = *reinterpret_cast<const short8*>(&Wt[nt * 16 + lr][64 + lg * 8]);
    gacc[nt] = __builtin_amdgcn_mfma_f32_16x16x32_bf16(a0, b0, gacc[nt], 0, 0, 0);
    gacc[nt] = __builtin_amdgcn_mfma_f32_16x16x32_bf16(a1, bv1, gacc[nt], 0, 0, 0);
    gacc[nt] = __builtin_amdgcn_mfma_f32_16x16x32_bf16(a2, bv2, gacc[nt], 0, 0, 0);
  }
  // mid overwrites A-tile: wave-private rows, a-frags already in registers
#pragma unroll
  for (int nt = 0; nt < 6; nt++) {
    int col = nt * 16 + lr;
    float bias = b1[col];
#pragma unroll
    for (int j = 0; j < 4; j++) {
      int row = rowBase + lg * 4 + j;
      At[row][col] = __float2bfloat16(fmaxf(gacc[nt][j] + bias, 0.f));
    }
  }
  __syncthreads();   // all waves done reading Wt(W1)
  for (int i = t; i < 24 * 96; i += 256) {
    int kg = i / 96, c = i - kg * 96;
    int k0 = kg * 4;
    float w0 = W2[(k0 + 0) * 96 + c];
    float w1 = W2[(k0 + 1) * 96 + c];
    float w2 = W2[(k0 + 2) * 96 + c];
    float w3 = W2[(k0 + 3) * 96 + c];
    *reinterpret_cast<uint2*>(&Wt[c][k0]) = make_uint2(pack2(w0, w1), pack2(w2, w3));
  }
  __syncthreads();
  short8 m0 = *reinterpret_cast<const short8*>(&At[rowBase + lr][lg * 8]);
  short8 m1 = *reinterpret_cast<const short8*>(&At[rowBase + lr][32 + lg * 8]);
  short8 m2 = *reinterpret_cast<const short8*>(&At[rowBase + lr][64 + lg * 8]);
#pragma unroll
  for (int nt = 0; nt < 6; nt++) gacc[nt] = (f32x4){0.f, 0.f, 0.f, 0.f};
#pragma unroll
  for (int nt = 0; nt < 6; nt++) {
    short8 b0 = *reinterpret_cast<const short8*>(&Wt[nt * 16 + lr][lg * 8]);
    short8 bv1 = *reinterpret_cast<const short8*>(&Wt[nt * 16 + lr][32 + lg * 8]);
    short8 bv2 = *reinterpret_cast<const short8*>(&Wt[nt * 16 + lr][64 + lg * 8]);
    gacc[nt] = __builtin_amdgcn_mfma_f32_16x16x32_bf16(m0, b0, gacc[nt], 0, 0, 0);
    gacc[nt] = __builtin_amdgcn_mfma_f32_16x16x32_bf16(m1, bv1, gacc[nt], 0, 0, 0);
    gacc[nt] = __builtin_amdgcn_mfma_f32_16x16x32_bf16(m2, bv2, gacc[nt], 0, 0, 0);
  }
#pragma unroll
  for (int nt = 0; nt < 6; nt++) {
    int col = nt * 16 + lr;
    float bias = b2[col];
#pragma unroll
    for (int j = 0; j < 4; j++) {
      int row = rowBase + lg * 4 + j;
      int n = n0 + row;
      if (n < Nn) z[(size_t)n * 96 + col] = gacc[nt][j] + bias;
    }
  }
}

// ---------------- FUSED GraphNorm: stats + normalize + residual, one block per graph ----------------

__global__ __launch_bounds__(384) void k_gnorm(const float* __restrict__ z, u16* __restrict__ h16,
                                               const int* __restrict__ gptr, const float* __restrict__ ms,
                                               const float* __restrict__ gw, const float* __restrict__ gb) {
  __shared__ float r1[16][100];
  __shared__ float r2[16][100];
  __shared__ float smm[96], sinv[96], sgb[96];
  int g = blockIdx.x, t = threadIdx.x;
  int beg = gptr[g], end = gptr[g + 1];
  int sub = t / 24, slot = t - (t / 24) * 24;
  int sl = slot * 4;
  float4 s1 = make_float4(0.f, 0.f, 0.f, 0.f), s2 = s1;
  for (int n = beg + sub; n < end; n += 16) {
    float4 zv = *reinterpret_cast<const float4*>(z + (size_t)n * 96 + sl);
    s1.x += zv.x; s1.y += zv.y; s1.z += zv.z; s1.w += zv.w;
    s2.x += zv.x * zv.x; s2.y += zv.y * zv.y; s2.z += zv.z * zv.z; s2.w += zv.w * zv.w;
  }
  *reinterpret_cast<float4*>(&r1[sub][sl]) = s1;
  *reinterpret_cast<float4*>(&r2[sub][sl]) = s2;
  __syncthreads();
  if (t < 96) {
    float S1 = 0.f, S2 = 0.f;
#pragma unroll
    for (int u = 0; u < 16; u++) { S1 += r1[u][t]; S2 += r2[u][t]; }
    float c = (float)max(end - beg, 1);
    float m = S1 / c;
    float mm = m * ms[t];
    float var = S2 / c - 2.f * mm * m + mm * mm;
    var = fmaxf(var, 0.f);
    smm[t] = mm;
    sinv[t] = rsqrtf(var + 1e-5f) * gw[t];
    sgb[t] = gb[t];
  }
  __syncthreads();
  float4 mm4 = *reinterpret_cast<const float4*>(&smm[sl]);
  float4 iv4 = *reinterpret_cast<const float4*>(&sinv[sl]);
  float4 gb4 = *reinterpret_cast<const float4*>(&sgb[sl]);
  for (int n = beg + sub; n < end; n += 16) {
    float4 zv = *reinterpret_cast<const float4*>(z + (size_t)n * 96 + sl);
    uint2 hv = *reinterpret_cast<const uint2*>(h16 + (size_t)n * 96 + sl);
    float o0 = fmaxf((zv.x - mm4.x) * iv4.x + gb4.x, 0.f) + blo(hv.x);
    float o1 = fmaxf((zv.y - mm4.y) * iv4.y + gb4.y, 0.f) + bhi(hv.x);
    float o2 = fmaxf((zv.z - mm4.z) * iv4.z + gb4.z, 0.f) + blo(hv.y);
    float o3 = fmaxf((zv.w - mm4.w) * iv4.w + gb4.w, 0.f) + bhi(hv.y);
    *reinterpret_cast<uint2*>(h16 + (size_t)n * 96 + sl) = make_uint2(pack2(o0, o1), pack2(o2, o3));
  }
}

// ---------------- pooling + LayerNorm + output MLP ----------------

__global__ __launch_bounds__(256) void k_pool_out(const u16* __restrict__ h16, const int* __restrict__ gptr,
                                                  const float* __restrict__ lng, const float* __restrict__ lnb,
                                                  const float* __restrict__ W1, const float* __restrict__ b1,
                                                  const float* __restrict__ W2, const float* __restrict__ b2,
                                                  float* __restrict__ out) {
  __shared__ float sh1[2][96], sh2[2][96];
  __shared__ float gbuf[192];
  __shared__ float rs[4], rq[4];
  __shared__ float s_mu, s_rstd;
  __shared__ float inter[96];
  int g = blockIdx.x, t = threadIdx.x;
  int beg = gptr[g], end = gptr[g + 1];
  if (t < 192) {
    int j = t % 96, half = t / 96;
    float s = 0.f, m = -INFINITY;
    for (int n = beg + half; n < end; n += 2) {
      float v = bus(h16[(size_t)n * 96 + j]);
      s += v; m = fmaxf(m, v);
    }
    sh1[half][j] = s; sh2[half][j] = m;
  }
  __syncthreads();
  if (t < 96) {
    float c = (float)max(end - beg, 1);
    gbuf[t] = (sh1[0][t] + sh1[1][t]) / c;
    gbuf[96 + t] = fmaxf(sh2[0][t], sh2[1][t]);
  }
  __syncthreads();
  float sv = (t < 192) ? gbuf[t] : 0.f;
  float qv = sv * sv;
#pragma unroll
  for (int off = 32; off; off >>= 1) { sv += __shfl_down(sv, off); qv += __shfl_down(qv, off); }
  if ((t & 63) == 0) { rs[t >> 6] = sv; rq[t >> 6] = qv; }
  __syncthreads();
  if (t == 0) {
    float S = rs[0] + rs[1] + rs[2] + rs[3];
    float Q = rq[0] + rq[1] + rq[2] + rq[3];
    float mu = S / 192.f;
    float va = Q / 192.f - mu * mu;
    s_mu = mu; s_rstd = rsqrtf(fmaxf(va, 0.f) + 1e-5f);
  }
  __syncthreads();
  if (t < 192) gbuf[t] = (gbuf[t] - s_mu) * s_rstd * lng[t] + lnb[t];
  __syncthreads();
  if (t < 96) {
    float a = b1[t];
    for (int k = 0; k < 192; k++) a += gbuf[k] * W1[k * 96 + t];
    inter[t] = fmaxf(a, 0.f);
  }
  __syncthreads();
  {
    float a = b2[t];
    for (int j = 0; j < 96; j++) a += inter[j] * W2[j * 256 + t];
    out[g * 256 + t] = a;
  }
}

// ---------------- host ----------------

extern "C" void kernel_launch(void* const* d_in, const int* in_sizes, int n_in,
                              void* d_out, int out_size, void* d_ws, size_t ws_size,
                              hipStream_t stream) {
  (void)in_sizes; (void)n_in; (void)out_size; (void)ws_size;
  const float* x     = (const float*)d_in[0];
  const float* eattr = (const float*)d_in[1];
  const int*   eidx2 = (const int*)  d_in[2];
  const int*   batch = (const int*)  d_in[3];
  const float* nodeW = (const float*)d_in[4];
  const float* nodeb = (const float*)d_in[5];
  const float* edgeW = (const float*)d_in[6];
  const float* edgeb = (const float*)d_in[7];
  const float* mlpW1 = (const float*)d_in[8];
  const float* mlpb1 = (const float*)d_in[9];
  const float* mlpW2 = (const float*)d_in[10];
  const float* mlpb2 = (const float*)d_in[11];
  const float* epsA  = (const float*)d_in[12];
  const float* gnw   = (const float*)d_in[13];
  const float* gnb   = (const float*)d_in[14];
  const float* gnms  = (const float*)d_in[15];
  const float* lng   = (const float*)d_in[16];
  const float* lnb   = (const float*)d_in[17];
  const float* oW1   = (const float*)d_in[18];
  const float* ob1   = (const float*)d_in[19];
  const float* oW2   = (const float*)d_in[20];
  const float* ob2   = (const float*)d_in[21];
  float* out = (float*)d_out;

  const int* srcArr = eidx2;        // edge_index[0]
  const int* dstArr = eidx2 + Ee;   // edge_index[1]

  char* p = (char*)d_ws;
  auto carve = [&](size_t bytes) -> void* {
    void* r = (void*)p;
    p += ((bytes + 255) & ~(size_t)255);
    return r;
  };
  // Total ~105 MB.
  u16* h16     = (u16*)carve((size_t)Nn * 96 * 2);     // h state, bf16
  float* aggz  = (float*)carve((size_t)Nn * 96 * 4);   // z (f32)
  float* eSum  = (float*)carve((size_t)Nn * 96 * 4);   // layer-invariant edge-message sums (f32)
  int* rowptr  = (int*)carve((size_t)(Nn + 1) * 4);
  int* elist   = (int*)carve((size_t)Ee * 4);
  int* gptr    = (int*)carve((size_t)(Gg + 1) * 4);
  // srcPerm (Ee ints) doubles as CSR temp space (deg/localA/cursor/bsum, 3*Nn+NB ints < Ee).
  int* srcPerm = (int*)carve((size_t)Ee * 4);
  int* deg     = srcPerm;
  int* localA  = srcPerm + Nn;
  int* cursor  = srcPerm + 2 * Nn;
  int* bsum    = srcPerm + 3 * Nn;

  hipMemsetAsync(deg, 0, (size_t)Nn * 4, stream);
  k_gptr<<<1, 512, 0, stream>>>(batch, gptr);
  k_deg<<<(Ee + 255) / 256, 256, 0, stream>>>(dstArr, deg);
  k_scanA<<<(Nn + 1023) / 1024, 256, 0, stream>>>(deg, localA, bsum);
  k_scanB<<<1, 128, 0, stream>>>(bsum);
  k_scanC<<<(Nn + 255) / 256, 256, 0, stream>>>(localA, bsum, rowptr, cursor);
  k_fill<<<(Ee + 255) / 256, 256, 0, stream>>>(dstArr, cursor, elist);

  // eSum precompute (MFMA + contention-free reduce; also writes srcPerm over dead CSR temps)
  k_esum<<<(Nn + ES_NODES - 1) / ES_NODES, 256, 0, stream>>>(eattr, elist, srcArr, rowptr,
                                                             edgeW, edgeb, srcPerm, eSum);

  k_node_mlp<<<(Nn + 15) / 16, 256, 0, stream>>>(x, nodeW, nodeb, h16);

  for (int i = 0; i < 3; i++) {
    k_layer<<<(Nn + 63) / 64, 256, 0, stream>>>(h16, srcPerm, rowptr, eSum,
                                                mlpW1 + i * 9216, mlpb1 + i * 96,
                                                mlpW2 + i * 9216, mlpb2 + i * 96, epsA, i, aggz);
    k_gnorm<<<Gg, 384, 0, stream>>>(aggz, h16, gptr, gnms + i * 96, gnw + i * 96, gnb + i * 96);
  }

  k_pool_out<<<Gg, 256, 0, stream>>>(h16, gptr, lng, lnb, oW1, ob1, oW2, ob2, out);
}

// Round 18
// 531.728 us; speedup vs baseline: 1.6585x; 1.0208x over previous
//
#include <hip/hip_runtime.h>
#include <hip/hip_bf16.h>
#include <cfloat>

#define Nn 100000
#define Ee 800000
#define Gg 256
// H=96, NI=32, EI=10, OUT=256, L=3

typedef __attribute__((ext_vector_type(8))) short short8;
typedef __attribute__((ext_vector_type(4))) float f32x4;
typedef unsigned short u16;

static __device__ __forceinline__ float blo(unsigned u) { return __builtin_bit_cast(float, u << 16); }
static __device__ __forceinline__ float bhi(unsigned u) { return __builtin_bit_cast(float, u & 0xffff0000u); }
static __device__ __forceinline__ float bus(u16 u) { return __builtin_bit_cast(float, ((unsigned)u) << 16); }
static __device__ __forceinline__ u16 f2bu(float f) {
  __hip_bfloat16 b = __float2bfloat16(f);
  return __builtin_bit_cast(u16, b);
}
static __device__ __forceinline__ unsigned pack2(float lo, float hi) {
  return (unsigned)f2bu(lo) | ((unsigned)f2bu(hi) << 16);
}

// ---------------- CSR build ----------------

__global__ __launch_bounds__(512) void k_gptr(const int* __restrict__ batch, int* __restrict__ gptr) {
  int g = threadIdx.x;
  if (g > Gg) return;
  if (g == Gg) { gptr[Gg] = Nn; return; }
  int lo = 0, hi = Nn;
  while (lo < hi) { int mid = (lo + hi) >> 1; if (batch[mid] < g) lo = mid + 1; else hi = mid; }
  gptr[g] = lo;
}

__global__ __launch_bounds__(256) void k_deg(const int* __restrict__ dst, int* __restrict__ deg) {
  int e = blockIdx.x * 256 + threadIdx.x;
  if (e < Ee) atomicAdd(&deg[dst[e]], 1);
}

__global__ __launch_bounds__(256) void k_scanA(const int* __restrict__ deg, int* __restrict__ localA,
                                               int* __restrict__ bsum) {
  __shared__ int ts[256];
  int t = threadIdx.x, b = blockIdx.x;
  int base = b * 1024 + t * 4;
  int v[4]; int s = 0;
#pragma unroll
  for (int k = 0; k < 4; k++) { int idx = base + k; v[k] = (idx < Nn) ? deg[idx] : 0; s += v[k]; }
  ts[t] = s; __syncthreads();
  for (int off = 1; off < 256; off <<= 1) {
    int y = (t >= off) ? ts[t - off] : 0;
    __syncthreads();
    ts[t] += y;
    __syncthreads();
  }
  int ex = ts[t] - s;
#pragma unroll
  for (int k = 0; k < 4; k++) { int idx = base + k; if (idx < Nn) localA[idx] = ex; ex += v[k]; }
  if (t == 255) bsum[b] = ts[255];
}

__global__ __launch_bounds__(128) void k_scanB(int* __restrict__ bsum) {
  __shared__ int s[128];
  const int NB = (Nn + 1023) / 1024;
  int t = threadIdx.x;
  int v = (t < NB) ? bsum[t] : 0;
  s[t] = v; __syncthreads();
  for (int off = 1; off < 128; off <<= 1) {
    int y = (t >= off) ? s[t - off] : 0;
    __syncthreads();
    s[t] += y;
    __syncthreads();
  }
  if (t < NB) bsum[t] = s[t] - v;   // exclusive
}

__global__ __launch_bounds__(256) void k_scanC(const int* __restrict__ localA, const int* __restrict__ bsum,
                                               int* __restrict__ rowptr, int* __restrict__ cursor) {
  int i = blockIdx.x * 256 + threadIdx.x;
  if (i < Nn) { int v = localA[i] + bsum[i >> 10]; rowptr[i] = v; cursor[i] = v; }
  if (i == 0) rowptr[Nn] = Ee;
}

__global__ __launch_bounds__(256) void k_fill(const int* __restrict__ dst, int* __restrict__ cursor,
                                              int* __restrict__ elist) {
  int e = blockIdx.x * 256 + threadIdx.x;
  if (e < Ee) { int p = atomicAdd(&cursor[dst[e]], 1); elist[p] = e; }
}

// ---------------- eSum precompute v4 (scalar, 2 cols/thread, run-length reg accumulate) ----------------
// eSum[nd] = sum_{e->nd} relu(ea_e@eW+eb). 192 threads = 48 col-pairs x 4 edge-subsets.
// ea broadcast from LDS shared across the 2 cols; weights in 10 float2 regs. dstl monotone
// (dst-sorted elist) -> register accumulator flushed to sub-exclusive eT slot only on dst
// change (carries across chunks). ZERO atomics. Also fills srcPerm[q]=srcArr[elist[q]].

#define ES_NODES 16
#define ES_CHUNK 64

__global__ __launch_bounds__(192) void k_esum(const float* __restrict__ eattr,
                                              const int* __restrict__ elist,
                                              const int* __restrict__ srcArr,
                                              const int* __restrict__ rowptr,
                                              const float* __restrict__ eW,
                                              const float* __restrict__ eb,
                                              int* __restrict__ srcPerm,
                                              float* __restrict__ eSum) {
  __shared__ float ea[ES_CHUNK][10];
  __shared__ int dstl[ES_CHUNK];
  __shared__ float eT[4][ES_NODES][96];
  __shared__ int rp16[ES_NODES + 1];
  int t = threadIdx.x;
  int n0 = blockIdx.x * ES_NODES;
  if (t <= ES_NODES) rp16[t] = rowptr[min(n0 + t, Nn)];
  for (int i = t; i < 4 * ES_NODES * 96; i += 192) ((float*)eT)[i] = 0.f;
  int jp = t % 48, sub = t / 48;         // cols j0, j0+1; edge stride 4
  int j0 = jp * 2;
  float2 wreg[10];
#pragma unroll
  for (int k = 0; k < 10; k++) wreg[k] = *reinterpret_cast<const float2*>(&eW[k * 96 + j0]);
  float2 breg = *reinterpret_cast<const float2*>(&eb[j0]);
  __syncthreads();
  int beg = rp16[0], end = rp16[ES_NODES];
  float raccx = 0.f, raccy = 0.f;
  int rdst = -1;
  for (int cs = beg; cs < end; cs += ES_CHUNK) {
    int m = min(ES_CHUNK, end - cs);
    for (int i = t; i < m; i += 192) {
      int q = cs + i;
      int e = elist[q];
      srcPerm[q] = srcArr[e];
      int lo = 0, hi = ES_NODES - 1;
      while (lo < hi) { int mid = (lo + hi + 1) >> 1; if (rp16[mid] <= q) lo = mid; else hi = mid - 1; }
      dstl[i] = lo;
    }
    for (int i = t; i < 5 * m; i += 192) {
      int ii = i / 5, k2 = (i - ii * 5) * 2;
      int e = elist[cs + ii];            // redundant load, L1-hit
      *reinterpret_cast<float2*>(&ea[ii][k2]) = *reinterpret_cast<const float2*>(&eattr[(size_t)e * 10 + k2]);
    }
    __syncthreads();
    for (int i = sub; i < m; i += 4) {
      float ax = breg.x, ay = breg.y;
#pragma unroll
      for (int k = 0; k < 10; k++) {
        float a = ea[i][k];
        ax += a * wreg[k].x;
        ay += a * wreg[k].y;
      }
      ax = fmaxf(ax, 0.f);
      ay = fmaxf(ay, 0.f);
      int d = dstl[i];
      if (d != rdst) {
        if (rdst >= 0) {
          eT[sub][rdst][j0]     += raccx;
          eT[sub][rdst][j0 + 1] += raccy;
        }
        rdst = d; raccx = ax; raccy = ay;
      } else {
        raccx += ax; raccy += ay;
      }
    }
    __syncthreads();   // accumulate reads of ea/dstl done before next chunk restages
  }
  if (rdst >= 0) {
    eT[sub][rdst][j0]     += raccx;
    eT[sub][rdst][j0 + 1] += raccy;
  }
  __syncthreads();
  for (int i = t; i < ES_NODES * 96; i += 192) {
    int nl = i / 96, jj = i - nl * 96;
    int n = n0 + nl;
    if (n < Nn) eSum[(size_t)n * 96 + jj] = eT[0][nl][jj] + eT[1][nl][jj] + eT[2][nl][jj] + eT[3][nl][jj];
  }
}

// ---------------- node MLP: h16 = relu(x @ W + b), x[N,32] ----------------

__global__ __launch_bounds__(256) void k_node_mlp(const float* __restrict__ x, const float* __restrict__ W,
                                                  const float* __restrict__ b, u16* __restrict__ h16) {
  __shared__ float xs[16][33];
  __shared__ float Ws[32 * 96];
  __shared__ float bs[96];
  int t = threadIdx.x;
  int n0 = blockIdx.x * 16;
  for (int i = t; i < 32 * 96; i += 256) Ws[i] = W[i];
  if (t < 96) bs[t] = b[t];
  for (int i = t; i < 512; i += 256) {
    int nl = i >> 5, k = i & 31; int n = n0 + nl;
    xs[nl][k] = (n < Nn) ? x[n * 32 + k] : 0.f;
  }
  __syncthreads();
#pragma unroll
  for (int p = 0; p < 6; p++) {
    int oi = t + p * 256; int nl = oi / 96, j = oi % 96; int n = n0 + nl;
    if (n < Nn) {
      float acc = bs[j];
#pragma unroll
      for (int k = 0; k < 32; k++) acc += xs[nl][k] * Ws[k * 96 + j];
      h16[(size_t)n * 96 + j] = f2bu(fmaxf(acc, 0.f));
    }
  }
}

// ---------------- FUSED layer kernel: h-gather sum + eSum + MFMA MLP ----------------

#define MPAD 104

#define ACC8H(hv, B) \
  acc[B+0] += blo(hv.x); acc[B+1] += bhi(hv.x); acc[B+2] += blo(hv.y); acc[B+3] += bhi(hv.y); \
  acc[B+4] += blo(hv.z); acc[B+5] += bhi(hv.z); acc[B+6] += blo(hv.w); acc[B+7] += bhi(hv.w);

#define LOADH(hp, H0, H1, H2) \
  uint4 H0 = *reinterpret_cast<const uint4*>(hp); \
  uint4 H1 = *reinterpret_cast<const uint4*>(hp + 8); \
  uint4 H2 = *reinterpret_cast<const uint4*>(hp + 16);

__global__ __launch_bounds__(256) void k_layer(const u16* __restrict__ h16,
                                               const int* __restrict__ srcPerm,
                                               const int* __restrict__ rowptr,
                                               const float* __restrict__ eSum,
                                               const float* __restrict__ W1, const float* __restrict__ b1,
                                               const float* __restrict__ W2, const float* __restrict__ b2,
                                               const float* __restrict__ epsA, int layer,
                                               float* __restrict__ z) {
  __shared__ __align__(16) __hip_bfloat16 At[64][MPAD];   // A-tile, then mid (wave-private rows)
  __shared__ __align__(16) __hip_bfloat16 Wt[96][MPAD];   // Wt[col][k]
  __shared__ int rp[65];
  int t = threadIdx.x;
  int n0 = blockIdx.x * 64;
  if (t < 65) rp[t] = rowptr[min(n0 + t, Nn)];
  __syncthreads();
  float epsv = 1.0f + epsA[layer];
  int nl = t >> 2, q = t & 3;            // node-local, feature-quarter
  int beg = rp[nl], end = rp[nl + 1];
  const size_t fo = (size_t)q * 24;      // feature offset (elements)
  float acc[24];
#pragma unroll
  for (int j = 0; j < 24; j++) acc[j] = 0.f;
  int e = beg;
  for (; e + 4 <= end; e += 4) {
    int s0 = srcPerm[e], s1 = srcPerm[e + 1], s2 = srcPerm[e + 2], s3 = srcPerm[e + 3];
    const u16* hp0 = h16 + (size_t)s0 * 96 + fo;
    const u16* hp1 = h16 + (size_t)s1 * 96 + fo;
    const u16* hp2 = h16 + (size_t)s2 * 96 + fo;
    const u16* hp3 = h16 + (size_t)s3 * 96 + fo;
    LOADH(hp0, ha0, ha1, ha2)
    LOADH(hp1, hb0, hb1, hb2)
    LOADH(hp2, hc0, hc1, hc2)
    LOADH(hp3, hd0, hd1, hd2)
    ACC8H(ha0, 0)
    ACC8H(ha1, 8)
    ACC8H(ha2, 16)
    ACC8H(hb0, 0)
    ACC8H(hb1, 8)
    ACC8H(hb2, 16)
    ACC8H(hc0, 0)
    ACC8H(hc1, 8)
    ACC8H(hc2, 16)
    ACC8H(hd0, 0)
    ACC8H(hd1, 8)
    ACC8H(hd2, 16)
  }
  for (; e < end; e++) {
    int s0 = srcPerm[e];
    const u16* hp0 = h16 + (size_t)s0 * 96 + fo;
    LOADH(hp0, ha0, ha1, ha2)
    ACC8H(ha0, 0)
    ACC8H(ha1, 8)
    ACC8H(ha2, 16)
  }
  {
    int n = n0 + nl;
    uint4 hh0 = make_uint4(0, 0, 0, 0), hh1 = hh0, hh2 = hh0;
    float4 es0 = make_float4(0.f, 0.f, 0.f, 0.f), es1 = es0, es2 = es0, es3 = es0, es4 = es0, es5 = es0;
    if (n < Nn) {
      const u16* hp = h16 + (size_t)n * 96 + fo;
      hh0 = *reinterpret_cast<const uint4*>(hp);
      hh1 = *reinterpret_cast<const uint4*>(hp + 8);
      hh2 = *reinterpret_cast<const uint4*>(hp + 16);
      const float* ep = eSum + (size_t)n * 96 + fo;
      es0 = *reinterpret_cast<const float4*>(ep);
      es1 = *reinterpret_cast<const float4*>(ep + 4);
      es2 = *reinterpret_cast<const float4*>(ep + 8);
      es3 = *reinterpret_cast<const float4*>(ep + 12);
      es4 = *reinterpret_cast<const float4*>(ep + 16);
      es5 = *reinterpret_cast<const float4*>(ep + 20);
    }
    uint4 w0, w1, w2;
    w0.x = pack2(fmaf(epsv, blo(hh0.x), acc[0] + es0.x),  fmaf(epsv, bhi(hh0.x), acc[1] + es0.y));
    w0.y = pack2(fmaf(epsv, blo(hh0.y), acc[2] + es0.z),  fmaf(epsv, bhi(hh0.y), acc[3] + es0.w));
    w0.z = pack2(fmaf(epsv, blo(hh0.z), acc[4] + es1.x),  fmaf(epsv, bhi(hh0.z), acc[5] + es1.y));
    w0.w = pack2(fmaf(epsv, blo(hh0.w), acc[6] + es1.z),  fmaf(epsv, bhi(hh0.w), acc[7] + es1.w));
    w1.x = pack2(fmaf(epsv, blo(hh1.x), acc[8] + es2.x),  fmaf(epsv, bhi(hh1.x), acc[9] + es2.y));
    w1.y = pack2(fmaf(epsv, blo(hh1.y), acc[10] + es2.z), fmaf(epsv, bhi(hh1.y), acc[11] + es2.w));
    w1.z = pack2(fmaf(epsv, blo(hh1.z), acc[12] + es3.x), fmaf(epsv, bhi(hh1.z), acc[13] + es3.y));
    w1.w = pack2(fmaf(epsv, blo(hh1.w), acc[14] + es3.z), fmaf(epsv, bhi(hh1.w), acc[15] + es3.w));
    w2.x = pack2(fmaf(epsv, blo(hh2.x), acc[16] + es4.x), fmaf(epsv, bhi(hh2.x), acc[17] + es4.y));
    w2.y = pack2(fmaf(epsv, blo(hh2.y), acc[18] + es4.z), fmaf(epsv, bhi(hh2.y), acc[19] + es4.w));
    w2.z = pack2(fmaf(epsv, blo(hh2.z), acc[20] + es5.x), fmaf(epsv, bhi(hh2.z), acc[21] + es5.y));
    w2.w = pack2(fmaf(epsv, blo(hh2.w), acc[22] + es5.z), fmaf(epsv, bhi(hh2.w), acc[23] + es5.w));
    *reinterpret_cast<uint4*>(&At[nl][fo]) = w0;
    *reinterpret_cast<uint4*>(&At[nl][fo + 8]) = w1;
    *reinterpret_cast<uint4*>(&At[nl][fo + 16]) = w2;
  }
  // stage W1: k-fast packed writes (c across lanes -> coalesced global reads, uint2 LDS writes)
  for (int i = t; i < 24 * 96; i += 256) {
    int kg = i / 96, c = i - kg * 96;
    int k0 = kg * 4;
    float w0 = W1[(k0 + 0) * 96 + c];
    float w1 = W1[(k0 + 1) * 96 + c];
    float w2 = W1[(k0 + 2) * 96 + c];
    float w3 = W1[(k0 + 3) * 96 + c];
    *reinterpret_cast<uint2*>(&Wt[c][k0]) = make_uint2(pack2(w0, w1), pack2(w2, w3));
  }
  __syncthreads();
  int w = t >> 6, l = t & 63;
  int lr = l & 15, lg = l >> 4;
  int rowBase = w * 16;
  short8 a0 = *reinterpret_cast<const short8*>(&At[rowBase + lr][lg * 8]);
  short8 a1 = *reinterpret_cast<const short8*>(&At[rowBase + lr][32 + lg * 8]);
  short8 a2 = *reinterpret_cast<const short8*>(&At[rowBase + lr][64 + lg * 8]);
  f32x4 gacc[6];
#pragma unroll
  for (int nt = 0; nt < 6; nt++) gacc[nt] = (f32x4){0.f, 0.f, 0.f, 0.f};
#pragma unroll
  for (int nt = 0; nt < 6; nt++) {
    short8 b0 = *reinterpret_cast<const short8*>(&Wt[nt * 16 + lr][lg * 8]);
    short8 bv1 = *reinterpret_cast<const short8*>(&Wt[nt * 16 + lr][32 + lg * 8]);
    short8 bv2 = *reinterpret_cast<const short8*>(&Wt[nt * 16 + lr][64 + lg * 8]);
    gacc[nt] = __builtin_amdgcn_mfma_f32_16x16x32_bf16(a0, b0, gacc[nt], 0, 0, 0);
    gacc[nt] = __builtin_amdgcn_mfma_f32_16x16x32_bf16(a1, bv1, gacc[nt], 0, 0, 0);
    gacc[nt] = __builtin_amdgcn_mfma_f32_16x16x32_bf16(a2, bv2, gacc[nt], 0, 0, 0);
  }
  // mid overwrites A-tile: wave-private rows, a-frags already in registers
#pragma unroll
  for (int nt = 0; nt < 6; nt++) {
    int col = nt * 16 + lr;
    float bias = b1[col];
#pragma unroll
    for (int j = 0; j < 4; j++) {
      int row = rowBase + lg * 4 + j;
      At[row][col] = __float2bfloat16(fmaxf(gacc[nt][j] + bias, 0.f));
    }
  }
  __syncthreads();   // all waves done reading Wt(W1)
  for (int i = t; i < 24 * 96; i += 256) {
    int kg = i / 96, c = i - kg * 96;
    int k0 = kg * 4;
    float w0 = W2[(k0 + 0) * 96 + c];
    float w1 = W2[(k0 + 1) * 96 + c];
    float w2 = W2[(k0 + 2) * 96 + c];
    float w3 = W2[(k0 + 3) * 96 + c];
    *reinterpret_cast<uint2*>(&Wt[c][k0]) = make_uint2(pack2(w0, w1), pack2(w2, w3));
  }
  __syncthreads();
  short8 m0 = *reinterpret_cast<const short8*>(&At[rowBase + lr][lg * 8]);
  short8 m1 = *reinterpret_cast<const short8*>(&At[rowBase + lr][32 + lg * 8]);
  short8 m2 = *reinterpret_cast<const short8*>(&At[rowBase + lr][64 + lg * 8]);
#pragma unroll
  for (int nt = 0; nt < 6; nt++) gacc[nt] = (f32x4){0.f, 0.f, 0.f, 0.f};
#pragma unroll
  for (int nt = 0; nt < 6; nt++) {
    short8 b0 = *reinterpret_cast<const short8*>(&Wt[nt * 16 + lr][lg * 8]);
    short8 bv1 = *reinterpret_cast<const short8*>(&Wt[nt * 16 + lr][32 + lg * 8]);
    short8 bv2 = *reinterpret_cast<const short8*>(&Wt[nt * 16 + lr][64 + lg * 8]);
    gacc[nt] = __builtin_amdgcn_mfma_f32_16x16x32_bf16(m0, b0, gacc[nt], 0, 0, 0);
    gacc[nt] = __builtin_amdgcn_mfma_f32_16x16x32_bf16(m1, bv1, gacc[nt], 0, 0, 0);
    gacc[nt] = __builtin_amdgcn_mfma_f32_16x16x32_bf16(m2, bv2, gacc[nt], 0, 0, 0);
  }
#pragma unroll
  for (int nt = 0; nt < 6; nt++) {
    int col = nt * 16 + lr;
    float bias = b2[col];
#pragma unroll
    for (int j = 0; j < 4; j++) {
      int row = rowBase + lg * 4 + j;
      int n = n0 + row;
      if (n < Nn) z[(size_t)n * 96 + col] = gacc[nt][j] + bias;
    }
  }
}

// ---------------- FUSED GraphNorm: stats + normalize + residual, one block per graph ----------------

__global__ __launch_bounds__(384) void k_gnorm(const float* __restrict__ z, u16* __restrict__ h16,
                                               const int* __restrict__ gptr, const float* __restrict__ ms,
                                               const float* __restrict__ gw, const float* __restrict__ gb) {
  __shared__ float r1[16][100];
  __shared__ float r2[16][100];
  __shared__ float smm[96], sinv[96], sgb[96];
  int g = blockIdx.x, t = threadIdx.x;
  int beg = gptr[g], end = gptr[g + 1];
  int sub = t / 24, slot = t - (t / 24) * 24;
  int sl = slot * 4;
  float4 s1 = make_float4(0.f, 0.f, 0.f, 0.f), s2 = s1;
  for (int n = beg + sub; n < end; n += 16) {
    float4 zv = *reinterpret_cast<const float4*>(z + (size_t)n * 96 + sl);
    s1.x += zv.x; s1.y += zv.y; s1.z += zv.z; s1.w += zv.w;
    s2.x += zv.x * zv.x; s2.y += zv.y * zv.y; s2.z += zv.z * zv.z; s2.w += zv.w * zv.w;
  }
  *reinterpret_cast<float4*>(&r1[sub][sl]) = s1;
  *reinterpret_cast<float4*>(&r2[sub][sl]) = s2;
  __syncthreads();
  if (t < 96) {
    float S1 = 0.f, S2 = 0.f;
#pragma unroll
    for (int u = 0; u < 16; u++) { S1 += r1[u][t]; S2 += r2[u][t]; }
    float c = (float)max(end - beg, 1);
    float m = S1 / c;
    float mm = m * ms[t];
    float var = S2 / c - 2.f * mm * m + mm * mm;
    var = fmaxf(var, 0.f);
    smm[t] = mm;
    sinv[t] = rsqrtf(var + 1e-5f) * gw[t];
    sgb[t] = gb[t];
  }
  __syncthreads();
  float4 mm4 = *reinterpret_cast<const float4*>(&smm[sl]);
  float4 iv4 = *reinterpret_cast<const float4*>(&sinv[sl]);
  float4 gb4 = *reinterpret_cast<const float4*>(&sgb[sl]);
  for (int n = beg + sub; n < end; n += 16) {
    float4 zv = *reinterpret_cast<const float4*>(z + (size_t)n * 96 + sl);
    uint2 hv = *reinterpret_cast<const uint2*>(h16 + (size_t)n * 96 + sl);
    float o0 = fmaxf((zv.x - mm4.x) * iv4.x + gb4.x, 0.f) + blo(hv.x);
    float o1 = fmaxf((zv.y - mm4.y) * iv4.y + gb4.y, 0.f) + bhi(hv.x);
    float o2 = fmaxf((zv.z - mm4.z) * iv4.z + gb4.z, 0.f) + blo(hv.y);
    float o3 = fmaxf((zv.w - mm4.w) * iv4.w + gb4.w, 0.f) + bhi(hv.y);
    *reinterpret_cast<uint2*>(h16 + (size_t)n * 96 + sl) = make_uint2(pack2(o0, o1), pack2(o2, o3));
  }
}

// ---------------- pooling + LayerNorm + output MLP ----------------

__global__ __launch_bounds__(256) void k_pool_out(const u16* __restrict__ h16, const int* __restrict__ gptr,
                                                  const float* __restrict__ lng, const float* __restrict__ lnb,
                                                  const float* __restrict__ W1, const float* __restrict__ b1,
                                                  const float* __restrict__ W2, const float* __restrict__ b2,
                                                  float* __restrict__ out) {
  __shared__ float sh1[2][96], sh2[2][96];
  __shared__ float gbuf[192];
  __shared__ float rs[4], rq[4];
  __shared__ float s_mu, s_rstd;
  __shared__ float inter[96];
  int g = blockIdx.x, t = threadIdx.x;
  int beg = gptr[g], end = gptr[g + 1];
  if (t < 192) {
    int j = t % 96, half = t / 96;
    float s = 0.f, m = -INFINITY;
    for (int n = beg + half; n < end; n += 2) {
      float v = bus(h16[(size_t)n * 96 + j]);
      s += v; m = fmaxf(m, v);
    }
    sh1[half][j] = s; sh2[half][j] = m;
  }
  __syncthreads();
  if (t < 96) {
    float c = (float)max(end - beg, 1);
    gbuf[t] = (sh1[0][t] + sh1[1][t]) / c;
    gbuf[96 + t] = fmaxf(sh2[0][t], sh2[1][t]);
  }
  __syncthreads();
  float sv = (t < 192) ? gbuf[t] : 0.f;
  float qv = sv * sv;
#pragma unroll
  for (int off = 32; off; off >>= 1) { sv += __shfl_down(sv, off); qv += __shfl_down(qv, off); }
  if ((t & 63) == 0) { rs[t >> 6] = sv; rq[t >> 6] = qv; }
  __syncthreads();
  if (t == 0) {
    float S = rs[0] + rs[1] + rs[2] + rs[3];
    float Q = rq[0] + rq[1] + rq[2] + rq[3];
    float mu = S / 192.f;
    float va = Q / 192.f - mu * mu;
    s_mu = mu; s_rstd = rsqrtf(fmaxf(va, 0.f) + 1e-5f);
  }
  __syncthreads();
  if (t < 192) gbuf[t] = (gbuf[t] - s_mu) * s_rstd * lng[t] + lnb[t];
  __syncthreads();
  if (t < 96) {
    float a = b1[t];
    for (int k = 0; k < 192; k++) a += gbuf[k] * W1[k * 96 + t];
    inter[t] = fmaxf(a, 0.f);
  }
  __syncthreads();
  {
    float a = b2[t];
    for (int j = 0; j < 96; j++) a += inter[j] * W2[j * 256 + t];
    out[g * 256 + t] = a;
  }
}

// ---------------- host ----------------

extern "C" void kernel_launch(void* const* d_in, const int* in_sizes, int n_in,
                              void* d_out, int out_size, void* d_ws, size_t ws_size,
                              hipStream_t stream) {
  (void)in_sizes; (void)n_in; (void)out_size; (void)ws_size;
  const float* x     = (const float*)d_in[0];
  const float* eattr = (const float*)d_in[1];
  const int*   eidx2 = (const int*)  d_in[2];
  const int*   batch = (const int*)  d_in[3];
  const float* nodeW = (const float*)d_in[4];
  const float* nodeb = (const float*)d_in[5];
  const float* edgeW = (const float*)d_in[6];
  const float* edgeb = (const float*)d_in[7];
  const float* mlpW1 = (const float*)d_in[8];
  const float* mlpb1 = (const float*)d_in[9];
  const float* mlpW2 = (const float*)d_in[10];
  const float* mlpb2 = (const float*)d_in[11];
  const float* epsA  = (const float*)d_in[12];
  const float* gnw   = (const float*)d_in[13];
  const float* gnb   = (const float*)d_in[14];
  const float* gnms  = (const float*)d_in[15];
  const float* lng   = (const float*)d_in[16];
  const float* lnb   = (const float*)d_in[17];
  const float* oW1   = (const float*)d_in[18];
  const float* ob1   = (const float*)d_in[19];
  const float* oW2   = (const float*)d_in[20];
  const float* ob2   = (const float*)d_in[21];
  float* out = (float*)d_out;

  const int* srcArr = eidx2;        // edge_index[0]
  const int* dstArr = eidx2 + Ee;   // edge_index[1]

  char* p = (char*)d_ws;
  auto carve = [&](size_t bytes) -> void* {
    void* r = (void*)p;
    p += ((bytes + 255) & ~(size_t)255);
    return r;
  };
  // Total ~105 MB.
  u16* h16     = (u16*)carve((size_t)Nn * 96 * 2);     // h state, bf16
  float* aggz  = (float*)carve((size_t)Nn * 96 * 4);   // z (f32)
  float* eSum  = (float*)carve((size_t)Nn * 96 * 4);   // layer-invariant edge-message sums (f32)
  int* rowptr  = (int*)carve((size_t)(Nn + 1) * 4);
  int* elist   = (int*)carve((size_t)Ee * 4);
  int* gptr    = (int*)carve((size_t)(Gg + 1) * 4);
  // srcPerm (Ee ints) doubles as CSR temp space (deg/localA/cursor/bsum, 3*Nn+NB ints < Ee).
  int* srcPerm = (int*)carve((size_t)Ee * 4);
  int* deg     = srcPerm;
  int* localA  = srcPerm + Nn;
  int* cursor  = srcPerm + 2 * Nn;
  int* bsum    = srcPerm + 3 * Nn;

  hipMemsetAsync(deg, 0, (size_t)Nn * 4, stream);
  k_gptr<<<1, 512, 0, stream>>>(batch, gptr);
  k_deg<<<(Ee + 255) / 256, 256, 0, stream>>>(dstArr, deg);
  k_scanA<<<(Nn + 1023) / 1024, 256, 0, stream>>>(deg, localA, bsum);
  k_scanB<<<1, 128, 0, stream>>>(bsum);
  k_scanC<<<(Nn + 255) / 256, 256, 0, stream>>>(localA, bsum, rowptr, cursor);
  k_fill<<<(Ee + 255) / 256, 256, 0, stream>>>(dstArr, cursor, elist);

  // eSum precompute (scalar v4; also writes srcPerm over dead CSR temps)
  k_esum<<<(Nn + ES_NODES - 1) / ES_NODES, 192, 0, stream>>>(eattr, elist, srcArr, rowptr,
                                                             edgeW, edgeb, srcPerm, eSum);

  k_node_mlp<<<(Nn + 15) / 16, 256, 0, stream>>>(x, nodeW, nodeb, h16);

  for (int i = 0; i < 3; i++) {
    k_layer<<<(Nn + 63) / 64, 256, 0, stream>>>(h16, srcPerm, rowptr, eSum,
                                                mlpW1 + i * 9216, mlpb1 + i * 96,
                                                mlpW2 + i * 9216, mlpb2 + i * 96, epsA, i, aggz);
    k_gnorm<<<Gg, 384, 0, stream>>>(aggz, h16, gptr, gnms + i * 96, gnw + i * 96, gnb + i * 96);
  }

  k_pool_out<<<Gg, 256, 0, stream>>>(h16, gptr, lng, lnb, oW1, ob1, oW2, ob2, out);
}

// Round 19
// 509.286 us; speedup vs baseline: 1.7316x; 1.0441x over previous
//
#include <hip/hip_runtime.h>
#include <hip/hip_bf16.h>
#include <cfloat>

#define Nn 100000
#define Ee 800000
#define Gg 256
// H=96, NI=32, EI=10, OUT=256, L=3

typedef __attribute__((ext_vector_type(8))) short short8;
typedef __attribute__((ext_vector_type(4))) float f32x4;
typedef unsigned short u16;

static __device__ __forceinline__ float blo(unsigned u) { return __builtin_bit_cast(float, u << 16); }
static __device__ __forceinline__ float bhi(unsigned u) { return __builtin_bit_cast(float, u & 0xffff0000u); }
static __device__ __forceinline__ float bus(u16 u) { return __builtin_bit_cast(float, ((unsigned)u) << 16); }
static __device__ __forceinline__ u16 f2bu(float f) {
  __hip_bfloat16 b = __float2bfloat16(f);
  return __builtin_bit_cast(u16, b);
}
static __device__ __forceinline__ unsigned pack2(float lo, float hi) {
  return (unsigned)f2bu(lo) | ((unsigned)f2bu(hi) << 16);
}

// ---------------- CSR build ----------------

__global__ __launch_bounds__(512) void k_gptr(const int* __restrict__ batch, int* __restrict__ gptr) {
  int g = threadIdx.x;
  if (g > Gg) return;
  if (g == Gg) { gptr[Gg] = Nn; return; }
  int lo = 0, hi = Nn;
  while (lo < hi) { int mid = (lo + hi) >> 1; if (batch[mid] < g) lo = mid + 1; else hi = mid; }
  gptr[g] = lo;
}

__global__ __launch_bounds__(256) void k_deg(const int* __restrict__ dst, int* __restrict__ deg) {
  int e = blockIdx.x * 256 + threadIdx.x;
  if (e < Ee) atomicAdd(&deg[dst[e]], 1);
}

__global__ __launch_bounds__(256) void k_scanA(const int* __restrict__ deg, int* __restrict__ localA,
                                               int* __restrict__ bsum) {
  __shared__ int ts[256];
  int t = threadIdx.x, b = blockIdx.x;
  int base = b * 1024 + t * 4;
  int v[4]; int s = 0;
#pragma unroll
  for (int k = 0; k < 4; k++) { int idx = base + k; v[k] = (idx < Nn) ? deg[idx] : 0; s += v[k]; }
  ts[t] = s; __syncthreads();
  for (int off = 1; off < 256; off <<= 1) {
    int y = (t >= off) ? ts[t - off] : 0;
    __syncthreads();
    ts[t] += y;
    __syncthreads();
  }
  int ex = ts[t] - s;
#pragma unroll
  for (int k = 0; k < 4; k++) { int idx = base + k; if (idx < Nn) localA[idx] = ex; ex += v[k]; }
  if (t == 255) bsum[b] = ts[255];
}

__global__ __launch_bounds__(128) void k_scanB(int* __restrict__ bsum) {
  __shared__ int s[128];
  const int NB = (Nn + 1023) / 1024;
  int t = threadIdx.x;
  int v = (t < NB) ? bsum[t] : 0;
  s[t] = v; __syncthreads();
  for (int off = 1; off < 128; off <<= 1) {
    int y = (t >= off) ? s[t - off] : 0;
    __syncthreads();
    s[t] += y;
    __syncthreads();
  }
  if (t < NB) bsum[t] = s[t] - v;   // exclusive
}

__global__ __launch_bounds__(256) void k_scanC(const int* __restrict__ localA, const int* __restrict__ bsum,
                                               int* __restrict__ rowptr, int* __restrict__ cursor) {
  int i = blockIdx.x * 256 + threadIdx.x;
  if (i < Nn) { int v = localA[i] + bsum[i >> 10]; rowptr[i] = v; cursor[i] = v; }
  if (i == 0) rowptr[Nn] = Ee;
}

__global__ __launch_bounds__(256) void k_fill(const int* __restrict__ dst, int* __restrict__ cursor,
                                              int* __restrict__ elist) {
  int e = blockIdx.x * 256 + threadIdx.x;
  if (e < Ee) { int p = atomicAdd(&cursor[dst[e]], 1); elist[p] = e; }
}

// ---------------- eSum precompute v5 (scalar 2 cols/thread, run-length regs, ES_NODES=8) ----------------
// eSum[nd] = sum_{e->nd} relu(ea_e@eW+eb). LDS ~15KB -> 10 blocks/CU (30 waves) to hide the
// random 40B eattr gather latency. 192 threads = 48 col-pairs x 4 edge-subsets; run-length
// register accumulation into sub-exclusive eT slots (zero atomics). Fills srcPerm too.

#define ES_NODES 8
#define ES_CHUNK 64

__global__ __launch_bounds__(192) void k_esum(const float* __restrict__ eattr,
                                              const int* __restrict__ elist,
                                              const int* __restrict__ srcArr,
                                              const int* __restrict__ rowptr,
                                              const float* __restrict__ eW,
                                              const float* __restrict__ eb,
                                              int* __restrict__ srcPerm,
                                              float* __restrict__ eSum) {
  __shared__ float ea[ES_CHUNK][10];
  __shared__ int dstl[ES_CHUNK];
  __shared__ float eT[4][ES_NODES][96];
  __shared__ int rp16[ES_NODES + 1];
  int t = threadIdx.x;
  int n0 = blockIdx.x * ES_NODES;
  if (t <= ES_NODES) rp16[t] = rowptr[min(n0 + t, Nn)];
  for (int i = t; i < 4 * ES_NODES * 96; i += 192) ((float*)eT)[i] = 0.f;
  int jp = t % 48, sub = t / 48;         // cols j0, j0+1; edge stride 4
  int j0 = jp * 2;
  float2 wreg[10];
#pragma unroll
  for (int k = 0; k < 10; k++) wreg[k] = *reinterpret_cast<const float2*>(&eW[k * 96 + j0]);
  float2 breg = *reinterpret_cast<const float2*>(&eb[j0]);
  __syncthreads();
  int beg = rp16[0], end = rp16[ES_NODES];
  float raccx = 0.f, raccy = 0.f;
  int rdst = -1;
  for (int cs = beg; cs < end; cs += ES_CHUNK) {
    int m = min(ES_CHUNK, end - cs);
    for (int i = t; i < m; i += 192) {
      int q = cs + i;
      int e = elist[q];
      srcPerm[q] = srcArr[e];
      int lo = 0, hi = ES_NODES - 1;
      while (lo < hi) { int mid = (lo + hi + 1) >> 1; if (rp16[mid] <= q) lo = mid; else hi = mid - 1; }
      dstl[i] = lo;
    }
    for (int i = t; i < 5 * m; i += 192) {
      int ii = i / 5, k2 = (i - ii * 5) * 2;
      int e = elist[cs + ii];            // redundant load, L1-hit
      *reinterpret_cast<float2*>(&ea[ii][k2]) = *reinterpret_cast<const float2*>(&eattr[(size_t)e * 10 + k2]);
    }
    __syncthreads();
    for (int i = sub; i < m; i += 4) {
      float ax = breg.x, ay = breg.y;
#pragma unroll
      for (int k = 0; k < 10; k++) {
        float a = ea[i][k];
        ax += a * wreg[k].x;
        ay += a * wreg[k].y;
      }
      ax = fmaxf(ax, 0.f);
      ay = fmaxf(ay, 0.f);
      int d = dstl[i];
      if (d != rdst) {
        if (rdst >= 0) {
          eT[sub][rdst][j0]     += raccx;
          eT[sub][rdst][j0 + 1] += raccy;
        }
        rdst = d; raccx = ax; raccy = ay;
      } else {
        raccx += ax; raccy += ay;
      }
    }
    __syncthreads();   // accumulate reads of ea/dstl done before next chunk restages
  }
  if (rdst >= 0) {
    eT[sub][rdst][j0]     += raccx;
    eT[sub][rdst][j0 + 1] += raccy;
  }
  __syncthreads();
  for (int i = t; i < ES_NODES * 96; i += 192) {
    int nl = i / 96, jj = i - nl * 96;
    int n = n0 + nl;
    if (n < Nn) eSum[(size_t)n * 96 + jj] = eT[0][nl][jj] + eT[1][nl][jj] + eT[2][nl][jj] + eT[3][nl][jj];
  }
}

// ---------------- node MLP: h16 = relu(x @ W + b), x[N,32] ----------------

__global__ __launch_bounds__(256) void k_node_mlp(const float* __restrict__ x, const float* __restrict__ W,
                                                  const float* __restrict__ b, u16* __restrict__ h16) {
  __shared__ float xs[16][33];
  __shared__ float Ws[32 * 96];
  __shared__ float bs[96];
  int t = threadIdx.x;
  int n0 = blockIdx.x * 16;
  for (int i = t; i < 32 * 96; i += 256) Ws[i] = W[i];
  if (t < 96) bs[t] = b[t];
  for (int i = t; i < 512; i += 256) {
    int nl = i >> 5, k = i & 31; int n = n0 + nl;
    xs[nl][k] = (n < Nn) ? x[n * 32 + k] : 0.f;
  }
  __syncthreads();
#pragma unroll
  for (int p = 0; p < 6; p++) {
    int oi = t + p * 256; int nl = oi / 96, j = oi % 96; int n = n0 + nl;
    if (n < Nn) {
      float acc = bs[j];
#pragma unroll
      for (int k = 0; k < 32; k++) acc += xs[nl][k] * Ws[k * 96 + j];
      h16[(size_t)n * 96 + j] = f2bu(fmaxf(acc, 0.f));
    }
  }
}

// ---------------- FUSED layer kernel: h-gather sum + eSum + MFMA MLP ----------------

#define MPAD 104

#define ACC8H(hv, B) \
  acc[B+0] += blo(hv.x); acc[B+1] += bhi(hv.x); acc[B+2] += blo(hv.y); acc[B+3] += bhi(hv.y); \
  acc[B+4] += blo(hv.z); acc[B+5] += bhi(hv.z); acc[B+6] += blo(hv.w); acc[B+7] += bhi(hv.w);

#define LOADH(hp, H0, H1, H2) \
  uint4 H0 = *reinterpret_cast<const uint4*>(hp); \
  uint4 H1 = *reinterpret_cast<const uint4*>(hp + 8); \
  uint4 H2 = *reinterpret_cast<const uint4*>(hp + 16);

__global__ __launch_bounds__(256) void k_layer(const u16* __restrict__ h16,
                                               const int* __restrict__ srcPerm,
                                               const int* __restrict__ rowptr,
                                               const float* __restrict__ eSum,
                                               const float* __restrict__ W1, const float* __restrict__ b1,
                                               const float* __restrict__ W2, const float* __restrict__ b2,
                                               const float* __restrict__ epsA, int layer,
                                               float* __restrict__ z) {
  __shared__ __align__(16) __hip_bfloat16 At[64][MPAD];   // A-tile, then mid (wave-private rows)
  __shared__ __align__(16) __hip_bfloat16 Wt[96][MPAD];   // Wt[col][k]
  __shared__ int rp[65];
  int t = threadIdx.x;
  int n0 = blockIdx.x * 64;
  if (t < 65) rp[t] = rowptr[min(n0 + t, Nn)];
  __syncthreads();
  float epsv = 1.0f + epsA[layer];
  int nl = t >> 2, q = t & 3;            // node-local, feature-quarter
  int beg = rp[nl], end = rp[nl + 1];
  const size_t fo = (size_t)q * 24;      // feature offset (elements)
  float acc[24];
#pragma unroll
  for (int j = 0; j < 24; j++) acc[j] = 0.f;
  int e = beg;
  for (; e + 4 <= end; e += 4) {
    int s0 = srcPerm[e], s1 = srcPerm[e + 1], s2 = srcPerm[e + 2], s3 = srcPerm[e + 3];
    const u16* hp0 = h16 + (size_t)s0 * 96 + fo;
    const u16* hp1 = h16 + (size_t)s1 * 96 + fo;
    const u16* hp2 = h16 + (size_t)s2 * 96 + fo;
    const u16* hp3 = h16 + (size_t)s3 * 96 + fo;
    LOADH(hp0, ha0, ha1, ha2)
    LOADH(hp1, hb0, hb1, hb2)
    LOADH(hp2, hc0, hc1, hc2)
    LOADH(hp3, hd0, hd1, hd2)
    ACC8H(ha0, 0)
    ACC8H(ha1, 8)
    ACC8H(ha2, 16)
    ACC8H(hb0, 0)
    ACC8H(hb1, 8)
    ACC8H(hb2, 16)
    ACC8H(hc0, 0)
    ACC8H(hc1, 8)
    ACC8H(hc2, 16)
    ACC8H(hd0, 0)
    ACC8H(hd1, 8)
    ACC8H(hd2, 16)
  }
  for (; e < end; e++) {
    int s0 = srcPerm[e];
    const u16* hp0 = h16 + (size_t)s0 * 96 + fo;
    LOADH(hp0, ha0, ha1, ha2)
    ACC8H(ha0, 0)
    ACC8H(ha1, 8)
    ACC8H(ha2, 16)
  }
  {
    int n = n0 + nl;
    uint4 hh0 = make_uint4(0, 0, 0, 0), hh1 = hh0, hh2 = hh0;
    float4 es0 = make_float4(0.f, 0.f, 0.f, 0.f), es1 = es0, es2 = es0, es3 = es0, es4 = es0, es5 = es0;
    if (n < Nn) {
      const u16* hp = h16 + (size_t)n * 96 + fo;
      hh0 = *reinterpret_cast<const uint4*>(hp);
      hh1 = *reinterpret_cast<const uint4*>(hp + 8);
      hh2 = *reinterpret_cast<const uint4*>(hp + 16);
      const float* ep = eSum + (size_t)n * 96 + fo;
      es0 = *reinterpret_cast<const float4*>(ep);
      es1 = *reinterpret_cast<const float4*>(ep + 4);
      es2 = *reinterpret_cast<const float4*>(ep + 8);
      es3 = *reinterpret_cast<const float4*>(ep + 12);
      es4 = *reinterpret_cast<const float4*>(ep + 16);
      es5 = *reinterpret_cast<const float4*>(ep + 20);
    }
    uint4 w0, w1, w2;
    w0.x = pack2(fmaf(epsv, blo(hh0.x), acc[0] + es0.x),  fmaf(epsv, bhi(hh0.x), acc[1] + es0.y));
    w0.y = pack2(fmaf(epsv, blo(hh0.y), acc[2] + es0.z),  fmaf(epsv, bhi(hh0.y), acc[3] + es0.w));
    w0.z = pack2(fmaf(epsv, blo(hh0.z), acc[4] + es1.x),  fmaf(epsv, bhi(hh0.z), acc[5] + es1.y));
    w0.w = pack2(fmaf(epsv, blo(hh0.w), acc[6] + es1.z),  fmaf(epsv, bhi(hh0.w), acc[7] + es1.w));
    w1.x = pack2(fmaf(epsv, blo(hh1.x), acc[8] + es2.x),  fmaf(epsv, bhi(hh1.x), acc[9] + es2.y));
    w1.y = pack2(fmaf(epsv, blo(hh1.y), acc[10] + es2.z), fmaf(epsv, bhi(hh1.y), acc[11] + es2.w));
    w1.z = pack2(fmaf(epsv, blo(hh1.z), acc[12] + es3.x), fmaf(epsv, bhi(hh1.z), acc[13] + es3.y));
    w1.w = pack2(fmaf(epsv, blo(hh1.w), acc[14] + es3.z), fmaf(epsv, bhi(hh1.w), acc[15] + es3.w));
    w2.x = pack2(fmaf(epsv, blo(hh2.x), acc[16] + es4.x), fmaf(epsv, bhi(hh2.x), acc[17] + es4.y));
    w2.y = pack2(fmaf(epsv, blo(hh2.y), acc[18] + es4.z), fmaf(epsv, bhi(hh2.y), acc[19] + es4.w));
    w2.z = pack2(fmaf(epsv, blo(hh2.z), acc[20] + es5.x), fmaf(epsv, bhi(hh2.z), acc[21] + es5.y));
    w2.w = pack2(fmaf(epsv, blo(hh2.w), acc[22] + es5.z), fmaf(epsv, bhi(hh2.w), acc[23] + es5.w));
    *reinterpret_cast<uint4*>(&At[nl][fo]) = w0;
    *reinterpret_cast<uint4*>(&At[nl][fo + 8]) = w1;
    *reinterpret_cast<uint4*>(&At[nl][fo + 16]) = w2;
  }
  // stage W1: k-fast packed writes (c across lanes -> coalesced global reads, uint2 LDS writes)
  for (int i = t; i < 24 * 96; i += 256) {
    int kg = i / 96, c = i - kg * 96;
    int k0 = kg * 4;
    float w0 = W1[(k0 + 0) * 96 + c];
    float w1 = W1[(k0 + 1) * 96 + c];
    float w2 = W1[(k0 + 2) * 96 + c];
    float w3 = W1[(k0 + 3) * 96 + c];
    *reinterpret_cast<uint2*>(&Wt[c][k0]) = make_uint2(pack2(w0, w1), pack2(w2, w3));
  }
  __syncthreads();
  int w = t >> 6, l = t & 63;
  int lr = l & 15, lg = l >> 4;
  int rowBase = w * 16;
  short8 a0 = *reinterpret_cast<const short8*>(&At[rowBase + lr][lg * 8]);
  short8 a1 = *reinterpret_cast<const short8*>(&At[rowBase + lr][32 + lg * 8]);
  short8 a2 = *reinterpret_cast<const short8*>(&At[rowBase + lr][64 + lg * 8]);
  f32x4 gacc[6];
#pragma unroll
  for (int nt = 0; nt < 6; nt++) gacc[nt] = (f32x4){0.f, 0.f, 0.f, 0.f};
#pragma unroll
  for (int nt = 0; nt < 6; nt++) {
    short8 b0 = *reinterpret_cast<const short8*>(&Wt[nt * 16 + lr][lg * 8]);
    short8 bv1 = *reinterpret_cast<const short8*>(&Wt[nt * 16 + lr][32 + lg * 8]);
    short8 bv2 = *reinterpret_cast<const short8*>(&Wt[nt * 16 + lr][64 + lg * 8]);
    gacc[nt] = __builtin_amdgcn_mfma_f32_16x16x32_bf16(a0, b0, gacc[nt], 0, 0, 0);
    gacc[nt] = __builtin_amdgcn_mfma_f32_16x16x32_bf16(a1, bv1, gacc[nt], 0, 0, 0);
    gacc[nt] = __builtin_amdgcn_mfma_f32_16x16x32_bf16(a2, bv2, gacc[nt], 0, 0, 0);
  }
  // mid overwrites A-tile: wave-private rows, a-frags already in registers
#pragma unroll
  for (int nt = 0; nt < 6; nt++) {
    int col = nt * 16 + lr;
    float bias = b1[col];
#pragma unroll
    for (int j = 0; j < 4; j++) {
      int row = rowBase + lg * 4 + j;
      At[row][col] = __float2bfloat16(fmaxf(gacc[nt][j] + bias, 0.f));
    }
  }
  __syncthreads();   // all waves done reading Wt(W1)
  for (int i = t; i < 24 * 96; i += 256) {
    int kg = i / 96, c = i - kg * 96;
    int k0 = kg * 4;
    float w0 = W2[(k0 + 0) * 96 + c];
    float w1 = W2[(k0 + 1) * 96 + c];
    float w2 = W2[(k0 + 2) * 96 + c];
    float w3 = W2[(k0 + 3) * 96 + c];
    *reinterpret_cast<uint2*>(&Wt[c][k0]) = make_uint2(pack2(w0, w1), pack2(w2, w3));
  }
  __syncthreads();
  short8 m0 = *reinterpret_cast<const short8*>(&At[rowBase + lr][lg * 8]);
  short8 m1 = *reinterpret_cast<const short8*>(&At[rowBase + lr][32 + lg * 8]);
  short8 m2 = *reinterpret_cast<const short8*>(&At[rowBase + lr][64 + lg * 8]);
#pragma unroll
  for (int nt = 0; nt < 6; nt++) gacc[nt] = (f32x4){0.f, 0.f, 0.f, 0.f};
#pragma unroll
  for (int nt = 0; nt < 6; nt++) {
    short8 b0 = *reinterpret_cast<const short8*>(&Wt[nt * 16 + lr][lg * 8]);
    short8 bv1 = *reinterpret_cast<const short8*>(&Wt[nt * 16 + lr][32 + lg * 8]);
    short8 bv2 = *reinterpret_cast<const short8*>(&Wt[nt * 16 + lr][64 + lg * 8]);
    gacc[nt] = __builtin_amdgcn_mfma_f32_16x16x32_bf16(m0, b0, gacc[nt], 0, 0, 0);
    gacc[nt] = __builtin_amdgcn_mfma_f32_16x16x32_bf16(m1, bv1, gacc[nt], 0, 0, 0);
    gacc[nt] = __builtin_amdgcn_mfma_f32_16x16x32_bf16(m2, bv2, gacc[nt], 0, 0, 0);
  }
#pragma unroll
  for (int nt = 0; nt < 6; nt++) {
    int col = nt * 16 + lr;
    float bias = b2[col];
#pragma unroll
    for (int j = 0; j < 4; j++) {
      int row = rowBase + lg * 4 + j;
      int n = n0 + row;
      if (n < Nn) z[(size_t)n * 96 + col] = gacc[nt][j] + bias;
    }
  }
}

// ---------------- FUSED GraphNorm: stats + normalize + residual, one block per graph ----------------

__global__ __launch_bounds__(384) void k_gnorm(const float* __restrict__ z, u16* __restrict__ h16,
                                               const int* __restrict__ gptr, const float* __restrict__ ms,
                                               const float* __restrict__ gw, const float* __restrict__ gb) {
  __shared__ float r1[16][100];
  __shared__ float r2[16][100];
  __shared__ float smm[96], sinv[96], sgb[96];
  int g = blockIdx.x, t = threadIdx.x;
  int beg = gptr[g], end = gptr[g + 1];
  int sub = t / 24, slot = t - (t / 24) * 24;
  int sl = slot * 4;
  float4 s1 = make_float4(0.f, 0.f, 0.f, 0.f), s2 = s1;
  for (int n = beg + sub; n < end; n += 16) {
    float4 zv = *reinterpret_cast<const float4*>(z + (size_t)n * 96 + sl);
    s1.x += zv.x; s1.y += zv.y; s1.z += zv.z; s1.w += zv.w;
    s2.x += zv.x * zv.x; s2.y += zv.y * zv.y; s2.z += zv.z * zv.z; s2.w += zv.w * zv.w;
  }
  *reinterpret_cast<float4*>(&r1[sub][sl]) = s1;
  *reinterpret_cast<float4*>(&r2[sub][sl]) = s2;
  __syncthreads();
  if (t < 96) {
    float S1 = 0.f, S2 = 0.f;
#pragma unroll
    for (int u = 0; u < 16; u++) { S1 += r1[u][t]; S2 += r2[u][t]; }
    float c = (float)max(end - beg, 1);
    float m = S1 / c;
    float mm = m * ms[t];
    float var = S2 / c - 2.f * mm * m + mm * mm;
    var = fmaxf(var, 0.f);
    smm[t] = mm;
    sinv[t] = rsqrtf(var + 1e-5f) * gw[t];
    sgb[t] = gb[t];
  }
  __syncthreads();
  float4 mm4 = *reinterpret_cast<const float4*>(&smm[sl]);
  float4 iv4 = *reinterpret_cast<const float4*>(&sinv[sl]);
  float4 gb4 = *reinterpret_cast<const float4*>(&sgb[sl]);
  for (int n = beg + sub; n < end; n += 16) {
    float4 zv = *reinterpret_cast<const float4*>(z + (size_t)n * 96 + sl);
    uint2 hv = *reinterpret_cast<const uint2*>(h16 + (size_t)n * 96 + sl);
    float o0 = fmaxf((zv.x - mm4.x) * iv4.x + gb4.x, 0.f) + blo(hv.x);
    float o1 = fmaxf((zv.y - mm4.y) * iv4.y + gb4.y, 0.f) + bhi(hv.x);
    float o2 = fmaxf((zv.z - mm4.z) * iv4.z + gb4.z, 0.f) + blo(hv.y);
    float o3 = fmaxf((zv.w - mm4.w) * iv4.w + gb4.w, 0.f) + bhi(hv.y);
    *reinterpret_cast<uint2*>(h16 + (size_t)n * 96 + sl) = make_uint2(pack2(o0, o1), pack2(o2, o3));
  }
}

// ---------------- pooling + LayerNorm + output MLP ----------------

__global__ __launch_bounds__(256) void k_pool_out(const u16* __restrict__ h16, const int* __restrict__ gptr,
                                                  const float* __restrict__ lng, const float* __restrict__ lnb,
                                                  const float* __restrict__ W1, const float* __restrict__ b1,
                                                  const float* __restrict__ W2, const float* __restrict__ b2,
                                                  float* __restrict__ out) {
  __shared__ float sh1[2][96], sh2[2][96];
  __shared__ float gbuf[192];
  __shared__ float rs[4], rq[4];
  __shared__ float s_mu, s_rstd;
  __shared__ float inter[96];
  int g = blockIdx.x, t = threadIdx.x;
  int beg = gptr[g], end = gptr[g + 1];
  if (t < 192) {
    int j = t % 96, half = t / 96;
    float s = 0.f, m = -INFINITY;
    for (int n = beg + half; n < end; n += 2) {
      float v = bus(h16[(size_t)n * 96 + j]);
      s += v; m = fmaxf(m, v);
    }
    sh1[half][j] = s; sh2[half][j] = m;
  }
  __syncthreads();
  if (t < 96) {
    float c = (float)max(end - beg, 1);
    gbuf[t] = (sh1[0][t] + sh1[1][t]) / c;
    gbuf[96 + t] = fmaxf(sh2[0][t], sh2[1][t]);
  }
  __syncthreads();
  float sv = (t < 192) ? gbuf[t] : 0.f;
  float qv = sv * sv;
#pragma unroll
  for (int off = 32; off; off >>= 1) { sv += __shfl_down(sv, off); qv += __shfl_down(qv, off); }
  if ((t & 63) == 0) { rs[t >> 6] = sv; rq[t >> 6] = qv; }
  __syncthreads();
  if (t == 0) {
    float S = rs[0] + rs[1] + rs[2] + rs[3];
    float Q = rq[0] + rq[1] + rq[2] + rq[3];
    float mu = S / 192.f;
    float va = Q / 192.f - mu * mu;
    s_mu = mu; s_rstd = rsqrtf(fmaxf(va, 0.f) + 1e-5f);
  }
  __syncthreads();
  if (t < 192) gbuf[t] = (gbuf[t] - s_mu) * s_rstd * lng[t] + lnb[t];
  __syncthreads();
  if (t < 96) {
    float a = b1[t];
    for (int k = 0; k < 192; k++) a += gbuf[k] * W1[k * 96 + t];
    inter[t] = fmaxf(a, 0.f);
  }
  __syncthreads();
  {
    float a = b2[t];
    for (int j = 0; j < 96; j++) a += inter[j] * W2[j * 256 + t];
    out[g * 256 + t] = a;
  }
}

// ---------------- host ----------------

extern "C" void kernel_launch(void* const* d_in, const int* in_sizes, int n_in,
                              void* d_out, int out_size, void* d_ws, size_t ws_size,
                              hipStream_t stream) {
  (void)in_sizes; (void)n_in; (void)out_size; (void)ws_size;
  const float* x     = (const float*)d_in[0];
  const float* eattr = (const float*)d_in[1];
  const int*   eidx2 = (const int*)  d_in[2];
  const int*   batch = (const int*)  d_in[3];
  const float* nodeW = (const float*)d_in[4];
  const float* nodeb = (const float*)d_in[5];
  const float* edgeW = (const float*)d_in[6];
  const float* edgeb = (const float*)d_in[7];
  const float* mlpW1 = (const float*)d_in[8];
  const float* mlpb1 = (const float*)d_in[9];
  const float* mlpW2 = (const float*)d_in[10];
  const float* mlpb2 = (const float*)d_in[11];
  const float* epsA  = (const float*)d_in[12];
  const float* gnw   = (const float*)d_in[13];
  const float* gnb   = (const float*)d_in[14];
  const float* gnms  = (const float*)d_in[15];
  const float* lng   = (const float*)d_in[16];
  const float* lnb   = (const float*)d_in[17];
  const float* oW1   = (const float*)d_in[18];
  const float* ob1   = (const float*)d_in[19];
  const float* oW2   = (const float*)d_in[20];
  const float* ob2   = (const float*)d_in[21];
  float* out = (float*)d_out;

  const int* srcArr = eidx2;        // edge_index[0]
  const int* dstArr = eidx2 + Ee;   // edge_index[1]

  char* p = (char*)d_ws;
  auto carve = [&](size_t bytes) -> void* {
    void* r = (void*)p;
    p += ((bytes + 255) & ~(size_t)255);
    return r;
  };
  // Total ~105 MB.
  u16* h16     = (u16*)carve((size_t)Nn * 96 * 2);     // h state, bf16
  float* aggz  = (float*)carve((size_t)Nn * 96 * 4);   // z (f32)
  float* eSum  = (float*)carve((size_t)Nn * 96 * 4);   // layer-invariant edge-message sums (f32)
  int* rowptr  = (int*)carve((size_t)(Nn + 1) * 4);
  int* elist   = (int*)carve((size_t)Ee * 4);
  int* gptr    = (int*)carve((size_t)(Gg + 1) * 4);
  // srcPerm (Ee ints) doubles as CSR temp space (deg/localA/cursor/bsum, 3*Nn+NB ints < Ee).
  int* srcPerm = (int*)carve((size_t)Ee * 4);
  int* deg     = srcPerm;
  int* localA  = srcPerm + Nn;
  int* cursor  = srcPerm + 2 * Nn;
  int* bsum    = srcPerm + 3 * Nn;

  hipMemsetAsync(deg, 0, (size_t)Nn * 4, stream);
  k_gptr<<<1, 512, 0, stream>>>(batch, gptr);
  k_deg<<<(Ee + 255) / 256, 256, 0, stream>>>(dstArr, deg);
  k_scanA<<<(Nn + 1023) / 1024, 256, 0, stream>>>(deg, localA, bsum);
  k_scanB<<<1, 128, 0, stream>>>(bsum);
  k_scanC<<<(Nn + 255) / 256, 256, 0, stream>>>(localA, bsum, rowptr, cursor);
  k_fill<<<(Ee + 255) / 256, 256, 0, stream>>>(dstArr, cursor, elist);

  // eSum precompute (scalar v5, ES_NODES=8; also writes srcPerm over dead CSR temps)
  k_esum<<<(Nn + ES_NODES - 1) / ES_NODES, 192, 0, stream>>>(eattr, elist, srcArr, rowptr,
                                                             edgeW, edgeb, srcPerm, eSum);

  k_node_mlp<<<(Nn + 15) / 16, 256, 0, stream>>>(x, nodeW, nodeb, h16);

  for (int i = 0; i < 3; i++) {
    k_layer<<<(Nn + 63) / 64, 256, 0, stream>>>(h16, srcPerm, rowptr, eSum,
                                                mlpW1 + i * 9216, mlpb1 + i * 96,
                                                mlpW2 + i * 9216, mlpb2 + i * 96, epsA, i, aggz);
    k_gnorm<<<Gg, 384, 0, stream>>>(aggz, h16, gptr, gnms + i * 96, gnw + i * 96, gnb + i * 96);
  }

  k_pool_out<<<Gg, 256, 0, stream>>>(h16, gptr, lng, lnb, oW1, ob1, oW2, ob2, out);
}

// Round 20
// 493.499 us; speedup vs baseline: 1.7870x; 1.0320x over previous
//
#include <hip/hip_runtime.h>
#include <hip/hip_bf16.h>
#include <cfloat>

#define Nn 100000
#define Ee 800000
#define Gg 256
// H=96, NI=32, EI=10, OUT=256, L=3

typedef __attribute__((ext_vector_type(8))) short short8;
typedef __attribute__((ext_vector_type(4))) float f32x4;
typedef unsigned short u16;

static __device__ __forceinline__ float blo(unsigned u) { return __builtin_bit_cast(float, u << 16); }
static __device__ __forceinline__ float bhi(unsigned u) { return __builtin_bit_cast(float, u & 0xffff0000u); }
static __device__ __forceinline__ float bus(u16 u) { return __builtin_bit_cast(float, ((unsigned)u) << 16); }
static __device__ __forceinline__ u16 f2bu(float f) {
  __hip_bfloat16 b = __float2bfloat16(f);
  return __builtin_bit_cast(u16, b);
}
static __device__ __forceinline__ unsigned pack2(float lo, float hi) {
  return (unsigned)f2bu(lo) | ((unsigned)f2bu(hi) << 16);
}

// ---------------- CSR build ----------------

__global__ __launch_bounds__(512) void k_gptr(const int* __restrict__ batch, int* __restrict__ gptr) {
  int g = threadIdx.x;
  if (g > Gg) return;
  if (g == Gg) { gptr[Gg] = Nn; return; }
  int lo = 0, hi = Nn;
  while (lo < hi) { int mid = (lo + hi) >> 1; if (batch[mid] < g) lo = mid + 1; else hi = mid; }
  gptr[g] = lo;
}

__global__ __launch_bounds__(256) void k_deg(const int* __restrict__ dst, int* __restrict__ deg) {
  int e = blockIdx.x * 256 + threadIdx.x;
  if (e < Ee) atomicAdd(&deg[dst[e]], 1);
}

__global__ __launch_bounds__(256) void k_scanA(const int* __restrict__ deg, int* __restrict__ localA,
                                               int* __restrict__ bsum) {
  __shared__ int ts[256];
  int t = threadIdx.x, b = blockIdx.x;
  int base = b * 1024 + t * 4;
  int v[4]; int s = 0;
#pragma unroll
  for (int k = 0; k < 4; k++) { int idx = base + k; v[k] = (idx < Nn) ? deg[idx] : 0; s += v[k]; }
  ts[t] = s; __syncthreads();
  for (int off = 1; off < 256; off <<= 1) {
    int y = (t >= off) ? ts[t - off] : 0;
    __syncthreads();
    ts[t] += y;
    __syncthreads();
  }
  int ex = ts[t] - s;
#pragma unroll
  for (int k = 0; k < 4; k++) { int idx = base + k; if (idx < Nn) localA[idx] = ex; ex += v[k]; }
  if (t == 255) bsum[b] = ts[255];
}

__global__ __launch_bounds__(128) void k_scanB(int* __restrict__ bsum) {
  __shared__ int s[128];
  const int NB = (Nn + 1023) / 1024;
  int t = threadIdx.x;
  int v = (t < NB) ? bsum[t] : 0;
  s[t] = v; __syncthreads();
  for (int off = 1; off < 128; off <<= 1) {
    int y = (t >= off) ? s[t - off] : 0;
    __syncthreads();
    s[t] += y;
    __syncthreads();
  }
  if (t < NB) bsum[t] = s[t] - v;   // exclusive
}

__global__ __launch_bounds__(256) void k_scanC(const int* __restrict__ localA, const int* __restrict__ bsum,
                                               int* __restrict__ rowptr, int* __restrict__ cursor) {
  int i = blockIdx.x * 256 + threadIdx.x;
  if (i < Nn) { int v = localA[i] + bsum[i >> 10]; rowptr[i] = v; cursor[i] = v; }
  if (i == 0) rowptr[Nn] = Ee;
}

__global__ __launch_bounds__(256) void k_fill(const int* __restrict__ dst, int* __restrict__ cursor,
                                              int* __restrict__ elist) {
  int e = blockIdx.x * 256 + threadIdx.x;
  if (e < Ee) { int p = atomicAdd(&cursor[dst[e]], 1); elist[p] = e; }
}

// ---------------- eSum precompute v5 (scalar 2 cols/thread, run-length regs, ES_NODES=8) ----------------

#define ES_NODES 8
#define ES_CHUNK 64

__global__ __launch_bounds__(192) void k_esum(const float* __restrict__ eattr,
                                              const int* __restrict__ elist,
                                              const int* __restrict__ srcArr,
                                              const int* __restrict__ rowptr,
                                              const float* __restrict__ eW,
                                              const float* __restrict__ eb,
                                              int* __restrict__ srcPerm,
                                              float* __restrict__ eSum) {
  __shared__ float ea[ES_CHUNK][10];
  __shared__ int dstl[ES_CHUNK];
  __shared__ float eT[4][ES_NODES][96];
  __shared__ int rp16[ES_NODES + 1];
  int t = threadIdx.x;
  int n0 = blockIdx.x * ES_NODES;
  if (t <= ES_NODES) rp16[t] = rowptr[min(n0 + t, Nn)];
  for (int i = t; i < 4 * ES_NODES * 96; i += 192) ((float*)eT)[i] = 0.f;
  int jp = t % 48, sub = t / 48;         // cols j0, j0+1; edge stride 4
  int j0 = jp * 2;
  float2 wreg[10];
#pragma unroll
  for (int k = 0; k < 10; k++) wreg[k] = *reinterpret_cast<const float2*>(&eW[k * 96 + j0]);
  float2 breg = *reinterpret_cast<const float2*>(&eb[j0]);
  __syncthreads();
  int beg = rp16[0], end = rp16[ES_NODES];
  float raccx = 0.f, raccy = 0.f;
  int rdst = -1;
  for (int cs = beg; cs < end; cs += ES_CHUNK) {
    int m = min(ES_CHUNK, end - cs);
    for (int i = t; i < m; i += 192) {
      int q = cs + i;
      int e = elist[q];
      srcPerm[q] = srcArr[e];
      int lo = 0, hi = ES_NODES - 1;
      while (lo < hi) { int mid = (lo + hi + 1) >> 1; if (rp16[mid] <= q) lo = mid; else hi = mid - 1; }
      dstl[i] = lo;
    }
    for (int i = t; i < 5 * m; i += 192) {
      int ii = i / 5, k2 = (i - ii * 5) * 2;
      int e = elist[cs + ii];            // redundant load, L1-hit
      *reinterpret_cast<float2*>(&ea[ii][k2]) = *reinterpret_cast<const float2*>(&eattr[(size_t)e * 10 + k2]);
    }
    __syncthreads();
    for (int i = sub; i < m; i += 4) {
      float ax = breg.x, ay = breg.y;
#pragma unroll
      for (int k = 0; k < 10; k++) {
        float a = ea[i][k];
        ax += a * wreg[k].x;
        ay += a * wreg[k].y;
      }
      ax = fmaxf(ax, 0.f);
      ay = fmaxf(ay, 0.f);
      int d = dstl[i];
      if (d != rdst) {
        if (rdst >= 0) {
          eT[sub][rdst][j0]     += raccx;
          eT[sub][rdst][j0 + 1] += raccy;
        }
        rdst = d; raccx = ax; raccy = ay;
      } else {
        raccx += ax; raccy += ay;
      }
    }
    __syncthreads();   // accumulate reads of ea/dstl done before next chunk restages
  }
  if (rdst >= 0) {
    eT[sub][rdst][j0]     += raccx;
    eT[sub][rdst][j0 + 1] += raccy;
  }
  __syncthreads();
  for (int i = t; i < ES_NODES * 96; i += 192) {
    int nl = i / 96, jj = i - nl * 96;
    int n = n0 + nl;
    if (n < Nn) eSum[(size_t)n * 96 + jj] = eT[0][nl][jj] + eT[1][nl][jj] + eT[2][nl][jj] + eT[3][nl][jj];
  }
}

// ---------------- node MLP: h16 = relu(x @ W + b), x[N,32] ----------------

__global__ __launch_bounds__(256) void k_node_mlp(const float* __restrict__ x, const float* __restrict__ W,
                                                  const float* __restrict__ b, u16* __restrict__ h16) {
  __shared__ float xs[16][33];
  __shared__ float Ws[32 * 96];
  __shared__ float bs[96];
  int t = threadIdx.x;
  int n0 = blockIdx.x * 16;
  for (int i = t; i < 32 * 96; i += 256) Ws[i] = W[i];
  if (t < 96) bs[t] = b[t];
  for (int i = t; i < 512; i += 256) {
    int nl = i >> 5, k = i & 31; int n = n0 + nl;
    xs[nl][k] = (n < Nn) ? x[n * 32 + k] : 0.f;
  }
  __syncthreads();
#pragma unroll
  for (int p = 0; p < 6; p++) {
    int oi = t + p * 256; int nl = oi / 96, j = oi % 96; int n = n0 + nl;
    if (n < Nn) {
      float acc = bs[j];
#pragma unroll
      for (int k = 0; k < 32; k++) acc += xs[nl][k] * Ws[k * 96 + j];
      h16[(size_t)n * 96 + j] = f2bu(fmaxf(acc, 0.f));
    }
  }
}

// ---------------- FUSED layer kernel v7: 128 nodes/block, 512 threads (8 waves) ----------------
// LDS ~47KB -> 3 blocks/CU x 8 waves = 24 waves/CU (was 16) for the latency-bound gather,
// and W1/W2 staging amortized over 2x rows. Same gather (4 thr/node) + MFMA structure.

#define MPAD 104
#define BN 128

#define ACC8H(hv, B) \
  acc[B+0] += blo(hv.x); acc[B+1] += bhi(hv.x); acc[B+2] += blo(hv.y); acc[B+3] += bhi(hv.y); \
  acc[B+4] += blo(hv.z); acc[B+5] += bhi(hv.z); acc[B+6] += blo(hv.w); acc[B+7] += bhi(hv.w);

#define LOADH(hp, H0, H1, H2) \
  uint4 H0 = *reinterpret_cast<const uint4*>(hp); \
  uint4 H1 = *reinterpret_cast<const uint4*>(hp + 8); \
  uint4 H2 = *reinterpret_cast<const uint4*>(hp + 16);

__global__ __launch_bounds__(512) void k_layer(const u16* __restrict__ h16,
                                               const int* __restrict__ srcPerm,
                                               const int* __restrict__ rowptr,
                                               const float* __restrict__ eSum,
                                               const float* __restrict__ W1, const float* __restrict__ b1,
                                               const float* __restrict__ W2, const float* __restrict__ b2,
                                               const float* __restrict__ epsA, int layer,
                                               float* __restrict__ z) {
  __shared__ __align__(16) __hip_bfloat16 At[BN][MPAD];   // A-tile, then mid (wave-private rows)
  __shared__ __align__(16) __hip_bfloat16 Wt[96][MPAD];   // Wt[col][k]
  __shared__ int rp[BN + 1];
  int t = threadIdx.x;
  int n0 = blockIdx.x * BN;
  if (t <= BN) rp[t] = rowptr[min(n0 + t, Nn)];
  __syncthreads();
  float epsv = 1.0f + epsA[layer];
  int nl = t >> 2, q = t & 3;            // node-local (0..127), feature-quarter
  int beg = rp[nl], end = rp[nl + 1];
  const size_t fo = (size_t)q * 24;      // feature offset (elements)
  float acc[24];
#pragma unroll
  for (int j = 0; j < 24; j++) acc[j] = 0.f;
  int e = beg;
  for (; e + 4 <= end; e += 4) {
    int s0 = srcPerm[e], s1 = srcPerm[e + 1], s2 = srcPerm[e + 2], s3 = srcPerm[e + 3];
    const u16* hp0 = h16 + (size_t)s0 * 96 + fo;
    const u16* hp1 = h16 + (size_t)s1 * 96 + fo;
    const u16* hp2 = h16 + (size_t)s2 * 96 + fo;
    const u16* hp3 = h16 + (size_t)s3 * 96 + fo;
    LOADH(hp0, ha0, ha1, ha2)
    LOADH(hp1, hb0, hb1, hb2)
    LOADH(hp2, hc0, hc1, hc2)
    LOADH(hp3, hd0, hd1, hd2)
    ACC8H(ha0, 0)
    ACC8H(ha1, 8)
    ACC8H(ha2, 16)
    ACC8H(hb0, 0)
    ACC8H(hb1, 8)
    ACC8H(hb2, 16)
    ACC8H(hc0, 0)
    ACC8H(hc1, 8)
    ACC8H(hc2, 16)
    ACC8H(hd0, 0)
    ACC8H(hd1, 8)
    ACC8H(hd2, 16)
  }
  for (; e < end; e++) {
    int s0 = srcPerm[e];
    const u16* hp0 = h16 + (size_t)s0 * 96 + fo;
    LOADH(hp0, ha0, ha1, ha2)
    ACC8H(ha0, 0)
    ACC8H(ha1, 8)
    ACC8H(ha2, 16)
  }
  {
    int n = n0 + nl;
    uint4 hh0 = make_uint4(0, 0, 0, 0), hh1 = hh0, hh2 = hh0;
    float4 es0 = make_float4(0.f, 0.f, 0.f, 0.f), es1 = es0, es2 = es0, es3 = es0, es4 = es0, es5 = es0;
    if (n < Nn) {
      const u16* hp = h16 + (size_t)n * 96 + fo;
      hh0 = *reinterpret_cast<const uint4*>(hp);
      hh1 = *reinterpret_cast<const uint4*>(hp + 8);
      hh2 = *reinterpret_cast<const uint4*>(hp + 16);
      const float* ep = eSum + (size_t)n * 96 + fo;
      es0 = *reinterpret_cast<const float4*>(ep);
      es1 = *reinterpret_cast<const float4*>(ep + 4);
      es2 = *reinterpret_cast<const float4*>(ep + 8);
      es3 = *reinterpret_cast<const float4*>(ep + 12);
      es4 = *reinterpret_cast<const float4*>(ep + 16);
      es5 = *reinterpret_cast<const float4*>(ep + 20);
    }
    uint4 w0, w1, w2;
    w0.x = pack2(fmaf(epsv, blo(hh0.x), acc[0] + es0.x),  fmaf(epsv, bhi(hh0.x), acc[1] + es0.y));
    w0.y = pack2(fmaf(epsv, blo(hh0.y), acc[2] + es0.z),  fmaf(epsv, bhi(hh0.y), acc[3] + es0.w));
    w0.z = pack2(fmaf(epsv, blo(hh0.z), acc[4] + es1.x),  fmaf(epsv, bhi(hh0.z), acc[5] + es1.y));
    w0.w = pack2(fmaf(epsv, blo(hh0.w), acc[6] + es1.z),  fmaf(epsv, bhi(hh0.w), acc[7] + es1.w));
    w1.x = pack2(fmaf(epsv, blo(hh1.x), acc[8] + es2.x),  fmaf(epsv, bhi(hh1.x), acc[9] + es2.y));
    w1.y = pack2(fmaf(epsv, blo(hh1.y), acc[10] + es2.z), fmaf(epsv, bhi(hh1.y), acc[11] + es2.w));
    w1.z = pack2(fmaf(epsv, blo(hh1.z), acc[12] + es3.x), fmaf(epsv, bhi(hh1.z), acc[13] + es3.y));
    w1.w = pack2(fmaf(epsv, blo(hh1.w), acc[14] + es3.z), fmaf(epsv, bhi(hh1.w), acc[15] + es3.w));
    w2.x = pack2(fmaf(epsv, blo(hh2.x), acc[16] + es4.x), fmaf(epsv, bhi(hh2.x), acc[17] + es4.y));
    w2.y = pack2(fmaf(epsv, blo(hh2.y), acc[18] + es4.z), fmaf(epsv, bhi(hh2.y), acc[19] + es4.w));
    w2.z = pack2(fmaf(epsv, blo(hh2.z), acc[20] + es5.x), fmaf(epsv, bhi(hh2.z), acc[21] + es5.y));
    w2.w = pack2(fmaf(epsv, blo(hh2.w), acc[22] + es5.z), fmaf(epsv, bhi(hh2.w), acc[23] + es5.w));
    *reinterpret_cast<uint4*>(&At[nl][fo]) = w0;
    *reinterpret_cast<uint4*>(&At[nl][fo + 8]) = w1;
    *reinterpret_cast<uint4*>(&At[nl][fo + 16]) = w2;
  }
  // stage W1: k-fast packed writes (c across lanes -> coalesced global reads, uint2 LDS writes)
  for (int i = t; i < 24 * 96; i += 512) {
    int kg = i / 96, c = i - kg * 96;
    int k0 = kg * 4;
    float w0 = W1[(k0 + 0) * 96 + c];
    float w1 = W1[(k0 + 1) * 96 + c];
    float w2 = W1[(k0 + 2) * 96 + c];
    float w3 = W1[(k0 + 3) * 96 + c];
    *reinterpret_cast<uint2*>(&Wt[c][k0]) = make_uint2(pack2(w0, w1), pack2(w2, w3));
  }
  __syncthreads();
  int w = t >> 6, l = t & 63;
  int lr = l & 15, lg = l >> 4;
  int rowBase = w * 16;
  short8 a0 = *reinterpret_cast<const short8*>(&At[rowBase + lr][lg * 8]);
  short8 a1 = *reinterpret_cast<const short8*>(&At[rowBase + lr][32 + lg * 8]);
  short8 a2 = *reinterpret_cast<const short8*>(&At[rowBase + lr][64 + lg * 8]);
  f32x4 gacc[6];
#pragma unroll
  for (int nt = 0; nt < 6; nt++) gacc[nt] = (f32x4){0.f, 0.f, 0.f, 0.f};
#pragma unroll
  for (int nt = 0; nt < 6; nt++) {
    short8 b0 = *reinterpret_cast<const short8*>(&Wt[nt * 16 + lr][lg * 8]);
    short8 bv1 = *reinterpret_cast<const short8*>(&Wt[nt * 16 + lr][32 + lg * 8]);
    short8 bv2 = *reinterpret_cast<const short8*>(&Wt[nt * 16 + lr][64 + lg * 8]);
    gacc[nt] = __builtin_amdgcn_mfma_f32_16x16x32_bf16(a0, b0, gacc[nt], 0, 0, 0);
    gacc[nt] = __builtin_amdgcn_mfma_f32_16x16x32_bf16(a1, bv1, gacc[nt], 0, 0, 0);
    gacc[nt] = __builtin_amdgcn_mfma_f32_16x16x32_bf16(a2, bv2, gacc[nt], 0, 0, 0);
  }
  // mid overwrites A-tile: wave-private rows, a-frags already in registers
#pragma unroll
  for (int nt = 0; nt < 6; nt++) {
    int col = nt * 16 + lr;
    float bias = b1[col];
#pragma unroll
    for (int j = 0; j < 4; j++) {
      int row = rowBase + lg * 4 + j;
      At[row][col] = __float2bfloat16(fmaxf(gacc[nt][j] + bias, 0.f));
    }
  }
  __syncthreads();   // all waves done reading Wt(W1)
  for (int i = t; i < 24 * 96; i += 512) {
    int kg = i / 96, c = i - kg * 96;
    int k0 = kg * 4;
    float w0 = W2[(k0 + 0) * 96 + c];
    float w1 = W2[(k0 + 1) * 96 + c];
    float w2 = W2[(k0 + 2) * 96 + c];
    float w3 = W2[(k0 + 3) * 96 + c];
    *reinterpret_cast<uint2*>(&Wt[c][k0]) = make_uint2(pack2(w0, w1), pack2(w2, w3));
  }
  __syncthreads();
  short8 m0 = *reinterpret_cast<const short8*>(&At[rowBase + lr][lg * 8]);
  short8 m1 = *reinterpret_cast<const short8*>(&At[rowBase + lr][32 + lg * 8]);
  short8 m2 = *reinterpret_cast<const short8*>(&At[rowBase + lr][64 + lg * 8]);
#pragma unroll
  for (int nt = 0; nt < 6; nt++) gacc[nt] = (f32x4){0.f, 0.f, 0.f, 0.f};
#pragma unroll
  for (int nt = 0; nt < 6; nt++) {
    short8 b0 = *reinterpret_cast<const short8*>(&Wt[nt * 16 + lr][lg * 8]);
    short8 bv1 = *reinterpret_cast<const short8*>(&Wt[nt * 16 + lr][32 + lg * 8]);
    short8 bv2 = *reinterpret_cast<const short8*>(&Wt[nt * 16 + lr][64 + lg * 8]);
    gacc[nt] = __builtin_amdgcn_mfma_f32_16x16x32_bf16(m0, b0, gacc[nt], 0, 0, 0);
    gacc[nt] = __builtin_amdgcn_mfma_f32_16x16x32_bf16(m1, bv1, gacc[nt], 0, 0, 0);
    gacc[nt] = __builtin_amdgcn_mfma_f32_16x16x32_bf16(m2, bv2, gacc[nt], 0, 0, 0);
  }
#pragma unroll
  for (int nt = 0; nt < 6; nt++) {
    int col = nt * 16 + lr;
    float bias = b2[col];
#pragma unroll
    for (int j = 0; j < 4; j++) {
      int row = rowBase + lg * 4 + j;
      int n = n0 + row;
      if (n < Nn) z[(size_t)n * 96 + col] = gacc[nt][j] + bias;
    }
  }
}

// ---------------- FUSED GraphNorm: stats + normalize + residual, one block per graph ----------------

__global__ __launch_bounds__(384) void k_gnorm(const float* __restrict__ z, u16* __restrict__ h16,
                                               const int* __restrict__ gptr, const float* __restrict__ ms,
                                               const float* __restrict__ gw, const float* __restrict__ gb) {
  __shared__ float r1[16][100];
  __shared__ float r2[16][100];
  __shared__ float smm[96], sinv[96], sgb[96];
  int g = blockIdx.x, t = threadIdx.x;
  int beg = gptr[g], end = gptr[g + 1];
  int sub = t / 24, slot = t - (t / 24) * 24;
  int sl = slot * 4;
  float4 s1 = make_float4(0.f, 0.f, 0.f, 0.f), s2 = s1;
  for (int n = beg + sub; n < end; n += 16) {
    float4 zv = *reinterpret_cast<const float4*>(z + (size_t)n * 96 + sl);
    s1.x += zv.x; s1.y += zv.y; s1.z += zv.z; s1.w += zv.w;
    s2.x += zv.x * zv.x; s2.y += zv.y * zv.y; s2.z += zv.z * zv.z; s2.w += zv.w * zv.w;
  }
  *reinterpret_cast<float4*>(&r1[sub][sl]) = s1;
  *reinterpret_cast<float4*>(&r2[sub][sl]) = s2;
  __syncthreads();
  if (t < 96) {
    float S1 = 0.f, S2 = 0.f;
#pragma unroll
    for (int u = 0; u < 16; u++) { S1 += r1[u][t]; S2 += r2[u][t]; }
    float c = (float)max(end - beg, 1);
    float m = S1 / c;
    float mm = m * ms[t];
    float var = S2 / c - 2.f * mm * m + mm * mm;
    var = fmaxf(var, 0.f);
    smm[t] = mm;
    sinv[t] = rsqrtf(var + 1e-5f) * gw[t];
    sgb[t] = gb[t];
  }
  __syncthreads();
  float4 mm4 = *reinterpret_cast<const float4*>(&smm[sl]);
  float4 iv4 = *reinterpret_cast<const float4*>(&sinv[sl]);
  float4 gb4 = *reinterpret_cast<const float4*>(&sgb[sl]);
  for (int n = beg + sub; n < end; n += 16) {
    float4 zv = *reinterpret_cast<const float4*>(z + (size_t)n * 96 + sl);
    uint2 hv = *reinterpret_cast<const uint2*>(h16 + (size_t)n * 96 + sl);
    float o0 = fmaxf((zv.x - mm4.x) * iv4.x + gb4.x, 0.f) + blo(hv.x);
    float o1 = fmaxf((zv.y - mm4.y) * iv4.y + gb4.y, 0.f) + bhi(hv.x);
    float o2 = fmaxf((zv.z - mm4.z) * iv4.z + gb4.z, 0.f) + blo(hv.y);
    float o3 = fmaxf((zv.w - mm4.w) * iv4.w + gb4.w, 0.f) + bhi(hv.y);
    *reinterpret_cast<uint2*>(h16 + (size_t)n * 96 + sl) = make_uint2(pack2(o0, o1), pack2(o2, o3));
  }
}

// ---------------- pooling + LayerNorm + output MLP ----------------

__global__ __launch_bounds__(256) void k_pool_out(const u16* __restrict__ h16, const int* __restrict__ gptr,
                                                  const float* __restrict__ lng, const float* __restrict__ lnb,
                                                  const float* __restrict__ W1, const float* __restrict__ b1,
                                                  const float* __restrict__ W2, const float* __restrict__ b2,
                                                  float* __restrict__ out) {
  __shared__ float sh1[2][96], sh2[2][96];
  __shared__ float gbuf[192];
  __shared__ float rs[4], rq[4];
  __shared__ float s_mu, s_rstd;
  __shared__ float inter[96];
  int g = blockIdx.x, t = threadIdx.x;
  int beg = gptr[g], end = gptr[g + 1];
  if (t < 192) {
    int j = t % 96, half = t / 96;
    float s = 0.f, m = -INFINITY;
    for (int n = beg + half; n < end; n += 2) {
      float v = bus(h16[(size_t)n * 96 + j]);
      s += v; m = fmaxf(m, v);
    }
    sh1[half][j] = s; sh2[half][j] = m;
  }
  __syncthreads();
  if (t < 96) {
    float c = (float)max(end - beg, 1);
    gbuf[t] = (sh1[0][t] + sh1[1][t]) / c;
    gbuf[96 + t] = fmaxf(sh2[0][t], sh2[1][t]);
  }
  __syncthreads();
  float sv = (t < 192) ? gbuf[t] : 0.f;
  float qv = sv * sv;
#pragma unroll
  for (int off = 32; off; off >>= 1) { sv += __shfl_down(sv, off); qv += __shfl_down(qv, off); }
  if ((t & 63) == 0) { rs[t >> 6] = sv; rq[t >> 6] = qv; }
  __syncthreads();
  if (t == 0) {
    float S = rs[0] + rs[1] + rs[2] + rs[3];
    float Q = rq[0] + rq[1] + rq[2] + rq[3];
    float mu = S / 192.f;
    float va = Q / 192.f - mu * mu;
    s_mu = mu; s_rstd = rsqrtf(fmaxf(va, 0.f) + 1e-5f);
  }
  __syncthreads();
  if (t < 192) gbuf[t] = (gbuf[t] - s_mu) * s_rstd * lng[t] + lnb[t];
  __syncthreads();
  if (t < 96) {
    float a = b1[t];
    for (int k = 0; k < 192; k++) a += gbuf[k] * W1[k * 96 + t];
    inter[t] = fmaxf(a, 0.f);
  }
  __syncthreads();
  {
    float a = b2[t];
    for (int j = 0; j < 96; j++) a += inter[j] * W2[j * 256 + t];
    out[g * 256 + t] = a;
  }
}

// ---------------- host ----------------

extern "C" void kernel_launch(void* const* d_in, const int* in_sizes, int n_in,
                              void* d_out, int out_size, void* d_ws, size_t ws_size,
                              hipStream_t stream) {
  (void)in_sizes; (void)n_in; (void)out_size; (void)ws_size;
  const float* x     = (const float*)d_in[0];
  const float* eattr = (const float*)d_in[1];
  const int*   eidx2 = (const int*)  d_in[2];
  const int*   batch = (const int*)  d_in[3];
  const float* nodeW = (const float*)d_in[4];
  const float* nodeb = (const float*)d_in[5];
  const float* edgeW = (const float*)d_in[6];
  const float* edgeb = (const float*)d_in[7];
  const float* mlpW1 = (const float*)d_in[8];
  const float* mlpb1 = (const float*)d_in[9];
  const float* mlpW2 = (const float*)d_in[10];
  const float* mlpb2 = (const float*)d_in[11];
  const float* epsA  = (const float*)d_in[12];
  const float* gnw   = (const float*)d_in[13];
  const float* gnb   = (const float*)d_in[14];
  const float* gnms  = (const float*)d_in[15];
  const float* lng   = (const float*)d_in[16];
  const float* lnb   = (const float*)d_in[17];
  const float* oW1   = (const float*)d_in[18];
  const float* ob1   = (const float*)d_in[19];
  const float* oW2   = (const float*)d_in[20];
  const float* ob2   = (const float*)d_in[21];
  float* out = (float*)d_out;

  const int* srcArr = eidx2;        // edge_index[0]
  const int* dstArr = eidx2 + Ee;   // edge_index[1]

  char* p = (char*)d_ws;
  auto carve = [&](size_t bytes) -> void* {
    void* r = (void*)p;
    p += ((bytes + 255) & ~(size_t)255);
    return r;
  };
  // Total ~105 MB.
  u16* h16     = (u16*)carve((size_t)Nn * 96 * 2);     // h state, bf16
  float* aggz  = (float*)carve((size_t)Nn * 96 * 4);   // z (f32)
  float* eSum  = (float*)carve((size_t)Nn * 96 * 4);   // layer-invariant edge-message sums (f32)
  int* rowptr  = (int*)carve((size_t)(Nn + 1) * 4);
  int* elist   = (int*)carve((size_t)Ee * 4);
  int* gptr    = (int*)carve((size_t)(Gg + 1) * 4);
  // srcPerm (Ee ints) doubles as CSR temp space (deg/localA/cursor/bsum, 3*Nn+NB ints < Ee).
  int* srcPerm = (int*)carve((size_t)Ee * 4);
  int* deg     = srcPerm;
  int* localA  = srcPerm + Nn;
  int* cursor  = srcPerm + 2 * Nn;
  int* bsum    = srcPerm + 3 * Nn;

  hipMemsetAsync(deg, 0, (size_t)Nn * 4, stream);
  k_gptr<<<1, 512, 0, stream>>>(batch, gptr);
  k_deg<<<(Ee + 255) / 256, 256, 0, stream>>>(dstArr, deg);
  k_scanA<<<(Nn + 1023) / 1024, 256, 0, stream>>>(deg, localA, bsum);
  k_scanB<<<1, 128, 0, stream>>>(bsum);
  k_scanC<<<(Nn + 255) / 256, 256, 0, stream>>>(localA, bsum, rowptr, cursor);
  k_fill<<<(Ee + 255) / 256, 256, 0, stream>>>(dstArr, cursor, elist);

  // eSum precompute (scalar v5, ES_NODES=8; also writes srcPerm over dead CSR temps)
  k_esum<<<(Nn + ES_NODES - 1) / ES_NODES, 192, 0, stream>>>(eattr, elist, srcArr, rowptr,
                                                             edgeW, edgeb, srcPerm, eSum);

  k_node_mlp<<<(Nn + 15) / 16, 256, 0, stream>>>(x, nodeW, nodeb, h16);

  for (int i = 0; i < 3; i++) {
    k_layer<<<(Nn + BN - 1) / BN, 512, 0, stream>>>(h16, srcPerm, rowptr, eSum,
                                                    mlpW1 + i * 9216, mlpb1 + i * 96,
                                                    mlpW2 + i * 9216, mlpb2 + i * 96, epsA, i, aggz);
    k_gnorm<<<Gg, 384, 0, stream>>>(aggz, h16, gptr, gnms + i * 96, gnw + i * 96, gnb + i * 96);
  }

  k_pool_out<<<Gg, 256, 0, stream>>>(h16, gptr, lng, lnb, oW1, ob1, oW2, ob2, out);
}

// Round 21
// 488.342 us; speedup vs baseline: 1.8059x; 1.0106x over previous
//
#include <hip/hip_runtime.h>
#include <hip/hip_bf16.h>
#include <cfloat>

#define Nn 100000
#define Ee 800000
#define Gg 256
// H=96, NI=32, EI=10, OUT=256, L=3

typedef __attribute__((ext_vector_type(8))) short short8;
typedef __attribute__((ext_vector_type(4))) float f32x4;
typedef unsigned short u16;

static __device__ __forceinline__ float blo(unsigned u) { return __builtin_bit_cast(float, u << 16); }
static __device__ __forceinline__ float bhi(unsigned u) { return __builtin_bit_cast(float, u & 0xffff0000u); }
static __device__ __forceinline__ float bus(u16 u) { return __builtin_bit_cast(float, ((unsigned)u) << 16); }
static __device__ __forceinline__ u16 f2bu(float f) {
  __hip_bfloat16 b = __float2bfloat16(f);
  return __builtin_bit_cast(u16, b);
}
static __device__ __forceinline__ unsigned pack2(float lo, float hi) {
  return (unsigned)f2bu(lo) | ((unsigned)f2bu(hi) << 16);
}

// ---------------- CSR build ----------------

__global__ __launch_bounds__(512) void k_gptr(const int* __restrict__ batch, int* __restrict__ gptr) {
  int g = threadIdx.x;
  if (g > Gg) return;
  if (g == Gg) { gptr[Gg] = Nn; return; }
  int lo = 0, hi = Nn;
  while (lo < hi) { int mid = (lo + hi) >> 1; if (batch[mid] < g) lo = mid + 1; else hi = mid; }
  gptr[g] = lo;
}

__global__ __launch_bounds__(256) void k_deg(const int* __restrict__ dst, int* __restrict__ deg) {
  int e = blockIdx.x * 256 + threadIdx.x;
  if (e < Ee) atomicAdd(&deg[dst[e]], 1);
}

__global__ __launch_bounds__(256) void k_scanA(const int* __restrict__ deg, int* __restrict__ localA,
                                               int* __restrict__ bsum) {
  __shared__ int ts[256];
  int t = threadIdx.x, b = blockIdx.x;
  int base = b * 1024 + t * 4;
  int v[4]; int s = 0;
#pragma unroll
  for (int k = 0; k < 4; k++) { int idx = base + k; v[k] = (idx < Nn) ? deg[idx] : 0; s += v[k]; }
  ts[t] = s; __syncthreads();
  for (int off = 1; off < 256; off <<= 1) {
    int y = (t >= off) ? ts[t - off] : 0;
    __syncthreads();
    ts[t] += y;
    __syncthreads();
  }
  int ex = ts[t] - s;
#pragma unroll
  for (int k = 0; k < 4; k++) { int idx = base + k; if (idx < Nn) localA[idx] = ex; ex += v[k]; }
  if (t == 255) bsum[b] = ts[255];
}

__global__ __launch_bounds__(128) void k_scanB(int* __restrict__ bsum) {
  __shared__ int s[128];
  const int NB = (Nn + 1023) / 1024;
  int t = threadIdx.x;
  int v = (t < NB) ? bsum[t] : 0;
  s[t] = v; __syncthreads();
  for (int off = 1; off < 128; off <<= 1) {
    int y = (t >= off) ? s[t - off] : 0;
    __syncthreads();
    s[t] += y;
    __syncthreads();
  }
  if (t < NB) bsum[t] = s[t] - v;   // exclusive
}

__global__ __launch_bounds__(256) void k_scanC(const int* __restrict__ localA, const int* __restrict__ bsum,
                                               int* __restrict__ rowptr, int* __restrict__ cursor) {
  int i = blockIdx.x * 256 + threadIdx.x;
  if (i < Nn) { int v = localA[i] + bsum[i >> 10]; rowptr[i] = v; cursor[i] = v; }
  if (i == 0) rowptr[Nn] = Ee;
}

__global__ __launch_bounds__(256) void k_fill(const int* __restrict__ dst, int* __restrict__ cursor,
                                              int* __restrict__ elist) {
  int e = blockIdx.x * 256 + threadIdx.x;
  if (e < Ee) { int p = atomicAdd(&cursor[dst[e]], 1); elist[p] = e; }
}

// ---------------- eSum precompute v6 (node-partitioned, direct global write, no eT) ----------------
// eSum[nd] = sum_{e->nd} relu(ea_e@eW+eb). Thread (col-pair jp, sub s) owns cols {2jp,2jp+1}
// of nodes {n0+2s, n0+2s+1}: every (node,col) accumulator is thread-local -> direct float2
// store at the end (zeros included for empty nodes). No eT scratch, no dstl/binary search,
// LDS ~2.7KB -> thread-limited occupancy (~30 waves/CU). ea reads are 2-way LDS broadcasts.
// Also fills srcPerm[q]=srcArr[elist[q]].

#define ES_NODES 8
#define ES_CHUNK 64

__global__ __launch_bounds__(192) void k_esum(const float* __restrict__ eattr,
                                              const int* __restrict__ elist,
                                              const int* __restrict__ srcArr,
                                              const int* __restrict__ rowptr,
                                              const float* __restrict__ eW,
                                              const float* __restrict__ eb,
                                              int* __restrict__ srcPerm,
                                              float* __restrict__ eSum) {
  __shared__ float ea[ES_CHUNK][10];
  __shared__ int rp16[ES_NODES + 1];
  int t = threadIdx.x;
  int n0 = blockIdx.x * ES_NODES;
  if (t <= ES_NODES) rp16[t] = rowptr[min(n0 + t, Nn)];
  int jp = t % 48, sub = t / 48;         // cols j0,j0+1; nodes 2*sub, 2*sub+1
  int j0 = jp * 2;
  float2 wreg[10];
#pragma unroll
  for (int k = 0; k < 10; k++) wreg[k] = *reinterpret_cast<const float2*>(&eW[k * 96 + j0]);
  float2 breg = *reinterpret_cast<const float2*>(&eb[j0]);
  __syncthreads();
  int beg = rp16[0], end = rp16[ES_NODES];
  int nA = 2 * sub, nB = 2 * sub + 1;
  int begA = rp16[nA], endA = rp16[nA + 1];
  int begB = rp16[nB], endB = rp16[nB + 1];
  float aAx = 0.f, aAy = 0.f, aBx = 0.f, aBy = 0.f;
  for (int cs = beg; cs < end; cs += ES_CHUNK) {
    int m = min(ES_CHUNK, end - cs);
    for (int i = t; i < m; i += 192) {
      int q = cs + i;
      srcPerm[q] = srcArr[elist[q]];
    }
    for (int i = t; i < 5 * m; i += 192) {
      int ii = i / 5, k2 = (i - ii * 5) * 2;
      int e = elist[cs + ii];            // redundant load, L1-hit
      *reinterpret_cast<float2*>(&ea[ii][k2]) = *reinterpret_cast<const float2*>(&eattr[(size_t)e * 10 + k2]);
    }
    __syncthreads();
    {
      int lo = max(begA - cs, 0), hi = min(endA - cs, m);
      for (int i = lo; i < hi; i++) {
        float ax = breg.x, ay = breg.y;
#pragma unroll
        for (int k = 0; k < 10; k++) {
          float a = ea[i][k];
          ax += a * wreg[k].x;
          ay += a * wreg[k].y;
        }
        aAx += fmaxf(ax, 0.f);
        aAy += fmaxf(ay, 0.f);
      }
    }
    {
      int lo = max(begB - cs, 0), hi = min(endB - cs, m);
      for (int i = lo; i < hi; i++) {
        float ax = breg.x, ay = breg.y;
#pragma unroll
        for (int k = 0; k < 10; k++) {
          float a = ea[i][k];
          ax += a * wreg[k].x;
          ay += a * wreg[k].y;
        }
        aBx += fmaxf(ax, 0.f);
        aBy += fmaxf(ay, 0.f);
      }
    }
    __syncthreads();   // reads of ea done before next chunk restages
  }
  {
    int n = n0 + nA;
    if (n < Nn) *reinterpret_cast<float2*>(&eSum[(size_t)n * 96 + j0]) = make_float2(aAx, aAy);
    n = n0 + nB;
    if (n < Nn) *reinterpret_cast<float2*>(&eSum[(size_t)n * 96 + j0]) = make_float2(aBx, aBy);
  }
}

// ---------------- node MLP: h16 = relu(x @ W + b), x[N,32] ----------------

__global__ __launch_bounds__(256) void k_node_mlp(const float* __restrict__ x, const float* __restrict__ W,
                                                  const float* __restrict__ b, u16* __restrict__ h16) {
  __shared__ float xs[16][33];
  __shared__ float Ws[32 * 96];
  __shared__ float bs[96];
  int t = threadIdx.x;
  int n0 = blockIdx.x * 16;
  for (int i = t; i < 32 * 96; i += 256) Ws[i] = W[i];
  if (t < 96) bs[t] = b[t];
  for (int i = t; i < 512; i += 256) {
    int nl = i >> 5, k = i & 31; int n = n0 + nl;
    xs[nl][k] = (n < Nn) ? x[n * 32 + k] : 0.f;
  }
  __syncthreads();
#pragma unroll
  for (int p = 0; p < 6; p++) {
    int oi = t + p * 256; int nl = oi / 96, j = oi % 96; int n = n0 + nl;
    if (n < Nn) {
      float acc = bs[j];
#pragma unroll
      for (int k = 0; k < 32; k++) acc += xs[nl][k] * Ws[k * 96 + j];
      h16[(size_t)n * 96 + j] = f2bu(fmaxf(acc, 0.f));
    }
  }
}

// ---------------- FUSED layer kernel v7: 128 nodes/block, 512 threads (8 waves) ----------------

#define MPAD 104
#define BN 128

#define ACC8H(hv, B) \
  acc[B+0] += blo(hv.x); acc[B+1] += bhi(hv.x); acc[B+2] += blo(hv.y); acc[B+3] += bhi(hv.y); \
  acc[B+4] += blo(hv.z); acc[B+5] += bhi(hv.z); acc[B+6] += blo(hv.w); acc[B+7] += bhi(hv.w);

#define LOADH(hp, H0, H1, H2) \
  uint4 H0 = *reinterpret_cast<const uint4*>(hp); \
  uint4 H1 = *reinterpret_cast<const uint4*>(hp + 8); \
  uint4 H2 = *reinterpret_cast<const uint4*>(hp + 16);

__global__ __launch_bounds__(512) void k_layer(const u16* __restrict__ h16,
                                               const int* __restrict__ srcPerm,
                                               const int* __restrict__ rowptr,
                                               const float* __restrict__ eSum,
                                               const float* __restrict__ W1, const float* __restrict__ b1,
                                               const float* __restrict__ W2, const float* __restrict__ b2,
                                               const float* __restrict__ epsA, int layer,
                                               float* __restrict__ z) {
  __shared__ __align__(16) __hip_bfloat16 At[BN][MPAD];   // A-tile, then mid (wave-private rows)
  __shared__ __align__(16) __hip_bfloat16 Wt[96][MPAD];   // Wt[col][k]
  __shared__ int rp[BN + 1];
  int t = threadIdx.x;
  int n0 = blockIdx.x * BN;
  if (t <= BN) rp[t] = rowptr[min(n0 + t, Nn)];
  __syncthreads();
  float epsv = 1.0f + epsA[layer];
  int nl = t >> 2, q = t & 3;            // node-local (0..127), feature-quarter
  int beg = rp[nl], end = rp[nl + 1];
  const size_t fo = (size_t)q * 24;      // feature offset (elements)
  float acc[24];
#pragma unroll
  for (int j = 0; j < 24; j++) acc[j] = 0.f;
  int e = beg;
  for (; e + 4 <= end; e += 4) {
    int s0 = srcPerm[e], s1 = srcPerm[e + 1], s2 = srcPerm[e + 2], s3 = srcPerm[e + 3];
    const u16* hp0 = h16 + (size_t)s0 * 96 + fo;
    const u16* hp1 = h16 + (size_t)s1 * 96 + fo;
    const u16* hp2 = h16 + (size_t)s2 * 96 + fo;
    const u16* hp3 = h16 + (size_t)s3 * 96 + fo;
    LOADH(hp0, ha0, ha1, ha2)
    LOADH(hp1, hb0, hb1, hb2)
    LOADH(hp2, hc0, hc1, hc2)
    LOADH(hp3, hd0, hd1, hd2)
    ACC8H(ha0, 0)
    ACC8H(ha1, 8)
    ACC8H(ha2, 16)
    ACC8H(hb0, 0)
    ACC8H(hb1, 8)
    ACC8H(hb2, 16)
    ACC8H(hc0, 0)
    ACC8H(hc1, 8)
    ACC8H(hc2, 16)
    ACC8H(hd0, 0)
    ACC8H(hd1, 8)
    ACC8H(hd2, 16)
  }
  for (; e < end; e++) {
    int s0 = srcPerm[e];
    const u16* hp0 = h16 + (size_t)s0 * 96 + fo;
    LOADH(hp0, ha0, ha1, ha2)
    ACC8H(ha0, 0)
    ACC8H(ha1, 8)
    ACC8H(ha2, 16)
  }
  {
    int n = n0 + nl;
    uint4 hh0 = make_uint4(0, 0, 0, 0), hh1 = hh0, hh2 = hh0;
    float4 es0 = make_float4(0.f, 0.f, 0.f, 0.f), es1 = es0, es2 = es0, es3 = es0, es4 = es0, es5 = es0;
    if (n < Nn) {
      const u16* hp = h16 + (size_t)n * 96 + fo;
      hh0 = *reinterpret_cast<const uint4*>(hp);
      hh1 = *reinterpret_cast<const uint4*>(hp + 8);
      hh2 = *reinterpret_cast<const uint4*>(hp + 16);
      const float* ep = eSum + (size_t)n * 96 + fo;
      es0 = *reinterpret_cast<const float4*>(ep);
      es1 = *reinterpret_cast<const float4*>(ep + 4);
      es2 = *reinterpret_cast<const float4*>(ep + 8);
      es3 = *reinterpret_cast<const float4*>(ep + 12);
      es4 = *reinterpret_cast<const float4*>(ep + 16);
      es5 = *reinterpret_cast<const float4*>(ep + 20);
    }
    uint4 w0, w1, w2;
    w0.x = pack2(fmaf(epsv, blo(hh0.x), acc[0] + es0.x),  fmaf(epsv, bhi(hh0.x), acc[1] + es0.y));
    w0.y = pack2(fmaf(epsv, blo(hh0.y), acc[2] + es0.z),  fmaf(epsv, bhi(hh0.y), acc[3] + es0.w));
    w0.z = pack2(fmaf(epsv, blo(hh0.z), acc[4] + es1.x),  fmaf(epsv, bhi(hh0.z), acc[5] + es1.y));
    w0.w = pack2(fmaf(epsv, blo(hh0.w), acc[6] + es1.z),  fmaf(epsv, bhi(hh0.w), acc[7] + es1.w));
    w1.x = pack2(fmaf(epsv, blo(hh1.x), acc[8] + es2.x),  fmaf(epsv, bhi(hh1.x), acc[9] + es2.y));
    w1.y = pack2(fmaf(epsv, blo(hh1.y), acc[10] + es2.z), fmaf(epsv, bhi(hh1.y), acc[11] + es2.w));
    w1.z = pack2(fmaf(epsv, blo(hh1.z), acc[12] + es3.x), fmaf(epsv, bhi(hh1.z), acc[13] + es3.y));
    w1.w = pack2(fmaf(epsv, blo(hh1.w), acc[14] + es3.z), fmaf(epsv, bhi(hh1.w), acc[15] + es3.w));
    w2.x = pack2(fmaf(epsv, blo(hh2.x), acc[16] + es4.x), fmaf(epsv, bhi(hh2.x), acc[17] + es4.y));
    w2.y = pack2(fmaf(epsv, blo(hh2.y), acc[18] + es4.z), fmaf(epsv, bhi(hh2.y), acc[19] + es4.w));
    w2.z = pack2(fmaf(epsv, blo(hh2.z), acc[20] + es5.x), fmaf(epsv, bhi(hh2.z), acc[21] + es5.y));
    w2.w = pack2(fmaf(epsv, blo(hh2.w), acc[22] + es5.z), fmaf(epsv, bhi(hh2.w), acc[23] + es5.w));
    *reinterpret_cast<uint4*>(&At[nl][fo]) = w0;
    *reinterpret_cast<uint4*>(&At[nl][fo + 8]) = w1;
    *reinterpret_cast<uint4*>(&At[nl][fo + 16]) = w2;
  }
  // stage W1: k-fast packed writes (c across lanes -> coalesced global reads, uint2 LDS writes)
  for (int i = t; i < 24 * 96; i += 512) {
    int kg = i / 96, c = i - kg * 96;
    int k0 = kg * 4;
    float w0 = W1[(k0 + 0) * 96 + c];
    float w1 = W1[(k0 + 1) * 96 + c];
    float w2 = W1[(k0 + 2) * 96 + c];
    float w3 = W1[(k0 + 3) * 96 + c];
    *reinterpret_cast<uint2*>(&Wt[c][k0]) = make_uint2(pack2(w0, w1), pack2(w2, w3));
  }
  __syncthreads();
  int w = t >> 6, l = t & 63;
  int lr = l & 15, lg = l >> 4;
  int rowBase = w * 16;
  short8 a0 = *reinterpret_cast<const short8*>(&At[rowBase + lr][lg * 8]);
  short8 a1 = *reinterpret_cast<const short8*>(&At[rowBase + lr][32 + lg * 8]);
  short8 a2 = *reinterpret_cast<const short8*>(&At[rowBase + lr][64 + lg * 8]);
  f32x4 gacc[6];
#pragma unroll
  for (int nt = 0; nt < 6; nt++) gacc[nt] = (f32x4){0.f, 0.f, 0.f, 0.f};
#pragma unroll
  for (int nt = 0; nt < 6; nt++) {
    short8 b0 = *reinterpret_cast<const short8*>(&Wt[nt * 16 + lr][lg * 8]);
    short8 bv1 = *reinterpret_cast<const short8*>(&Wt[nt * 16 + lr][32 + lg * 8]);
    short8 bv2 = *reinterpret_cast<const short8*>(&Wt[nt * 16 + lr][64 + lg * 8]);
    gacc[nt] = __builtin_amdgcn_mfma_f32_16x16x32_bf16(a0, b0, gacc[nt], 0, 0, 0);
    gacc[nt] = __builtin_amdgcn_mfma_f32_16x16x32_bf16(a1, bv1, gacc[nt], 0, 0, 0);
    gacc[nt] = __builtin_amdgcn_mfma_f32_16x16x32_bf16(a2, bv2, gacc[nt], 0, 0, 0);
  }
  // mid overwrites A-tile: wave-private rows, a-frags already in registers
#pragma unroll
  for (int nt = 0; nt < 6; nt++) {
    int col = nt * 16 + lr;
    float bias = b1[col];
#pragma unroll
    for (int j = 0; j < 4; j++) {
      int row = rowBase + lg * 4 + j;
      At[row][col] = __float2bfloat16(fmaxf(gacc[nt][j] + bias, 0.f));
    }
  }
  __syncthreads();   // all waves done reading Wt(W1)
  for (int i = t; i < 24 * 96; i += 512) {
    int kg = i / 96, c = i - kg * 96;
    int k0 = kg * 4;
    float w0 = W2[(k0 + 0) * 96 + c];
    float w1 = W2[(k0 + 1) * 96 + c];
    float w2 = W2[(k0 + 2) * 96 + c];
    float w3 = W2[(k0 + 3) * 96 + c];
    *reinterpret_cast<uint2*>(&Wt[c][k0]) = make_uint2(pack2(w0, w1), pack2(w2, w3));
  }
  __syncthreads();
  short8 m0 = *reinterpret_cast<const short8*>(&At[rowBase + lr][lg * 8]);
  short8 m1 = *reinterpret_cast<const short8*>(&At[rowBase + lr][32 + lg * 8]);
  short8 m2 = *reinterpret_cast<const short8*>(&At[rowBase + lr][64 + lg * 8]);
#pragma unroll
  for (int nt = 0; nt < 6; nt++) gacc[nt] = (f32x4){0.f, 0.f, 0.f, 0.f};
#pragma unroll
  for (int nt = 0; nt < 6; nt++) {
    short8 b0 = *reinterpret_cast<const short8*>(&Wt[nt * 16 + lr][lg * 8]);
    short8 bv1 = *reinterpret_cast<const short8*>(&Wt[nt * 16 + lr][32 + lg * 8]);
    short8 bv2 = *reinterpret_cast<const short8*>(&Wt[nt * 16 + lr][64 + lg * 8]);
    gacc[nt] = __builtin_amdgcn_mfma_f32_16x16x32_bf16(m0, b0, gacc[nt], 0, 0, 0);
    gacc[nt] = __builtin_amdgcn_mfma_f32_16x16x32_bf16(m1, bv1, gacc[nt], 0, 0, 0);
    gacc[nt] = __builtin_amdgcn_mfma_f32_16x16x32_bf16(m2, bv2, gacc[nt], 0, 0, 0);
  }
#pragma unroll
  for (int nt = 0; nt < 6; nt++) {
    int col = nt * 16 + lr;
    float bias = b2[col];
#pragma unroll
    for (int j = 0; j < 4; j++) {
      int row = rowBase + lg * 4 + j;
      int n = n0 + row;
      if (n < Nn) z[(size_t)n * 96 + col] = gacc[nt][j] + bias;
    }
  }
}

// ---------------- FUSED GraphNorm: stats + normalize + residual, one block per graph ----------------

__global__ __launch_bounds__(384) void k_gnorm(const float* __restrict__ z, u16* __restrict__ h16,
                                               const int* __restrict__ gptr, const float* __restrict__ ms,
                                               const float* __restrict__ gw, const float* __restrict__ gb) {
  __shared__ float r1[16][100];
  __shared__ float r2[16][100];
  __shared__ float smm[96], sinv[96], sgb[96];
  int g = blockIdx.x, t = threadIdx.x;
  int beg = gptr[g], end = gptr[g + 1];
  int sub = t / 24, slot = t - (t / 24) * 24;
  int sl = slot * 4;
  float4 s1 = make_float4(0.f, 0.f, 0.f, 0.f), s2 = s1;
  for (int n = beg + sub; n < end; n += 16) {
    float4 zv = *reinterpret_cast<const float4*>(z + (size_t)n * 96 + sl);
    s1.x += zv.x; s1.y += zv.y; s1.z += zv.z; s1.w += zv.w;
    s2.x += zv.x * zv.x; s2.y += zv.y * zv.y; s2.z += zv.z * zv.z; s2.w += zv.w * zv.w;
  }
  *reinterpret_cast<float4*>(&r1[sub][sl]) = s1;
  *reinterpret_cast<float4*>(&r2[sub][sl]) = s2;
  __syncthreads();
  if (t < 96) {
    float S1 = 0.f, S2 = 0.f;
#pragma unroll
    for (int u = 0; u < 16; u++) { S1 += r1[u][t]; S2 += r2[u][t]; }
    float c = (float)max(end - beg, 1);
    float m = S1 / c;
    float mm = m * ms[t];
    float var = S2 / c - 2.f * mm * m + mm * mm;
    var = fmaxf(var, 0.f);
    smm[t] = mm;
    sinv[t] = rsqrtf(var + 1e-5f) * gw[t];
    sgb[t] = gb[t];
  }
  __syncthreads();
  float4 mm4 = *reinterpret_cast<const float4*>(&smm[sl]);
  float4 iv4 = *reinterpret_cast<const float4*>(&sinv[sl]);
  float4 gb4 = *reinterpret_cast<const float4*>(&sgb[sl]);
  for (int n = beg + sub; n < end; n += 16) {
    float4 zv = *reinterpret_cast<const float4*>(z + (size_t)n * 96 + sl);
    uint2 hv = *reinterpret_cast<const uint2*>(h16 + (size_t)n * 96 + sl);
    float o0 = fmaxf((zv.x - mm4.x) * iv4.x + gb4.x, 0.f) + blo(hv.x);
    float o1 = fmaxf((zv.y - mm4.y) * iv4.y + gb4.y, 0.f) + bhi(hv.x);
    float o2 = fmaxf((zv.z - mm4.z) * iv4.z + gb4.z, 0.f) + blo(hv.y);
    float o3 = fmaxf((zv.w - mm4.w) * iv4.w + gb4.w, 0.f) + bhi(hv.y);
    *reinterpret_cast<uint2*>(h16 + (size_t)n * 96 + sl) = make_uint2(pack2(o0, o1), pack2(o2, o3));
  }
}

// ---------------- pooling + LayerNorm + output MLP ----------------

__global__ __launch_bounds__(256) void k_pool_out(const u16* __restrict__ h16, const int* __restrict__ gptr,
                                                  const float* __restrict__ lng, const float* __restrict__ lnb,
                                                  const float* __restrict__ W1, const float* __restrict__ b1,
                                                  const float* __restrict__ W2, const float* __restrict__ b2,
                                                  float* __restrict__ out) {
  __shared__ float sh1[2][96], sh2[2][96];
  __shared__ float gbuf[192];
  __shared__ float rs[4], rq[4];
  __shared__ float s_mu, s_rstd;
  __shared__ float inter[96];
  int g = blockIdx.x, t = threadIdx.x;
  int beg = gptr[g], end = gptr[g + 1];
  if (t < 192) {
    int j = t % 96, half = t / 96;
    float s = 0.f, m = -INFINITY;
    for (int n = beg + half; n < end; n += 2) {
      float v = bus(h16[(size_t)n * 96 + j]);
      s += v; m = fmaxf(m, v);
    }
    sh1[half][j] = s; sh2[half][j] = m;
  }
  __syncthreads();
  if (t < 96) {
    float c = (float)max(end - beg, 1);
    gbuf[t] = (sh1[0][t] + sh1[1][t]) / c;
    gbuf[96 + t] = fmaxf(sh2[0][t], sh2[1][t]);
  }
  __syncthreads();
  float sv = (t < 192) ? gbuf[t] : 0.f;
  float qv = sv * sv;
#pragma unroll
  for (int off = 32; off; off >>= 1) { sv += __shfl_down(sv, off); qv += __shfl_down(qv, off); }
  if ((t & 63) == 0) { rs[t >> 6] = sv; rq[t >> 6] = qv; }
  __syncthreads();
  if (t == 0) {
    float S = rs[0] + rs[1] + rs[2] + rs[3];
    float Q = rq[0] + rq[1] + rq[2] + rq[3];
    float mu = S / 192.f;
    float va = Q / 192.f - mu * mu;
    s_mu = mu; s_rstd = rsqrtf(fmaxf(va, 0.f) + 1e-5f);
  }
  __syncthreads();
  if (t < 192) gbuf[t] = (gbuf[t] - s_mu) * s_rstd * lng[t] + lnb[t];
  __syncthreads();
  if (t < 96) {
    float a = b1[t];
    for (int k = 0; k < 192; k++) a += gbuf[k] * W1[k * 96 + t];
    inter[t] = fmaxf(a, 0.f);
  }
  __syncthreads();
  {
    float a = b2[t];
    for (int j = 0; j < 96; j++) a += inter[j] * W2[j * 256 + t];
    out[g * 256 + t] = a;
  }
}

// ---------------- host ----------------

extern "C" void kernel_launch(void* const* d_in, const int* in_sizes, int n_in,
                              void* d_out, int out_size, void* d_ws, size_t ws_size,
                              hipStream_t stream) {
  (void)in_sizes; (void)n_in; (void)out_size; (void)ws_size;
  const float* x     = (const float*)d_in[0];
  const float* eattr = (const float*)d_in[1];
  const int*   eidx2 = (const int*)  d_in[2];
  const int*   batch = (const int*)  d_in[3];
  const float* nodeW = (const float*)d_in[4];
  const float* nodeb = (const float*)d_in[5];
  const float* edgeW = (const float*)d_in[6];
  const float* edgeb = (const float*)d_in[7];
  const float* mlpW1 = (const float*)d_in[8];
  const float* mlpb1 = (const float*)d_in[9];
  const float* mlpW2 = (const float*)d_in[10];
  const float* mlpb2 = (const float*)d_in[11];
  const float* epsA  = (const float*)d_in[12];
  const float* gnw   = (const float*)d_in[13];
  const float* gnb   = (const float*)d_in[14];
  const float* gnms  = (const float*)d_in[15];
  const float* lng   = (const float*)d_in[16];
  const float* lnb   = (const float*)d_in[17];
  const float* oW1   = (const float*)d_in[18];
  const float* ob1   = (const float*)d_in[19];
  const float* oW2   = (const float*)d_in[20];
  const float* ob2   = (const float*)d_in[21];
  float* out = (float*)d_out;

  const int* srcArr = eidx2;        // edge_index[0]
  const int* dstArr = eidx2 + Ee;   // edge_index[1]

  char* p = (char*)d_ws;
  auto carve = [&](size_t bytes) -> void* {
    void* r = (void*)p;
    p += ((bytes + 255) & ~(size_t)255);
    return r;
  };
  // Total ~105 MB.
  u16* h16     = (u16*)carve((size_t)Nn * 96 * 2);     // h state, bf16
  float* aggz  = (float*)carve((size_t)Nn * 96 * 4);   // z (f32)
  float* eSum  = (float*)carve((size_t)Nn * 96 * 4);   // layer-invariant edge-message sums (f32)
  int* rowptr  = (int*)carve((size_t)(Nn + 1) * 4);
  int* elist   = (int*)carve((size_t)Ee * 4);
  int* gptr    = (int*)carve((size_t)(Gg + 1) * 4);
  // srcPerm (Ee ints) doubles as CSR temp space (deg/localA/cursor/bsum, 3*Nn+NB ints < Ee).
  int* srcPerm = (int*)carve((size_t)Ee * 4);
  int* deg     = srcPerm;
  int* localA  = srcPerm + Nn;
  int* cursor  = srcPerm + 2 * Nn;
  int* bsum    = srcPerm + 3 * Nn;

  hipMemsetAsync(deg, 0, (size_t)Nn * 4, stream);
  k_gptr<<<1, 512, 0, stream>>>(batch, gptr);
  k_deg<<<(Ee + 255) / 256, 256, 0, stream>>>(dstArr, deg);
  k_scanA<<<(Nn + 1023) / 1024, 256, 0, stream>>>(deg, localA, bsum);
  k_scanB<<<1, 128, 0, stream>>>(bsum);
  k_scanC<<<(Nn + 255) / 256, 256, 0, stream>>>(localA, bsum, rowptr, cursor);
  k_fill<<<(Ee + 255) / 256, 256, 0, stream>>>(dstArr, cursor, elist);

  // eSum precompute (v6 node-partitioned; also writes srcPerm over dead CSR temps)
  k_esum<<<(Nn + ES_NODES - 1) / ES_NODES, 192, 0, stream>>>(eattr, elist, srcArr, rowptr,
                                                             edgeW, edgeb, srcPerm, eSum);

  k_node_mlp<<<(Nn + 15) / 16, 256, 0, stream>>>(x, nodeW, nodeb, h16);

  for (int i = 0; i < 3; i++) {
    k_layer<<<(Nn + BN - 1) / BN, 512, 0, stream>>>(h16, srcPerm, rowptr, eSum,
                                                    mlpW1 + i * 9216, mlpb1 + i * 96,
                                                    mlpW2 + i * 9216, mlpb2 + i * 96, epsA, i, aggz);
    k_gnorm<<<Gg, 384, 0, stream>>>(aggz, h16, gptr, gnms + i * 96, gnw + i * 96, gnb + i * 96);
  }

  k_pool_out<<<Gg, 256, 0, stream>>>(h16, gptr, lng, lnb, oW1, ob1, oW2, ob2, out);
}

// Round 22
// 478.013 us; speedup vs baseline: 1.8449x; 1.0216x over previous
//
#include <hip/hip_runtime.h>
#include <hip/hip_bf16.h>
#include <cfloat>

#define Nn 100000
#define Ee 800000
#define Gg 256
// H=96, NI=32, EI=10, OUT=256, L=3

typedef __attribute__((ext_vector_type(8))) short short8;
typedef __attribute__((ext_vector_type(4))) float f32x4;
typedef unsigned short u16;

static __device__ __forceinline__ float blo(unsigned u) { return __builtin_bit_cast(float, u << 16); }
static __device__ __forceinline__ float bhi(unsigned u) { return __builtin_bit_cast(float, u & 0xffff0000u); }
static __device__ __forceinline__ float bus(u16 u) { return __builtin_bit_cast(float, ((unsigned)u) << 16); }
static __device__ __forceinline__ u16 f2bu(float f) {
  __hip_bfloat16 b = __float2bfloat16(f);
  return __builtin_bit_cast(u16, b);
}
static __device__ __forceinline__ unsigned pack2(float lo, float hi) {
  return (unsigned)f2bu(lo) | ((unsigned)f2bu(hi) << 16);
}

// ---------------- CSR build ----------------

__global__ __launch_bounds__(512) void k_gptr(const int* __restrict__ batch, int* __restrict__ gptr) {
  int g = threadIdx.x;
  if (g > Gg) return;
  if (g == Gg) { gptr[Gg] = Nn; return; }
  int lo = 0, hi = Nn;
  while (lo < hi) { int mid = (lo + hi) >> 1; if (batch[mid] < g) lo = mid + 1; else hi = mid; }
  gptr[g] = lo;
}

__global__ __launch_bounds__(256) void k_deg(const int* __restrict__ dst, int* __restrict__ deg) {
  int e = blockIdx.x * 256 + threadIdx.x;
  if (e < Ee) atomicAdd(&deg[dst[e]], 1);
}

__global__ __launch_bounds__(256) void k_scanA(const int* __restrict__ deg, int* __restrict__ localA,
                                               int* __restrict__ bsum) {
  __shared__ int ts[256];
  int t = threadIdx.x, b = blockIdx.x;
  int base = b * 1024 + t * 4;
  int v[4]; int s = 0;
#pragma unroll
  for (int k = 0; k < 4; k++) { int idx = base + k; v[k] = (idx < Nn) ? deg[idx] : 0; s += v[k]; }
  ts[t] = s; __syncthreads();
  for (int off = 1; off < 256; off <<= 1) {
    int y = (t >= off) ? ts[t - off] : 0;
    __syncthreads();
    ts[t] += y;
    __syncthreads();
  }
  int ex = ts[t] - s;
#pragma unroll
  for (int k = 0; k < 4; k++) { int idx = base + k; if (idx < Nn) localA[idx] = ex; ex += v[k]; }
  if (t == 255) bsum[b] = ts[255];
}

__global__ __launch_bounds__(128) void k_scanB(int* __restrict__ bsum) {
  __shared__ int s[128];
  const int NB = (Nn + 1023) / 1024;
  int t = threadIdx.x;
  int v = (t < NB) ? bsum[t] : 0;
  s[t] = v; __syncthreads();
  for (int off = 1; off < 128; off <<= 1) {
    int y = (t >= off) ? s[t - off] : 0;
    __syncthreads();
    s[t] += y;
    __syncthreads();
  }
  if (t < NB) bsum[t] = s[t] - v;   // exclusive
}

__global__ __launch_bounds__(256) void k_scanC(const int* __restrict__ localA, const int* __restrict__ bsum,
                                               int* __restrict__ rowptr, int* __restrict__ cursor) {
  int i = blockIdx.x * 256 + threadIdx.x;
  if (i < Nn) { int v = localA[i] + bsum[i >> 10]; rowptr[i] = v; cursor[i] = v; }
  if (i == 0) rowptr[Nn] = Ee;
}

__global__ __launch_bounds__(256) void k_fill(const int* __restrict__ dst, int* __restrict__ cursor,
                                              int* __restrict__ elist) {
  int e = blockIdx.x * 256 + threadIdx.x;
  if (e < Ee) { int p = atomicAdd(&cursor[dst[e]], 1); elist[p] = e; }
}

// ---------------- eSum precompute (v5, proven 65us): scalar 2 cols/thread, run-length regs ----------------

#define ES_NODES 8
#define ES_CHUNK 64

__global__ __launch_bounds__(192) void k_esum(const float* __restrict__ eattr,
                                              const int* __restrict__ elist,
                                              const int* __restrict__ srcArr,
                                              const int* __restrict__ rowptr,
                                              const float* __restrict__ eW,
                                              const float* __restrict__ eb,
                                              int* __restrict__ srcPerm,
                                              float* __restrict__ eSum) {
  __shared__ float ea[ES_CHUNK][10];
  __shared__ int dstl[ES_CHUNK];
  __shared__ float eT[4][ES_NODES][96];
  __shared__ int rp16[ES_NODES + 1];
  int t = threadIdx.x;
  int n0 = blockIdx.x * ES_NODES;
  if (t <= ES_NODES) rp16[t] = rowptr[min(n0 + t, Nn)];
  for (int i = t; i < 4 * ES_NODES * 96; i += 192) ((float*)eT)[i] = 0.f;
  int jp = t % 48, sub = t / 48;         // cols j0, j0+1; edge stride 4
  int j0 = jp * 2;
  float2 wreg[10];
#pragma unroll
  for (int k = 0; k < 10; k++) wreg[k] = *reinterpret_cast<const float2*>(&eW[k * 96 + j0]);
  float2 breg = *reinterpret_cast<const float2*>(&eb[j0]);
  __syncthreads();
  int beg = rp16[0], end = rp16[ES_NODES];
  float raccx = 0.f, raccy = 0.f;
  int rdst = -1;
  for (int cs = beg; cs < end; cs += ES_CHUNK) {
    int m = min(ES_CHUNK, end - cs);
    for (int i = t; i < m; i += 192) {
      int q = cs + i;
      int e = elist[q];
      srcPerm[q] = srcArr[e];
      int lo = 0, hi = ES_NODES - 1;
      while (lo < hi) { int mid = (lo + hi + 1) >> 1; if (rp16[mid] <= q) lo = mid; else hi = mid - 1; }
      dstl[i] = lo;
    }
    for (int i = t; i < 5 * m; i += 192) {
      int ii = i / 5, k2 = (i - ii * 5) * 2;
      int e = elist[cs + ii];            // redundant load, L1-hit
      *reinterpret_cast<float2*>(&ea[ii][k2]) = *reinterpret_cast<const float2*>(&eattr[(size_t)e * 10 + k2]);
    }
    __syncthreads();
    for (int i = sub; i < m; i += 4) {
      float ax = breg.x, ay = breg.y;
#pragma unroll
      for (int k = 0; k < 10; k++) {
        float a = ea[i][k];
        ax += a * wreg[k].x;
        ay += a * wreg[k].y;
      }
      ax = fmaxf(ax, 0.f);
      ay = fmaxf(ay, 0.f);
      int d = dstl[i];
      if (d != rdst) {
        if (rdst >= 0) {
          eT[sub][rdst][j0]     += raccx;
          eT[sub][rdst][j0 + 1] += raccy;
        }
        rdst = d; raccx = ax; raccy = ay;
      } else {
        raccx += ax; raccy += ay;
      }
    }
    __syncthreads();   // accumulate reads of ea/dstl done before next chunk restages
  }
  if (rdst >= 0) {
    eT[sub][rdst][j0]     += raccx;
    eT[sub][rdst][j0 + 1] += raccy;
  }
  __syncthreads();
  for (int i = t; i < ES_NODES * 96; i += 192) {
    int nl = i / 96, jj = i - nl * 96;
    int n = n0 + nl;
    if (n < Nn) eSum[(size_t)n * 96 + jj] = eT[0][nl][jj] + eT[1][nl][jj] + eT[2][nl][jj] + eT[3][nl][jj];
  }
}

// ---------------- node MLP: h16 = relu(x @ W + b), x[N,32] ----------------

__global__ __launch_bounds__(256) void k_node_mlp(const float* __restrict__ x, const float* __restrict__ W,
                                                  const float* __restrict__ b, u16* __restrict__ h16) {
  __shared__ float xs[16][33];
  __shared__ float Ws[32 * 96];
  __shared__ float bs[96];
  int t = threadIdx.x;
  int n0 = blockIdx.x * 16;
  for (int i = t; i < 32 * 96; i += 256) Ws[i] = W[i];
  if (t < 96) bs[t] = b[t];
  for (int i = t; i < 512; i += 256) {
    int nl = i >> 5, k = i & 31; int n = n0 + nl;
    xs[nl][k] = (n < Nn) ? x[n * 32 + k] : 0.f;
  }
  __syncthreads();
#pragma unroll
  for (int p = 0; p < 6; p++) {
    int oi = t + p * 256; int nl = oi / 96, j = oi % 96; int n = n0 + nl;
    if (n < Nn) {
      float acc = bs[j];
#pragma unroll
      for (int k = 0; k < 32; k++) acc += xs[nl][k] * Ws[k * 96 + j];
      h16[(size_t)n * 96 + j] = f2bu(fmaxf(acc, 0.f));
    }
  }
}

// ---------------- FUSED layer kernel v7: 128 nodes/block, 512 threads (8 waves) ----------------

#define MPAD 104
#define BN 128

#define ACC8H(hv, B) \
  acc[B+0] += blo(hv.x); acc[B+1] += bhi(hv.x); acc[B+2] += blo(hv.y); acc[B+3] += bhi(hv.y); \
  acc[B+4] += blo(hv.z); acc[B+5] += bhi(hv.z); acc[B+6] += blo(hv.w); acc[B+7] += bhi(hv.w);

#define LOADH(hp, H0, H1, H2) \
  uint4 H0 = *reinterpret_cast<const uint4*>(hp); \
  uint4 H1 = *reinterpret_cast<const uint4*>(hp + 8); \
  uint4 H2 = *reinterpret_cast<const uint4*>(hp + 16);

__global__ __launch_bounds__(512) void k_layer(const u16* __restrict__ h16,
                                               const int* __restrict__ srcPerm,
                                               const int* __restrict__ rowptr,
                                               const float* __restrict__ eSum,
                                               const float* __restrict__ W1, const float* __restrict__ b1,
                                               const float* __restrict__ W2, const float* __restrict__ b2,
                                               const float* __restrict__ epsA, int layer,
                                               float* __restrict__ z) {
  __shared__ __align__(16) __hip_bfloat16 At[BN][MPAD];   // A-tile, then mid (wave-private rows)
  __shared__ __align__(16) __hip_bfloat16 Wt[96][MPAD];   // Wt[col][k]
  __shared__ int rp[BN + 1];
  int t = threadIdx.x;
  int n0 = blockIdx.x * BN;
  if (t <= BN) rp[t] = rowptr[min(n0 + t, Nn)];
  __syncthreads();
  float epsv = 1.0f + epsA[layer];
  int nl = t >> 2, q = t & 3;            // node-local (0..127), feature-quarter
  int beg = rp[nl], end = rp[nl + 1];
  const size_t fo = (size_t)q * 24;      // feature offset (elements)
  float acc[24];
#pragma unroll
  for (int j = 0; j < 24; j++) acc[j] = 0.f;
  int e = beg;
  for (; e + 4 <= end; e += 4) {
    int s0 = srcPerm[e], s1 = srcPerm[e + 1], s2 = srcPerm[e + 2], s3 = srcPerm[e + 3];
    const u16* hp0 = h16 + (size_t)s0 * 96 + fo;
    const u16* hp1 = h16 + (size_t)s1 * 96 + fo;
    const u16* hp2 = h16 + (size_t)s2 * 96 + fo;
    const u16* hp3 = h16 + (size_t)s3 * 96 + fo;
    LOADH(hp0, ha0, ha1, ha2)
    LOADH(hp1, hb0, hb1, hb2)
    LOADH(hp2, hc0, hc1, hc2)
    LOADH(hp3, hd0, hd1, hd2)
    ACC8H(ha0, 0)
    ACC8H(ha1, 8)
    ACC8H(ha2, 16)
    ACC8H(hb0, 0)
    ACC8H(hb1, 8)
    ACC8H(hb2, 16)
    ACC8H(hc0, 0)
    ACC8H(hc1, 8)
    ACC8H(hc2, 16)
    ACC8H(hd0, 0)
    ACC8H(hd1, 8)
    ACC8H(hd2, 16)
  }
  for (; e < end; e++) {
    int s0 = srcPerm[e];
    const u16* hp0 = h16 + (size_t)s0 * 96 + fo;
    LOADH(hp0, ha0, ha1, ha2)
    ACC8H(ha0, 0)
    ACC8H(ha1, 8)
    ACC8H(ha2, 16)
  }
  {
    int n = n0 + nl;
    uint4 hh0 = make_uint4(0, 0, 0, 0), hh1 = hh0, hh2 = hh0;
    float4 es0 = make_float4(0.f, 0.f, 0.f, 0.f), es1 = es0, es2 = es0, es3 = es0, es4 = es0, es5 = es0;
    if (n < Nn) {
      const u16* hp = h16 + (size_t)n * 96 + fo;
      hh0 = *reinterpret_cast<const uint4*>(hp);
      hh1 = *reinterpret_cast<const uint4*>(hp + 8);
      hh2 = *reinterpret_cast<const uint4*>(hp + 16);
      const float* ep = eSum + (size_t)n * 96 + fo;
      es0 = *reinterpret_cast<const float4*>(ep);
      es1 = *reinterpret_cast<const float4*>(ep + 4);
      es2 = *reinterpret_cast<const float4*>(ep + 8);
      es3 = *reinterpret_cast<const float4*>(ep + 12);
      es4 = *reinterpret_cast<const float4*>(ep + 16);
      es5 = *reinterpret_cast<const float4*>(ep + 20);
    }
    uint4 w0, w1, w2;
    w0.x = pack2(fmaf(epsv, blo(hh0.x), acc[0] + es0.x),  fmaf(epsv, bhi(hh0.x), acc[1] + es0.y));
    w0.y = pack2(fmaf(epsv, blo(hh0.y), acc[2] + es0.z),  fmaf(epsv, bhi(hh0.y), acc[3] + es0.w));
    w0.z = pack2(fmaf(epsv, blo(hh0.z), acc[4] + es1.x),  fmaf(epsv, bhi(hh0.z), acc[5] + es1.y));
    w0.w = pack2(fmaf(epsv, blo(hh0.w), acc[6] + es1.z),  fmaf(epsv, bhi(hh0.w), acc[7] + es1.w));
    w1.x = pack2(fmaf(epsv, blo(hh1.x), acc[8] + es2.x),  fmaf(epsv, bhi(hh1.x), acc[9] + es2.y));
    w1.y = pack2(fmaf(epsv, blo(hh1.y), acc[10] + es2.z), fmaf(epsv, bhi(hh1.y), acc[11] + es2.w));
    w1.z = pack2(fmaf(epsv, blo(hh1.z), acc[12] + es3.x), fmaf(epsv, bhi(hh1.z), acc[13] + es3.y));
    w1.w = pack2(fmaf(epsv, blo(hh1.w), acc[14] + es3.z), fmaf(epsv, bhi(hh1.w), acc[15] + es3.w));
    w2.x = pack2(fmaf(epsv, blo(hh2.x), acc[16] + es4.x), fmaf(epsv, bhi(hh2.x), acc[17] + es4.y));
    w2.y = pack2(fmaf(epsv, blo(hh2.y), acc[18] + es4.z), fmaf(epsv, bhi(hh2.y), acc[19] + es4.w));
    w2.z = pack2(fmaf(epsv, blo(hh2.z), acc[20] + es5.x), fmaf(epsv, bhi(hh2.z), acc[21] + es5.y));
    w2.w = pack2(fmaf(epsv, blo(hh2.w), acc[22] + es5.z), fmaf(epsv, bhi(hh2.w), acc[23] + es5.w));
    *reinterpret_cast<uint4*>(&At[nl][fo]) = w0;
    *reinterpret_cast<uint4*>(&At[nl][fo + 8]) = w1;
    *reinterpret_cast<uint4*>(&At[nl][fo + 16]) = w2;
  }
  // stage W1: k-fast packed writes (c across lanes -> coalesced global reads, uint2 LDS writes)
  for (int i = t; i < 24 * 96; i += 512) {
    int kg = i / 96, c = i - kg * 96;
    int k0 = kg * 4;
    float w0 = W1[(k0 + 0) * 96 + c];
    float w1 = W1[(k0 + 1) * 96 + c];
    float w2 = W1[(k0 + 2) * 96 + c];
    float w3 = W1[(k0 + 3) * 96 + c];
    *reinterpret_cast<uint2*>(&Wt[c][k0]) = make_uint2(pack2(w0, w1), pack2(w2, w3));
  }
  __syncthreads();
  int w = t >> 6, l = t & 63;
  int lr = l & 15, lg = l >> 4;
  int rowBase = w * 16;
  short8 a0 = *reinterpret_cast<const short8*>(&At[rowBase + lr][lg * 8]);
  short8 a1 = *reinterpret_cast<const short8*>(&At[rowBase + lr][32 + lg * 8]);
  short8 a2 = *reinterpret_cast<const short8*>(&At[rowBase + lr][64 + lg * 8]);
  f32x4 gacc[6];
#pragma unroll
  for (int nt = 0; nt < 6; nt++) gacc[nt] = (f32x4){0.f, 0.f, 0.f, 0.f};
#pragma unroll
  for (int nt = 0; nt < 6; nt++) {
    short8 b0 = *reinterpret_cast<const short8*>(&Wt[nt * 16 + lr][lg * 8]);
    short8 bv1 = *reinterpret_cast<const short8*>(&Wt[nt * 16 + lr][32 + lg * 8]);
    short8 bv2 = *reinterpret_cast<const short8*>(&Wt[nt * 16 + lr][64 + lg * 8]);
    gacc[nt] = __builtin_amdgcn_mfma_f32_16x16x32_bf16(a0, b0, gacc[nt], 0, 0, 0);
    gacc[nt] = __builtin_amdgcn_mfma_f32_16x16x32_bf16(a1, bv1, gacc[nt], 0, 0, 0);
    gacc[nt] = __builtin_amdgcn_mfma_f32_16x16x32_bf16(a2, bv2, gacc[nt], 0, 0, 0);
  }
  // mid overwrites A-tile: wave-private rows, a-frags already in registers
#pragma unroll
  for (int nt = 0; nt < 6; nt++) {
    int col = nt * 16 + lr;
    float bias = b1[col];
#pragma unroll
    for (int j = 0; j < 4; j++) {
      int row = rowBase + lg * 4 + j;
      At[row][col] = __float2bfloat16(fmaxf(gacc[nt][j] + bias, 0.f));
    }
  }
  __syncthreads();   // all waves done reading Wt(W1)
  for (int i = t; i < 24 * 96; i += 512) {
    int kg = i / 96, c = i - kg * 96;
    int k0 = kg * 4;
    float w0 = W2[(k0 + 0) * 96 + c];
    float w1 = W2[(k0 + 1) * 96 + c];
    float w2 = W2[(k0 + 2) * 96 + c];
    float w3 = W2[(k0 + 3) * 96 + c];
    *reinterpret_cast<uint2*>(&Wt[c][k0]) = make_uint2(pack2(w0, w1), pack2(w2, w3));
  }
  __syncthreads();
  short8 m0 = *reinterpret_cast<const short8*>(&At[rowBase + lr][lg * 8]);
  short8 m1 = *reinterpret_cast<const short8*>(&At[rowBase + lr][32 + lg * 8]);
  short8 m2 = *reinterpret_cast<const short8*>(&At[rowBase + lr][64 + lg * 8]);
#pragma unroll
  for (int nt = 0; nt < 6; nt++) gacc[nt] = (f32x4){0.f, 0.f, 0.f, 0.f};
#pragma unroll
  for (int nt = 0; nt < 6; nt++) {
    short8 b0 = *reinterpret_cast<const short8*>(&Wt[nt * 16 + lr][lg * 8]);
    short8 bv1 = *reinterpret_cast<const short8*>(&Wt[nt * 16 + lr][32 + lg * 8]);
    short8 bv2 = *reinterpret_cast<const short8*>(&Wt[nt * 16 + lr][64 + lg * 8]);
    gacc[nt] = __builtin_amdgcn_mfma_f32_16x16x32_bf16(m0, b0, gacc[nt], 0, 0, 0);
    gacc[nt] = __builtin_amdgcn_mfma_f32_16x16x32_bf16(m1, bv1, gacc[nt], 0, 0, 0);
    gacc[nt] = __builtin_amdgcn_mfma_f32_16x16x32_bf16(m2, bv2, gacc[nt], 0, 0, 0);
  }
#pragma unroll
  for (int nt = 0; nt < 6; nt++) {
    int col = nt * 16 + lr;
    float bias = b2[col];
#pragma unroll
    for (int j = 0; j < 4; j++) {
      int row = rowBase + lg * 4 + j;
      int n = n0 + row;
      if (n < Nn) z[(size_t)n * 96 + col] = gacc[nt][j] + bias;
    }
  }
}

// ---------------- FUSED GraphNorm v3: 768 threads (32 node-subsets) for latency hiding ----------------

__global__ __launch_bounds__(768) void k_gnorm(const float* __restrict__ z, u16* __restrict__ h16,
                                               const int* __restrict__ gptr, const float* __restrict__ ms,
                                               const float* __restrict__ gw, const float* __restrict__ gb) {
  __shared__ float r1[32][100];
  __shared__ float r2[32][100];
  __shared__ float smm[96], sinv[96], sgb[96];
  int g = blockIdx.x, t = threadIdx.x;
  int beg = gptr[g], end = gptr[g + 1];
  int sub = t / 24, slot = t - (t / 24) * 24;
  int sl = slot * 4;
  float4 s1 = make_float4(0.f, 0.f, 0.f, 0.f), s2 = s1;
  for (int n = beg + sub; n < end; n += 32) {
    float4 zv = *reinterpret_cast<const float4*>(z + (size_t)n * 96 + sl);
    s1.x += zv.x; s1.y += zv.y; s1.z += zv.z; s1.w += zv.w;
    s2.x += zv.x * zv.x; s2.y += zv.y * zv.y; s2.z += zv.z * zv.z; s2.w += zv.w * zv.w;
  }
  *reinterpret_cast<float4*>(&r1[sub][sl]) = s1;
  *reinterpret_cast<float4*>(&r2[sub][sl]) = s2;
  __syncthreads();
  if (t < 96) {
    float S1 = 0.f, S2 = 0.f;
#pragma unroll
    for (int u = 0; u < 32; u++) { S1 += r1[u][t]; S2 += r2[u][t]; }
    float c = (float)max(end - beg, 1);
    float m = S1 / c;
    float mm = m * ms[t];
    float var = S2 / c - 2.f * mm * m + mm * mm;
    var = fmaxf(var, 0.f);
    smm[t] = mm;
    sinv[t] = rsqrtf(var + 1e-5f) * gw[t];
    sgb[t] = gb[t];
  }
  __syncthreads();
  float4 mm4 = *reinterpret_cast<const float4*>(&smm[sl]);
  float4 iv4 = *reinterpret_cast<const float4*>(&sinv[sl]);
  float4 gb4 = *reinterpret_cast<const float4*>(&sgb[sl]);
  for (int n = beg + sub; n < end; n += 32) {
    float4 zv = *reinterpret_cast<const float4*>(z + (size_t)n * 96 + sl);
    uint2 hv = *reinterpret_cast<const uint2*>(h16 + (size_t)n * 96 + sl);
    float o0 = fmaxf((zv.x - mm4.x) * iv4.x + gb4.x, 0.f) + blo(hv.x);
    float o1 = fmaxf((zv.y - mm4.y) * iv4.y + gb4.y, 0.f) + bhi(hv.x);
    float o2 = fmaxf((zv.z - mm4.z) * iv4.z + gb4.z, 0.f) + blo(hv.y);
    float o3 = fmaxf((zv.w - mm4.w) * iv4.w + gb4.w, 0.f) + bhi(hv.y);
    *reinterpret_cast<uint2*>(h16 + (size_t)n * 96 + sl) = make_uint2(pack2(o0, o1), pack2(o2, o3));
  }
}

// ---------------- pooling + LayerNorm + output MLP ----------------

__global__ __launch_bounds__(256) void k_pool_out(const u16* __restrict__ h16, const int* __restrict__ gptr,
                                                  const float* __restrict__ lng, const float* __restrict__ lnb,
                                                  const float* __restrict__ W1, const float* __restrict__ b1,
                                                  const float* __restrict__ W2, const float* __restrict__ b2,
                                                  float* __restrict__ out) {
  __shared__ float sh1[2][96], sh2[2][96];
  __shared__ float gbuf[192];
  __shared__ float rs[4], rq[4];
  __shared__ float s_mu, s_rstd;
  __shared__ float inter[96];
  int g = blockIdx.x, t = threadIdx.x;
  int beg = gptr[g], end = gptr[g + 1];
  if (t < 192) {
    int j = t % 96, half = t / 96;
    float s = 0.f, m = -INFINITY;
    for (int n = beg + half; n < end; n += 2) {
      float v = bus(h16[(size_t)n * 96 + j]);
      s += v; m = fmaxf(m, v);
    }
    sh1[half][j] = s; sh2[half][j] = m;
  }
  __syncthreads();
  if (t < 96) {
    float c = (float)max(end - beg, 1);
    gbuf[t] = (sh1[0][t] + sh1[1][t]) / c;
    gbuf[96 + t] = fmaxf(sh2[0][t], sh2[1][t]);
  }
  __syncthreads();
  float sv = (t < 192) ? gbuf[t] : 0.f;
  float qv = sv * sv;
#pragma unroll
  for (int off = 32; off; off >>= 1) { sv += __shfl_down(sv, off); qv += __shfl_down(qv, off); }
  if ((t & 63) == 0) { rs[t >> 6] = sv; rq[t >> 6] = qv; }
  __syncthreads();
  if (t == 0) {
    float S = rs[0] + rs[1] + rs[2] + rs[3];
    float Q = rq[0] + rq[1] + rq[2] + rq[3];
    float mu = S / 192.f;
    float va = Q / 192.f - mu * mu;
    s_mu = mu; s_rstd = rsqrtf(fmaxf(va, 0.f) + 1e-5f);
  }
  __syncthreads();
  if (t < 192) gbuf[t] = (gbuf[t] - s_mu) * s_rstd * lng[t] + lnb[t];
  __syncthreads();
  if (t < 96) {
    float a = b1[t];
    for (int k = 0; k < 192; k++) a += gbuf[k] * W1[k * 96 + t];
    inter[t] = fmaxf(a, 0.f);
  }
  __syncthreads();
  {
    float a = b2[t];
    for (int j = 0; j < 96; j++) a += inter[j] * W2[j * 256 + t];
    out[g * 256 + t] = a;
  }
}

// ---------------- host ----------------

extern "C" void kernel_launch(void* const* d_in, const int* in_sizes, int n_in,
                              void* d_out, int out_size, void* d_ws, size_t ws_size,
                              hipStream_t stream) {
  (void)in_sizes; (void)n_in; (void)out_size; (void)ws_size;
  const float* x     = (const float*)d_in[0];
  const float* eattr = (const float*)d_in[1];
  const int*   eidx2 = (const int*)  d_in[2];
  const int*   batch = (const int*)  d_in[3];
  const float* nodeW = (const float*)d_in[4];
  const float* nodeb = (const float*)d_in[5];
  const float* edgeW = (const float*)d_in[6];
  const float* edgeb = (const float*)d_in[7];
  const float* mlpW1 = (const float*)d_in[8];
  const float* mlpb1 = (const float*)d_in[9];
  const float* mlpW2 = (const float*)d_in[10];
  const float* mlpb2 = (const float*)d_in[11];
  const float* epsA  = (const float*)d_in[12];
  const float* gnw   = (const float*)d_in[13];
  const float* gnb   = (const float*)d_in[14];
  const float* gnms  = (const float*)d_in[15];
  const float* lng   = (const float*)d_in[16];
  const float* lnb   = (const float*)d_in[17];
  const float* oW1   = (const float*)d_in[18];
  const float* ob1   = (const float*)d_in[19];
  const float* oW2   = (const float*)d_in[20];
  const float* ob2   = (const float*)d_in[21];
  float* out = (float*)d_out;

  const int* srcArr = eidx2;        // edge_index[0]
  const int* dstArr = eidx2 + Ee;   // edge_index[1]

  char* p = (char*)d_ws;
  auto carve = [&](size_t bytes) -> void* {
    void* r = (void*)p;
    p += ((bytes + 255) & ~(size_t)255);
    return r;
  };
  // Total ~105 MB.
  u16* h16     = (u16*)carve((size_t)Nn * 96 * 2);     // h state, bf16
  float* aggz  = (float*)carve((size_t)Nn * 96 * 4);   // z (f32)
  float* eSum  = (float*)carve((size_t)Nn * 96 * 4);   // layer-invariant edge-message sums (f32)
  int* rowptr  = (int*)carve((size_t)(Nn + 1) * 4);
  int* elist   = (int*)carve((size_t)Ee * 4);
  int* gptr    = (int*)carve((size_t)(Gg + 1) * 4);
  // srcPerm (Ee ints) doubles as CSR temp space (deg/localA/cursor/bsum, 3*Nn+NB ints < Ee).
  int* srcPerm = (int*)carve((size_t)Ee * 4);
  int* deg     = srcPerm;
  int* localA  = srcPerm + Nn;
  int* cursor  = srcPerm + 2 * Nn;
  int* bsum    = srcPerm + 3 * Nn;

  hipMemsetAsync(deg, 0, (size_t)Nn * 4, stream);
  k_gptr<<<1, 512, 0, stream>>>(batch, gptr);
  k_deg<<<(Ee + 255) / 256, 256, 0, stream>>>(dstArr, deg);
  k_scanA<<<(Nn + 1023) / 1024, 256, 0, stream>>>(deg, localA, bsum);
  k_scanB<<<1, 128, 0, stream>>>(bsum);
  k_scanC<<<(Nn + 255) / 256, 256, 0, stream>>>(localA, bsum, rowptr, cursor);
  k_fill<<<(Ee + 255) / 256, 256, 0, stream>>>(dstArr, cursor, elist);

  // eSum precompute (v5; also writes srcPerm over dead CSR temps)
  k_esum<<<(Nn + ES_NODES - 1) / ES_NODES, 192, 0, stream>>>(eattr, elist, srcArr, rowptr,
                                                             edgeW, edgeb, srcPerm, eSum);

  k_node_mlp<<<(Nn + 15) / 16, 256, 0, stream>>>(x, nodeW, nodeb, h16);

  for (int i = 0; i < 3; i++) {
    k_layer<<<(Nn + BN - 1) / BN, 512, 0, stream>>>(h16, srcPerm, rowptr, eSum,
                                                    mlpW1 + i * 9216, mlpb1 + i * 96,
                                                    mlpW2 + i * 9216, mlpb2 + i * 96, epsA, i, aggz);
    k_gnorm<<<Gg, 768, 0, stream>>>(aggz, h16, gptr, gnms + i * 96, gnw + i * 96, gnb + i * 96);
  }

  k_pool_out<<<Gg, 256, 0, stream>>>(h16, gptr, lng, lnb, oW1, ob1, oW2, ob2, out);
}